// Round 6
// baseline (1314.239 us; speedup 1.0000x reference)
//
#include <hip/hip_runtime.h>
#include <math.h>

#define SQ_EPS 1e-12f
#define BN_EPS 1e-5f

typedef short short8 __attribute__((ext_vector_type(8)));
typedef float f32x4 __attribute__((ext_vector_type(4)));
typedef unsigned short ushort_t;

__device__ inline unsigned short f2bf(float x) {
    unsigned int u = __float_as_uint(x);
    unsigned int r = (u + 0x7fffu + ((u >> 16) & 1u)) >> 16;   // round-to-nearest-even
    return (unsigned short)r;
}
__device__ inline float bf2f(unsigned short h) {
    return __uint_as_float(((unsigned int)h) << 16);
}

// ---------------- pooling: img(28x28) -> x2(14x14) -> x1(7x7); blocks 0-2 also zero bn accum ----------------
__global__ void pool_kernel(const float* __restrict__ img,
                            float* __restrict__ x2, float* __restrict__ x1,
                            float* __restrict__ bnp_base) {
    __shared__ float s_img[784];
    __shared__ float s_x2[196];
    int b = blockIdx.x;
    if (b < 3) {  // zero sum/sq accumulators for the 3 branches (ws is poisoned)
        bnp_base[b * 512 + threadIdx.x] = 0.f;
        bnp_base[b * 512 + 256 + threadIdx.x] = 0.f;
    }
    const float* im = img + b * 784;
    for (int i = threadIdx.x; i < 784; i += 256) s_img[i] = im[i];
    __syncthreads();
    for (int idx = threadIdx.x; idx < 196; idx += 256) {
        int i = idx / 14, j = idx % 14;
        float v = 0.25f * (s_img[(2*i)*28 + 2*j]     + s_img[(2*i)*28 + 2*j + 1] +
                           s_img[(2*i+1)*28 + 2*j]   + s_img[(2*i+1)*28 + 2*j + 1]);
        s_x2[idx] = v;
        x2[b*196 + idx] = v;
    }
    __syncthreads();
    for (int idx = threadIdx.x; idx < 49; idx += 256) {
        int i = idx / 7, j = idx % 7;
        float v = 0.25f * (s_x2[(2*i)*14 + 2*j]     + s_x2[(2*i)*14 + 2*j + 1] +
                           s_x2[(2*i+1)*14 + 2*j]   + s_x2[(2*i+1)*14 + 2*j + 1]);
        x1[b*49 + idx] = v;
    }
}

// ---------------- conv (1->128ch, stride1, VALID) + relu, split-bf16 out [b][pos][c], BN stats ----------------
template<int IH, int IW, int KS, int OH, int OW>
__global__ __launch_bounds__(256) void conv_split_kernel(
        const float* __restrict__ in, const float* __restrict__ w,
        const float* __restrict__ bias,
        ushort_t* __restrict__ yh, ushort_t* __restrict__ yl,
        float* __restrict__ bnp) {
    constexpr int KK = KS * KS;
    constexpr int OS = OH * OW;
    __shared__ float s_img[IH * IW];
    __shared__ float s_w[128 * KK];
    __shared__ float s_red[256];
    int b = blockIdx.x, tid = threadIdx.x;
    const float* ip = in + b * IH * IW;
    for (int i = tid; i < IH * IW; i += 256) s_img[i] = ip[i];
    for (int i = tid; i < 128 * KK; i += 256) s_w[i] = w[i];
    __syncthreads();
    int c = tid & 127, half = tid >> 7;
    float bias_c = bias[c];
    float bsum = 0.f, bsq = 0.f;
    for (int r = half; r < OH; r += 2) {
        float acc[OW];
        #pragma unroll
        for (int j = 0; j < OW; ++j) acc[j] = bias_c;
        for (int u = 0; u < KS; ++u) {
            float rg[OW + KS - 1];
            #pragma unroll
            for (int j = 0; j < OW + KS - 1; ++j) rg[j] = s_img[(r + u) * IW + j];
            #pragma unroll
            for (int v = 0; v < KS; ++v) {
                float wv = s_w[c * KK + u * KS + v];
                #pragma unroll
                for (int j = 0; j < OW; ++j) acc[j] += wv * rg[j + v];
            }
        }
        #pragma unroll
        for (int j = 0; j < OW; ++j) {
            float val = fmaxf(acc[j], 0.f);
            bsum += val; bsq += val * val;
            unsigned short h = f2bf(val);
            unsigned short lo = f2bf(val - bf2f(h));
            int oidx = ((b * OS) + r * OW + j) * 128 + c;
            yh[oidx] = h; yl[oidx] = lo;
        }
    }
    s_red[tid] = bsum; __syncthreads();
    if (tid < 128) atomicAdd(&bnp[c], s_red[tid] + s_red[tid + 128]);
    __syncthreads();
    s_red[tid] = bsq; __syncthreads();
    if (tid < 128) atomicAdd(&bnp[128 + c], s_red[tid] + s_red[tid + 128]);
}

// ---------------- finalize BN: scale/shift per channel, 3 branches ----------------
__global__ void bn_final_kernel(float* __restrict__ bnp_base) {
    int br = blockIdx.x;
    float* bnp = bnp_base + br * 512;
    float N = (br == 0) ? 6400.f : ((br == 1) ? 25600.f : 102400.f);
    int c = threadIdx.x;  // 128
    float mean = bnp[c] / N;
    float var = bnp[128 + c] / N - mean * mean;
    float inv = rsqrtf(var + BN_EPS);
    bnp[256 + c] = inv;
    bnp[384 + c] = -mean * inv;
}

// ---------------- weight transform (all branches): W[ch][c][uv]*scale_c -> split bf16 [uv][ch][c] ----------------
__global__ void wtrans_all_kernel(const float* __restrict__ w1, const float* __restrict__ w2,
                                  const float* __restrict__ w3, const float* __restrict__ bnp_base,
                                  ushort_t* __restrict__ wh1, ushort_t* __restrict__ wl1,
                                  ushort_t* __restrict__ wh2, ushort_t* __restrict__ wl2,
                                  ushort_t* __restrict__ wh3, ushort_t* __restrict__ wl3) {
    int blk = blockIdx.x;
    const float* w; const float* bnp; ushort_t* wh; ushort_t* wl; int KK;
    if (blk < 1152)      { w = w1; bnp = bnp_base;        wh = wh1; wl = wl1; KK = 9;  }
    else if (blk < 4352) { w = w2; bnp = bnp_base + 512;  wh = wh2; wl = wl2; KK = 25; blk -= 1152; }
    else                 { w = w3; bnp = bnp_base + 1024; wh = wh3; wl = wl3; KK = 81; blk -= 4352; }
    int idx = blk * 256 + threadIdx.x;
    int c = idx & 127, ch = (idx >> 7) & 255, uv = idx >> 15;
    float val = w[((ch << 7) + c) * KK + uv] * bnp[256 + c];
    unsigned short h = f2bf(val);
    unsigned short lo = f2bf(val - bf2f(h));
    wh[idx] = h; wl[idx] = lo;
}

// ---------------- fold BN shift into per-channel bias (all branches) ----------------
__global__ void biasfold_all_kernel(const float* __restrict__ w1, const float* __restrict__ w2,
                                    const float* __restrict__ w3, const float* __restrict__ bnp_base,
                                    const float* __restrict__ pb1, const float* __restrict__ pb2,
                                    const float* __restrict__ pb3,
                                    float* __restrict__ b1, float* __restrict__ b2, float* __restrict__ b3) {
    int br = blockIdx.x >> 8, ch = blockIdx.x & 255, tid = threadIdx.x;  // 128 threads, c = tid
    const float* w  = (br == 0) ? w1  : (br == 1) ? w2  : w3;
    const float* pb = (br == 0) ? pb1 : (br == 1) ? pb2 : pb3;
    float* bf       = (br == 0) ? b1  : (br == 1) ? b2  : b3;
    int KK          = (br == 0) ? 9   : (br == 1) ? 25  : 81;
    const float* bnp = bnp_base + br * 512;
    const float* wrow = w + (ch * 128 + tid) * KK;
    float s = 0.f;
    for (int uv = 0; uv < KK; ++uv) s += wrow[uv];
    s *= bnp[384 + tid];
    for (int off = 32; off; off >>= 1) s += __shfl_down(s, off);
    __shared__ float r2[2];
    if ((tid & 63) == 0) r2[tid >> 6] = s;
    __syncthreads();
    if (tid == 0) bf[ch] = pb[ch] + r2[0] + r2[1];
}

// ---------------- primary-caps conv as split-bf16 MFMA GEMM ----------------
// 64(M) x 64(N) block tile, 4 waves as 2x2 (each 32x32 = 2x2 of 16x16), BK=32.
template<int S, int WO, int IHg, int IWg, int KS>
__global__ __launch_bounds__(256, 4) void prim_gemm_mfma(
        const ushort_t* __restrict__ yh, const ushort_t* __restrict__ yl,
        const ushort_t* __restrict__ wh, const ushort_t* __restrict__ wl,
        const float* __restrict__ biasf, float* __restrict__ p) {
    constexpr int AP = 72;
    __shared__ ushort_t Ash[64 * AP], Asl[64 * AP];
    __shared__ ushort_t Bsh[64 * AP], Bsl[64 * AP];
    int tid = threadIdx.x;
    int bm = blockIdx.x * 64, ch0 = blockIdx.y * 64;
    int arow = tid >> 2;
    int cpart = (tid & 3) * 8;
    int m0 = bm + arow;
    int b0 = m0 / S, s0 = m0 % S;
    int abase = ((b0 * IHg + 2 * (s0 / WO)) * IWg + 2 * (s0 % WO)) * 128 + cpart;
    int bbase = (ch0 + arow) * 128 + cpart;
    int wLidx = arow * AP + cpart;
    int lane = tid & 63, wid = tid >> 6;
    int wm = wid & 1, wn = wid >> 1;
    int quad = lane >> 4, l16 = lane & 15;
    int aoffL[2], boffL[2];
    #pragma unroll
    for (int mi = 0; mi < 2; ++mi) aoffL[mi] = (wm * 32 + mi * 16 + l16) * AP + quad * 8;
    #pragma unroll
    for (int ni = 0; ni < 2; ++ni) boffL[ni] = (wn * 32 + ni * 16 + l16) * AP + quad * 8;
    f32x4 acc[2][2];
    #pragma unroll
    for (int mi = 0; mi < 2; ++mi)
        #pragma unroll
        for (int ni = 0; ni < 2; ++ni)
            acc[mi][ni] = (f32x4){0.f, 0.f, 0.f, 0.f};

    for (int u = 0; u < KS; ++u) {
        for (int v = 0; v < KS; ++v) {
            int aoff = (u * IWg + v) * 128;
            int boff = (u * KS + v) * 32768;
            for (int cs = 0; cs < 128; cs += 32) {
                int4 a4h = *reinterpret_cast<const int4*>(yh + abase + aoff + cs);
                int4 a4l = *reinterpret_cast<const int4*>(yl + abase + aoff + cs);
                int4 b4h = *reinterpret_cast<const int4*>(wh + bbase + boff + cs);
                int4 b4l = *reinterpret_cast<const int4*>(wl + bbase + boff + cs);
                __syncthreads();
                *reinterpret_cast<int4*>(&Ash[wLidx]) = a4h;
                *reinterpret_cast<int4*>(&Asl[wLidx]) = a4l;
                *reinterpret_cast<int4*>(&Bsh[wLidx]) = b4h;
                *reinterpret_cast<int4*>(&Bsl[wLidx]) = b4l;
                __syncthreads();
                short8 ah[2], al[2], bh[2], bl[2];
                #pragma unroll
                for (int mi = 0; mi < 2; ++mi) {
                    ah[mi] = *reinterpret_cast<const short8*>(&Ash[aoffL[mi]]);
                    al[mi] = *reinterpret_cast<const short8*>(&Asl[aoffL[mi]]);
                }
                #pragma unroll
                for (int ni = 0; ni < 2; ++ni) {
                    bh[ni] = *reinterpret_cast<const short8*>(&Bsh[boffL[ni]]);
                    bl[ni] = *reinterpret_cast<const short8*>(&Bsl[boffL[ni]]);
                }
                #pragma unroll
                for (int mi = 0; mi < 2; ++mi)
                    #pragma unroll
                    for (int ni = 0; ni < 2; ++ni) {
                        acc[mi][ni] = __builtin_amdgcn_mfma_f32_16x16x32_bf16(ah[mi], bh[ni], acc[mi][ni], 0, 0, 0);
                        acc[mi][ni] = __builtin_amdgcn_mfma_f32_16x16x32_bf16(al[mi], bh[ni], acc[mi][ni], 0, 0, 0);
                        acc[mi][ni] = __builtin_amdgcn_mfma_f32_16x16x32_bf16(ah[mi], bl[ni], acc[mi][ni], 0, 0, 0);
                    }
            }
        }
    }
    float bv[2];
    #pragma unroll
    for (int ni = 0; ni < 2; ++ni) bv[ni] = biasf[ch0 + wn * 32 + ni * 16 + l16];
    #pragma unroll
    for (int mi = 0; mi < 2; ++mi)
        #pragma unroll
        for (int ni = 0; ni < 2; ++ni) {
            int col = ch0 + wn * 32 + ni * 16 + l16;
            #pragma unroll
            for (int reg = 0; reg < 4; ++reg) {
                int row = bm + wm * 32 + mi * 16 + quad * 4 + reg;
                p[(size_t)row * 256 + col] = acc[mi][ni][reg] + bv[ni];
            }
        }
}

// ---------------- squash primary caps (all branches): p(B*S,256) -> u(B,32*S,8) ----------------
__global__ void squash_all_kernel(const float* __restrict__ p1, const float* __restrict__ p2,
                                  const float* __restrict__ p3,
                                  float* __restrict__ u1, float* __restrict__ u2,
                                  float* __restrict__ u3) {
    int blk = blockIdx.x;
    const float* p; float* u; int S;
    if (blk < 128)      { p = p1; u = u1; S = 4; }
    else if (blk < 416) { p = p2; u = u2; S = 9;  blk -= 128; }
    else                { p = p3; u = u3; S = 36; blk -= 416; }
    int idx = blk * 256 + threadIdx.x;   // over 256*S*32, o innermost
    int o = idx & 31, rest = idx >> 5;
    int s = rest % S, b = rest / S;
    const float* pp = p + (size_t)(b * S + s) * 256 + o;
    float t[8]; float sn = 0.f;
    #pragma unroll
    for (int i = 0; i < 8; ++i) { t[i] = pp[i * 32]; sn += t[i] * t[i]; }
    float f = sn / ((1.f + sn) * sqrtf(sn + SQ_EPS));
    float* up = u + (size_t)(b * (32 * S) + o * S + s) * 8;
    float4 w0 = {t[0] * f, t[1] * f, t[2] * f, t[3] * f};
    float4 w1 = {t[4] * f, t[5] * f, t[6] * f, t[7] * f};
    *reinterpret_cast<float4*>(up) = w0;
    *reinterpret_cast<float4*>(up + 4) = w1;
}

// ---------------- routing weights -> bf16 (after gemm3 frees yl3 region) ----------------
__global__ void rwtrans_kernel(const float* __restrict__ w1, const float* __restrict__ w2,
                               const float* __restrict__ w3,
                               ushort_t* __restrict__ o1, ushort_t* __restrict__ o2,
                               ushort_t* __restrict__ o3) {
    int idx = blockIdx.x * 256 + threadIdx.x;  // 7840*256 = 2,007,040 exact
    const float* src; ushort_t* dst; int off;
    if (idx < 163840)      { src = w1; dst = o1; off = idx; }
    else if (idx < 532480) { src = w2; dst = o2; off = idx - 163840; }
    else                   { src = w3; dst = o3; off = idx - 532480; }
    dst[off] = f2bf(src[off]);
}

// ---------------- dynamic routing (3 iters): priors in bf16-packed REGISTERS, w in bf16 ----------------
// grid (10, 256); each thread owns routes r = tid + 256k. LDS only for reductions.
template<int R>
__global__ __launch_bounds__(256, 4) void routing_reg_kernel(
        const float* __restrict__ u, const ushort_t* __restrict__ rwb,
        float* __restrict__ lens) {
    constexpr int KMAX = (R + 255) / 256;
    constexpr int KFULL = R / 256;
    constexpr int REM = R - KFULL * 256;
    int n = blockIdx.x, b = blockIdx.y;
    int tid = threadIdx.x, lane = tid & 63, wv = tid >> 6;
    __shared__ float red[4 * 16];
    __shared__ float vsh[16];
    __shared__ float sred[4];
    unsigned int pk[KMAX][8];
    float blog[KMAX];
    #pragma unroll
    for (int k = 0; k < KMAX; ++k) {
        bool valid = (k < KFULL) || (REM && tid < REM);
        blog[k] = 0.f;
        if (valid) {
            int r = tid + k * 256;
            const float4* up = (const float4*)(u + ((size_t)b * R + r) * 8);
            float4 ua = up[0], ub2 = up[1];
            float uu[8] = {ua.x, ua.y, ua.z, ua.w, ub2.x, ub2.y, ub2.z, ub2.w};
            const ushort_t* wr = rwb + ((size_t)n * R + r) * 128;
            float po[16] = {};
            #pragma unroll
            for (int i = 0; i < 8; ++i) {
                short8 wa = *reinterpret_cast<const short8*>(wr + i * 16);
                short8 wb = *reinterpret_cast<const short8*>(wr + i * 16 + 8);
                #pragma unroll
                for (int o = 0; o < 8; ++o) po[o]     += uu[i] * bf2f((unsigned short)wa[o]);
                #pragma unroll
                for (int o = 0; o < 8; ++o) po[8 + o] += uu[i] * bf2f((unsigned short)wb[o]);
            }
            #pragma unroll
            for (int j = 0; j < 8; ++j)
                pk[k][j] = (unsigned int)f2bf(po[2*j]) | ((unsigned int)f2bf(po[2*j+1]) << 16);
        } else {
            #pragma unroll
            for (int j = 0; j < 8; ++j) pk[k][j] = 0u;
        }
    }
    float v[16];
    for (int it = 0; it < 3; ++it) {
        float lmax = -1e30f;
        #pragma unroll
        for (int k = 0; k < KMAX; ++k) {
            bool valid = (k < KFULL) || (REM && tid < REM);
            if (valid) lmax = fmaxf(lmax, blog[k]);
        }
        for (int off = 32; off; off >>= 1) lmax = fmaxf(lmax, __shfl_down(lmax, off));
        if (lane == 0) sred[wv] = lmax;
        __syncthreads();
        float mx = fmaxf(fmaxf(sred[0], sred[1]), fmaxf(sred[2], sred[3]));
        __syncthreads();
        float ce[KMAX];
        float lsum = 0.f;
        #pragma unroll
        for (int k = 0; k < KMAX; ++k) {
            bool valid = (k < KFULL) || (REM && tid < REM);
            ce[k] = valid ? expf(blog[k] - mx) : 0.f;
            lsum += ce[k];
        }
        for (int off = 32; off; off >>= 1) lsum += __shfl_down(lsum, off);
        if (lane == 0) sred[wv] = lsum;
        __syncthreads();
        float inv = 1.f / (sred[0] + sred[1] + sred[2] + sred[3]);
        float sacc[16] = {};
        #pragma unroll
        for (int k = 0; k < KMAX; ++k) {
            float c = ce[k] * inv;
            #pragma unroll
            for (int j = 0; j < 8; ++j) {
                unsigned int w = pk[k][j];
                sacc[2*j]   += c * bf2f((unsigned short)(w & 0xffffu));
                sacc[2*j+1] += c * bf2f((unsigned short)(w >> 16));
            }
        }
        #pragma unroll
        for (int o = 0; o < 16; ++o) {
            float xv = sacc[o];
            for (int off = 32; off; off >>= 1) xv += __shfl_down(xv, off);
            if (lane == 0) red[wv * 16 + o] = xv;
        }
        __syncthreads();
        if (tid < 16) vsh[tid] = red[tid] + red[16 + tid] + red[32 + tid] + red[48 + tid];
        __syncthreads();
        if (tid == 0) {
            float sn = 0.f;
            #pragma unroll
            for (int o = 0; o < 16; ++o) sn += vsh[o] * vsh[o];
            float f = sn / ((1.f + sn) * sqrtf(sn + SQ_EPS));
            #pragma unroll
            for (int o = 0; o < 16; ++o) vsh[o] *= f;
        }
        __syncthreads();
        #pragma unroll
        for (int o = 0; o < 16; ++o) v[o] = vsh[o];
        if (it < 2) {
            #pragma unroll
            for (int k = 0; k < KMAX; ++k) {
                float dot = 0.f;
                #pragma unroll
                for (int j = 0; j < 8; ++j) {
                    unsigned int w = pk[k][j];
                    dot += bf2f((unsigned short)(w & 0xffffu)) * v[2*j];
                    dot += bf2f((unsigned short)(w >> 16)) * v[2*j+1];
                }
                blog[k] += dot;
            }
        }
    }
    if (tid == 0) {
        float sn = 0.f;
        #pragma unroll
        for (int o = 0; o < 16; ++o) sn += v[o] * v[o];
        lens[b * 10 + n] = sqrtf(sn + SQ_EPS);
    }
}

// ---------------- final: softmax over classes of l1+l2+l3 ----------------
__global__ void final_softmax_kernel(const float* __restrict__ l1, const float* __restrict__ l2,
                                     const float* __restrict__ l3, float* __restrict__ out) {
    int b = threadIdx.x;
    float v[10]; float mx = -1e30f;
    #pragma unroll
    for (int n = 0; n < 10; ++n) {
        v[n] = l1[b * 10 + n] + l2[b * 10 + n] + l3[b * 10 + n];
        mx = fmaxf(mx, v[n]);
    }
    float s = 0.f;
    #pragma unroll
    for (int n = 0; n < 10; ++n) { v[n] = expf(v[n] - mx); s += v[n]; }
    float inv = 1.f / s;
    #pragma unroll
    for (int n = 0; n < 10; ++n) out[b * 10 + n] = v[n] * inv;
}

extern "C" void kernel_launch(void* const* d_in, const int* in_sizes, int n_in,
                              void* d_out, int out_size, void* d_ws, size_t ws_size,
                              hipStream_t stream) {
    const float* x   = (const float*)d_in[0];
    const float* c1w = (const float*)d_in[1];
    const float* c1b = (const float*)d_in[2];
    const float* p1w = (const float*)d_in[3];
    const float* p1b = (const float*)d_in[4];
    const float* d1w = (const float*)d_in[5];
    const float* c2w = (const float*)d_in[6];
    const float* c2b = (const float*)d_in[7];
    const float* p2w = (const float*)d_in[8];
    const float* p2b = (const float*)d_in[9];
    const float* d2w = (const float*)d_in[10];
    const float* c3w = (const float*)d_in[11];
    const float* c3b = (const float*)d_in[12];
    const float* p3w = (const float*)d_in[13];
    const float* p3b = (const float*)d_in[14];
    const float* d3w = (const float*)d_in[15];

    float* ws = (float*)d_ws;
    // region layout (float units) — total 23,403,520 floats = 93.6 MB
    float* x2    = ws + 0;          // 50176
    float* x1    = ws + 50176;      // 12544
    float* yh1f  = ws + 62720;      // 409600   (819200 halves)  [aliased by u1 later]
    float* yl1f  = ws + 472320;     // 409600
    float* yh2f  = ws + 881920;     // 1638400  [aliased by u2 later]
    float* yl2f  = ws + 2520320;    // 1638400
    float* yh3f  = ws + 4158720;    // 6553600  [aliased by u3 later]
    float* yl3f  = ws + 10712320;   // 6553600  [aliased by rwb after gemm3]
    float* wh1f  = ws + 17265920;   // 147456
    float* wl1f  = ws + 17413376;   // 147456
    float* wh2f  = ws + 17560832;   // 409600
    float* wl2f  = ws + 17970432;   // 409600
    float* wh3f  = ws + 18380032;   // 1327104  [aliased by p2 later]
    float* wl3f  = ws + 19707136;   // 1327104  [aliased by p1 later]
    float* p3    = ws + 21034240;   // 2359296
    float* bnp1  = ws + 23393536;   // 512 (x3: bnp2, bnp3 follow)
    float* bias1 = ws + 23395072;   // 256
    float* bias2 = ws + 23395328;   // 256
    float* bias3 = ws + 23395584;   // 256
    float* l1    = ws + 23395840;   // 2560
    float* l2    = ws + 23398400;   // 2560
    float* l3    = ws + 23400960;   // 2560

    ushort_t* yh1 = (ushort_t*)yh1f; ushort_t* yl1 = (ushort_t*)yl1f;
    ushort_t* yh2 = (ushort_t*)yh2f; ushort_t* yl2 = (ushort_t*)yl2f;
    ushort_t* yh3 = (ushort_t*)yh3f; ushort_t* yl3 = (ushort_t*)yl3f;
    ushort_t* wh1 = (ushort_t*)wh1f; ushort_t* wl1 = (ushort_t*)wl1f;
    ushort_t* wh2 = (ushort_t*)wh2f; ushort_t* wl2 = (ushort_t*)wl2f;
    ushort_t* wh3 = (ushort_t*)wh3f; ushort_t* wl3 = (ushort_t*)wl3f;
    // aliases (safe by stream ordering):
    float* u1 = yh1f;   // written after gemm1 reads yh1
    float* u2 = yh2f;
    float* u3 = yh3f;
    float* p2 = wh3f;   // written after gemm3 reads wh3
    float* p1 = wl3f;
    // bf16 routing weights live in dead yl3 region (converted after gemm3):
    ushort_t* rwb1 = (ushort_t*)yl3f;          // 163840 halves
    ushort_t* rwb2 = rwb1 + 163840;            // 368640 halves
    ushort_t* rwb3 = rwb2 + 368640;            // 1474560 halves (total 2,007,040 <= 13,107,200)

    pool_kernel<<<256, 256, 0, stream>>>(x, x2, x1, bnp1);

    conv_split_kernel<7, 7, 3, 5, 5><<<256, 256, 0, stream>>>(x1, c1w, c1b, yh1, yl1, bnp1);
    conv_split_kernel<14, 14, 5, 10, 10><<<256, 256, 0, stream>>>(x2, c2w, c2b, yh2, yl2, bnp1 + 512);
    conv_split_kernel<28, 28, 9, 20, 20><<<256, 256, 0, stream>>>(x, c3w, c3b, yh3, yl3, bnp1 + 1024);

    bn_final_kernel<<<3, 128, 0, stream>>>(bnp1);

    wtrans_all_kernel<<<14720, 256, 0, stream>>>(p1w, p2w, p3w, bnp1,
                                                 wh1, wl1, wh2, wl2, wh3, wl3);
    biasfold_all_kernel<<<768, 128, 0, stream>>>(p1w, p2w, p3w, bnp1,
                                                 p1b, p2b, p3b, bias1, bias2, bias3);

    // gemm3 first: afterwards wh3/wl3 are dead (reused for p2/p1) and yl3 is dead (reused for rwb)
    prim_gemm_mfma<36, 6, 20, 20, 9><<<dim3(144, 4), 256, 0, stream>>>(yh3, yl3, wh3, wl3, bias3, p3);
    rwtrans_kernel<<<7840, 256, 0, stream>>>(d1w, d2w, d3w, rwb1, rwb2, rwb3);
    prim_gemm_mfma<9, 3, 10, 10, 5><<<dim3(36, 4), 256, 0, stream>>>(yh2, yl2, wh2, wl2, bias2, p2);
    prim_gemm_mfma<4, 2, 5, 5, 3><<<dim3(16, 4), 256, 0, stream>>>(yh1, yl1, wh1, wl1, bias1, p1);

    squash_all_kernel<<<1568, 256, 0, stream>>>(p1, p2, p3, u1, u2, u3);

    routing_reg_kernel<128><<<dim3(10, 256), 256, 0, stream>>>(u1, rwb1, l1);
    routing_reg_kernel<288><<<dim3(10, 256), 256, 0, stream>>>(u2, rwb2, l2);
    routing_reg_kernel<1152><<<dim3(10, 256), 256, 0, stream>>>(u3, rwb3, l3);

    final_softmax_kernel<<<1, 256, 0, stream>>>(l1, l2, l3, (float*)d_out);
}

// Round 7
// 807.221 us; speedup vs baseline: 1.6281x; 1.6281x over previous
//
#include <hip/hip_runtime.h>
#include <math.h>

#define SQ_EPS 1e-12f
#define BN_EPS 1e-5f

typedef short short8 __attribute__((ext_vector_type(8)));
typedef float f32x4 __attribute__((ext_vector_type(4)));
typedef unsigned short ushort_t;

__device__ inline unsigned short f2bf(float x) {
    unsigned int u = __float_as_uint(x);
    unsigned int r = (u + 0x7fffu + ((u >> 16) & 1u)) >> 16;   // round-to-nearest-even
    return (unsigned short)r;
}
__device__ inline float bf2f(unsigned short h) {
    return __uint_as_float(((unsigned int)h) << 16);
}

// ---------------- pooling: img(28x28) -> x2(14x14) -> x1(7x7); blocks 0-2 also zero bn accum ----------------
__global__ void pool_kernel(const float* __restrict__ img,
                            float* __restrict__ x2, float* __restrict__ x1,
                            float* __restrict__ bnp_base) {
    __shared__ float s_img[784];
    __shared__ float s_x2[196];
    int b = blockIdx.x;
    if (b < 3) {  // zero sum/sq accumulators for the 3 branches (ws is poisoned)
        bnp_base[b * 512 + threadIdx.x] = 0.f;
        bnp_base[b * 512 + 256 + threadIdx.x] = 0.f;
    }
    const float* im = img + b * 784;
    for (int i = threadIdx.x; i < 784; i += 256) s_img[i] = im[i];
    __syncthreads();
    for (int idx = threadIdx.x; idx < 196; idx += 256) {
        int i = idx / 14, j = idx % 14;
        float v = 0.25f * (s_img[(2*i)*28 + 2*j]     + s_img[(2*i)*28 + 2*j + 1] +
                           s_img[(2*i+1)*28 + 2*j]   + s_img[(2*i+1)*28 + 2*j + 1]);
        s_x2[idx] = v;
        x2[b*196 + idx] = v;
    }
    __syncthreads();
    for (int idx = threadIdx.x; idx < 49; idx += 256) {
        int i = idx / 7, j = idx % 7;
        float v = 0.25f * (s_x2[(2*i)*14 + 2*j]     + s_x2[(2*i)*14 + 2*j + 1] +
                           s_x2[(2*i+1)*14 + 2*j]   + s_x2[(2*i+1)*14 + 2*j + 1]);
        x1[b*49 + idx] = v;
    }
}

// ---------------- conv (1->128ch, stride1, VALID) + relu, split-bf16 out [b][pos][c], BN stats ----------------
template<int IH, int IW, int KS, int OH, int OW>
__global__ __launch_bounds__(256) void conv_split_kernel(
        const float* __restrict__ in, const float* __restrict__ w,
        const float* __restrict__ bias,
        ushort_t* __restrict__ yh, ushort_t* __restrict__ yl,
        float* __restrict__ bnp) {
    constexpr int KK = KS * KS;
    constexpr int OS = OH * OW;
    __shared__ float s_img[IH * IW];
    __shared__ float s_w[128 * KK];
    __shared__ float s_red[256];
    int b = blockIdx.x, tid = threadIdx.x;
    const float* ip = in + b * IH * IW;
    for (int i = tid; i < IH * IW; i += 256) s_img[i] = ip[i];
    for (int i = tid; i < 128 * KK; i += 256) s_w[i] = w[i];
    __syncthreads();
    int c = tid & 127, half = tid >> 7;
    float bias_c = bias[c];
    float bsum = 0.f, bsq = 0.f;
    for (int r = half; r < OH; r += 2) {
        float acc[OW];
        #pragma unroll
        for (int j = 0; j < OW; ++j) acc[j] = bias_c;
        for (int u = 0; u < KS; ++u) {
            float rg[OW + KS - 1];
            #pragma unroll
            for (int j = 0; j < OW + KS - 1; ++j) rg[j] = s_img[(r + u) * IW + j];
            #pragma unroll
            for (int v = 0; v < KS; ++v) {
                float wv = s_w[c * KK + u * KS + v];
                #pragma unroll
                for (int j = 0; j < OW; ++j) acc[j] += wv * rg[j + v];
            }
        }
        #pragma unroll
        for (int j = 0; j < OW; ++j) {
            float val = fmaxf(acc[j], 0.f);
            bsum += val; bsq += val * val;
            unsigned short h = f2bf(val);
            unsigned short lo = f2bf(val - bf2f(h));
            int oidx = ((b * OS) + r * OW + j) * 128 + c;
            yh[oidx] = h; yl[oidx] = lo;
        }
    }
    s_red[tid] = bsum; __syncthreads();
    if (tid < 128) atomicAdd(&bnp[c], s_red[tid] + s_red[tid + 128]);
    __syncthreads();
    s_red[tid] = bsq; __syncthreads();
    if (tid < 128) atomicAdd(&bnp[128 + c], s_red[tid] + s_red[tid + 128]);
}

// ---------------- finalize BN: scale/shift per channel, 3 branches ----------------
__global__ void bn_final_kernel(float* __restrict__ bnp_base) {
    int br = blockIdx.x;
    float* bnp = bnp_base + br * 512;
    float N = (br == 0) ? 6400.f : ((br == 1) ? 25600.f : 102400.f);
    int c = threadIdx.x;  // 128
    float mean = bnp[c] / N;
    float var = bnp[128 + c] / N - mean * mean;
    float inv = rsqrtf(var + BN_EPS);
    bnp[256 + c] = inv;
    bnp[384 + c] = -mean * inv;
}

// ---------------- weight transform (all branches): W[ch][c][uv]*scale_c -> split bf16 [uv][ch][c] ----------------
__global__ void wtrans_all_kernel(const float* __restrict__ w1, const float* __restrict__ w2,
                                  const float* __restrict__ w3, const float* __restrict__ bnp_base,
                                  ushort_t* __restrict__ wh1, ushort_t* __restrict__ wl1,
                                  ushort_t* __restrict__ wh2, ushort_t* __restrict__ wl2,
                                  ushort_t* __restrict__ wh3, ushort_t* __restrict__ wl3) {
    int blk = blockIdx.x;
    const float* w; const float* bnp; ushort_t* wh; ushort_t* wl; int KK;
    if (blk < 1152)      { w = w1; bnp = bnp_base;        wh = wh1; wl = wl1; KK = 9;  }
    else if (blk < 4352) { w = w2; bnp = bnp_base + 512;  wh = wh2; wl = wl2; KK = 25; blk -= 1152; }
    else                 { w = w3; bnp = bnp_base + 1024; wh = wh3; wl = wl3; KK = 81; blk -= 4352; }
    int idx = blk * 256 + threadIdx.x;
    int c = idx & 127, ch = (idx >> 7) & 255, uv = idx >> 15;
    float val = w[((ch << 7) + c) * KK + uv] * bnp[256 + c];
    unsigned short h = f2bf(val);
    unsigned short lo = f2bf(val - bf2f(h));
    wh[idx] = h; wl[idx] = lo;
}

// ---------------- fold BN shift into per-channel bias (all branches) ----------------
__global__ void biasfold_all_kernel(const float* __restrict__ w1, const float* __restrict__ w2,
                                    const float* __restrict__ w3, const float* __restrict__ bnp_base,
                                    const float* __restrict__ pb1, const float* __restrict__ pb2,
                                    const float* __restrict__ pb3,
                                    float* __restrict__ b1, float* __restrict__ b2, float* __restrict__ b3) {
    int br = blockIdx.x >> 8, ch = blockIdx.x & 255, tid = threadIdx.x;  // 128 threads, c = tid
    const float* w  = (br == 0) ? w1  : (br == 1) ? w2  : w3;
    const float* pb = (br == 0) ? pb1 : (br == 1) ? pb2 : pb3;
    float* bf       = (br == 0) ? b1  : (br == 1) ? b2  : b3;
    int KK          = (br == 0) ? 9   : (br == 1) ? 25  : 81;
    const float* bnp = bnp_base + br * 512;
    const float* wrow = w + (ch * 128 + tid) * KK;
    float s = 0.f;
    for (int uv = 0; uv < KK; ++uv) s += wrow[uv];
    s *= bnp[384 + tid];
    for (int off = 32; off; off >>= 1) s += __shfl_down(s, off);
    __shared__ float r2[2];
    if ((tid & 63) == 0) r2[tid >> 6] = s;
    __syncthreads();
    if (tid == 0) bf[ch] = pb[ch] + r2[0] + r2[1];
}

// ---------------- primary-caps conv as split-bf16 MFMA GEMM ----------------
// 64(M) x 64(N) block tile, 4 waves as 2x2 (each 32x32 = 2x2 of 16x16), BK=32.
template<int S, int WO, int IHg, int IWg, int KS>
__global__ __launch_bounds__(256, 4) void prim_gemm_mfma(
        const ushort_t* __restrict__ yh, const ushort_t* __restrict__ yl,
        const ushort_t* __restrict__ wh, const ushort_t* __restrict__ wl,
        const float* __restrict__ biasf, float* __restrict__ p) {
    constexpr int AP = 72;
    __shared__ ushort_t Ash[64 * AP], Asl[64 * AP];
    __shared__ ushort_t Bsh[64 * AP], Bsl[64 * AP];
    int tid = threadIdx.x;
    int bm = blockIdx.x * 64, ch0 = blockIdx.y * 64;
    int arow = tid >> 2;
    int cpart = (tid & 3) * 8;
    int m0 = bm + arow;
    int b0 = m0 / S, s0 = m0 % S;
    int abase = ((b0 * IHg + 2 * (s0 / WO)) * IWg + 2 * (s0 % WO)) * 128 + cpart;
    int bbase = (ch0 + arow) * 128 + cpart;
    int wLidx = arow * AP + cpart;
    int lane = tid & 63, wid = tid >> 6;
    int wm = wid & 1, wn = wid >> 1;
    int quad = lane >> 4, l16 = lane & 15;
    int aoffL[2], boffL[2];
    #pragma unroll
    for (int mi = 0; mi < 2; ++mi) aoffL[mi] = (wm * 32 + mi * 16 + l16) * AP + quad * 8;
    #pragma unroll
    for (int ni = 0; ni < 2; ++ni) boffL[ni] = (wn * 32 + ni * 16 + l16) * AP + quad * 8;
    f32x4 acc[2][2];
    #pragma unroll
    for (int mi = 0; mi < 2; ++mi)
        #pragma unroll
        for (int ni = 0; ni < 2; ++ni)
            acc[mi][ni] = (f32x4){0.f, 0.f, 0.f, 0.f};

    for (int u = 0; u < KS; ++u) {
        for (int v = 0; v < KS; ++v) {
            int aoff = (u * IWg + v) * 128;
            int boff = (u * KS + v) * 32768;
            for (int cs = 0; cs < 128; cs += 32) {
                int4 a4h = *reinterpret_cast<const int4*>(yh + abase + aoff + cs);
                int4 a4l = *reinterpret_cast<const int4*>(yl + abase + aoff + cs);
                int4 b4h = *reinterpret_cast<const int4*>(wh + bbase + boff + cs);
                int4 b4l = *reinterpret_cast<const int4*>(wl + bbase + boff + cs);
                __syncthreads();
                *reinterpret_cast<int4*>(&Ash[wLidx]) = a4h;
                *reinterpret_cast<int4*>(&Asl[wLidx]) = a4l;
                *reinterpret_cast<int4*>(&Bsh[wLidx]) = b4h;
                *reinterpret_cast<int4*>(&Bsl[wLidx]) = b4l;
                __syncthreads();
                short8 ah[2], al[2], bh[2], bl[2];
                #pragma unroll
                for (int mi = 0; mi < 2; ++mi) {
                    ah[mi] = *reinterpret_cast<const short8*>(&Ash[aoffL[mi]]);
                    al[mi] = *reinterpret_cast<const short8*>(&Asl[aoffL[mi]]);
                }
                #pragma unroll
                for (int ni = 0; ni < 2; ++ni) {
                    bh[ni] = *reinterpret_cast<const short8*>(&Bsh[boffL[ni]]);
                    bl[ni] = *reinterpret_cast<const short8*>(&Bsl[boffL[ni]]);
                }
                #pragma unroll
                for (int mi = 0; mi < 2; ++mi)
                    #pragma unroll
                    for (int ni = 0; ni < 2; ++ni) {
                        acc[mi][ni] = __builtin_amdgcn_mfma_f32_16x16x32_bf16(ah[mi], bh[ni], acc[mi][ni], 0, 0, 0);
                        acc[mi][ni] = __builtin_amdgcn_mfma_f32_16x16x32_bf16(al[mi], bh[ni], acc[mi][ni], 0, 0, 0);
                        acc[mi][ni] = __builtin_amdgcn_mfma_f32_16x16x32_bf16(ah[mi], bl[ni], acc[mi][ni], 0, 0, 0);
                    }
            }
        }
    }
    float bv[2];
    #pragma unroll
    for (int ni = 0; ni < 2; ++ni) bv[ni] = biasf[ch0 + wn * 32 + ni * 16 + l16];
    #pragma unroll
    for (int mi = 0; mi < 2; ++mi)
        #pragma unroll
        for (int ni = 0; ni < 2; ++ni) {
            int col = ch0 + wn * 32 + ni * 16 + l16;
            #pragma unroll
            for (int reg = 0; reg < 4; ++reg) {
                int row = bm + wm * 32 + mi * 16 + quad * 4 + reg;
                p[(size_t)row * 256 + col] = acc[mi][ni][reg] + bv[ni];
            }
        }
}

// ---------------- squash primary caps (all branches): p(B*S,256) -> u(B,32*S,8) ----------------
__global__ void squash_all_kernel(const float* __restrict__ p1, const float* __restrict__ p2,
                                  const float* __restrict__ p3,
                                  float* __restrict__ u1, float* __restrict__ u2,
                                  float* __restrict__ u3) {
    int blk = blockIdx.x;
    const float* p; float* u; int S;
    if (blk < 128)      { p = p1; u = u1; S = 4; }
    else if (blk < 416) { p = p2; u = u2; S = 9;  blk -= 128; }
    else                { p = p3; u = u3; S = 36; blk -= 416; }
    int idx = blk * 256 + threadIdx.x;   // over 256*S*32, o innermost
    int o = idx & 31, rest = idx >> 5;
    int s = rest % S, b = rest / S;
    const float* pp = p + (size_t)(b * S + s) * 256 + o;
    float t[8]; float sn = 0.f;
    #pragma unroll
    for (int i = 0; i < 8; ++i) { t[i] = pp[i * 32]; sn += t[i] * t[i]; }
    float f = sn / ((1.f + sn) * sqrtf(sn + SQ_EPS));
    float* up = u + (size_t)(b * (32 * S) + o * S + s) * 8;
    float4 w0 = {t[0] * f, t[1] * f, t[2] * f, t[3] * f};
    float4 w1 = {t[4] * f, t[5] * f, t[6] * f, t[7] * f};
    *reinterpret_cast<float4*>(up) = w0;
    *reinterpret_cast<float4*>(up + 4) = w1;
}

// ---------------- routing weights -> bf16 (after gemm3 frees yl3 region) ----------------
__global__ void rwtrans_kernel(const float* __restrict__ w1, const float* __restrict__ w2,
                               const float* __restrict__ w3,
                               ushort_t* __restrict__ o1, ushort_t* __restrict__ o2,
                               ushort_t* __restrict__ o3) {
    int idx = blockIdx.x * 256 + threadIdx.x;  // 7840*256 = 2,007,040 exact
    const float* src; ushort_t* dst; int off;
    if (idx < 163840)      { src = w1; dst = o1; off = idx; }
    else if (idx < 532480) { src = w2; dst = o2; off = idx - 163840; }
    else                   { src = w3; dst = o3; off = idx - 532480; }
    dst[off] = f2bf(src[off]);
}

// ---------------- dynamic routing (3 iters): priors packed bf16x2 in LDS (transposed, conflict-free),
//                  blog in registers, weights bf16 (slab fits per-XCD L2) ----------------
template<int R>
__global__ __launch_bounds__(256, 4) void routing_lds_kernel(
        const float* __restrict__ u, const ushort_t* __restrict__ rwb,
        float* __restrict__ lens) {
    constexpr int KMAX = (R + 255) / 256;
    int n = blockIdx.x, b = blockIdx.y;
    int tid = threadIdx.x, lane = tid & 63, wv = tid >> 6;
    __shared__ unsigned int pri[8 * R];   // pri[j*R + r] = bf16(po[2j]) | bf16(po[2j+1])<<16
    __shared__ float red[4 * 16];
    __shared__ float vsh[16];
    __shared__ float sred[4];
    float blog[KMAX];
    #pragma unroll
    for (int k = 0; k < KMAX; ++k) {
        blog[k] = 0.f;
        int r = tid + k * 256;
        if (r < R) {
            const float4* up = (const float4*)(u + ((size_t)b * R + r) * 8);
            float4 ua = up[0], ub2 = up[1];
            float uu[8] = {ua.x, ua.y, ua.z, ua.w, ub2.x, ub2.y, ub2.z, ub2.w};
            const ushort_t* wr = rwb + ((size_t)n * R + r) * 128;
            float po[16] = {};
            #pragma unroll
            for (int i = 0; i < 8; ++i) {
                short8 wa = *reinterpret_cast<const short8*>(wr + i * 16);
                short8 wb = *reinterpret_cast<const short8*>(wr + i * 16 + 8);
                #pragma unroll
                for (int o = 0; o < 8; ++o) po[o]     += uu[i] * bf2f((unsigned short)wa[o]);
                #pragma unroll
                for (int o = 0; o < 8; ++o) po[8 + o] += uu[i] * bf2f((unsigned short)wb[o]);
            }
            #pragma unroll
            for (int j = 0; j < 8; ++j)
                pri[j * R + r] = (unsigned int)f2bf(po[2*j]) | ((unsigned int)f2bf(po[2*j+1]) << 16);
        }
    }
    __syncthreads();
    float v[16];
    for (int it = 0; it < 3; ++it) {
        float lmax = -1e30f;
        #pragma unroll
        for (int k = 0; k < KMAX; ++k)
            if (tid + k * 256 < R) lmax = fmaxf(lmax, blog[k]);
        for (int off = 32; off; off >>= 1) lmax = fmaxf(lmax, __shfl_down(lmax, off));
        if (lane == 0) sred[wv] = lmax;
        __syncthreads();
        float mx = fmaxf(fmaxf(sred[0], sred[1]), fmaxf(sred[2], sred[3]));
        __syncthreads();
        float ce[KMAX];
        float lsum = 0.f;
        #pragma unroll
        for (int k = 0; k < KMAX; ++k) {
            ce[k] = (tid + k * 256 < R) ? expf(blog[k] - mx) : 0.f;
            lsum += ce[k];
        }
        for (int off = 32; off; off >>= 1) lsum += __shfl_down(lsum, off);
        if (lane == 0) sred[wv] = lsum;
        __syncthreads();
        float inv = 1.f / (sred[0] + sred[1] + sred[2] + sred[3]);
        float sacc[16] = {};
        #pragma unroll
        for (int k = 0; k < KMAX; ++k) {
            int r = tid + k * 256;
            if (r < R) {
                float c = ce[k] * inv;
                #pragma unroll
                for (int j = 0; j < 8; ++j) {
                    unsigned int w = pri[j * R + r];
                    sacc[2*j]   += c * bf2f((unsigned short)(w & 0xffffu));
                    sacc[2*j+1] += c * bf2f((unsigned short)(w >> 16));
                }
            }
        }
        #pragma unroll
        for (int o = 0; o < 16; ++o) {
            float xv = sacc[o];
            for (int off = 32; off; off >>= 1) xv += __shfl_down(xv, off);
            if (lane == 0) red[wv * 16 + o] = xv;
        }
        __syncthreads();
        if (tid < 16) vsh[tid] = red[tid] + red[16 + tid] + red[32 + tid] + red[48 + tid];
        __syncthreads();
        if (tid == 0) {
            float sn = 0.f;
            #pragma unroll
            for (int o = 0; o < 16; ++o) sn += vsh[o] * vsh[o];
            float f = sn / ((1.f + sn) * sqrtf(sn + SQ_EPS));
            #pragma unroll
            for (int o = 0; o < 16; ++o) vsh[o] *= f;
        }
        __syncthreads();
        #pragma unroll
        for (int o = 0; o < 16; ++o) v[o] = vsh[o];
        if (it < 2) {
            #pragma unroll
            for (int k = 0; k < KMAX; ++k) {
                int r = tid + k * 256;
                if (r < R) {
                    float dot = 0.f;
                    #pragma unroll
                    for (int j = 0; j < 8; ++j) {
                        unsigned int w = pri[j * R + r];
                        dot += bf2f((unsigned short)(w & 0xffffu)) * v[2*j];
                        dot += bf2f((unsigned short)(w >> 16)) * v[2*j+1];
                    }
                    blog[k] += dot;
                }
            }
        }
    }
    if (tid == 0) {
        float sn = 0.f;
        #pragma unroll
        for (int o = 0; o < 16; ++o) sn += v[o] * v[o];
        lens[b * 10 + n] = sqrtf(sn + SQ_EPS);
    }
}

// ---------------- final: softmax over classes of l1+l2+l3 ----------------
__global__ void final_softmax_kernel(const float* __restrict__ l1, const float* __restrict__ l2,
                                     const float* __restrict__ l3, float* __restrict__ out) {
    int b = threadIdx.x;
    float v[10]; float mx = -1e30f;
    #pragma unroll
    for (int n = 0; n < 10; ++n) {
        v[n] = l1[b * 10 + n] + l2[b * 10 + n] + l3[b * 10 + n];
        mx = fmaxf(mx, v[n]);
    }
    float s = 0.f;
    #pragma unroll
    for (int n = 0; n < 10; ++n) { v[n] = expf(v[n] - mx); s += v[n]; }
    float inv = 1.f / s;
    #pragma unroll
    for (int n = 0; n < 10; ++n) out[b * 10 + n] = v[n] * inv;
}

extern "C" void kernel_launch(void* const* d_in, const int* in_sizes, int n_in,
                              void* d_out, int out_size, void* d_ws, size_t ws_size,
                              hipStream_t stream) {
    const float* x   = (const float*)d_in[0];
    const float* c1w = (const float*)d_in[1];
    const float* c1b = (const float*)d_in[2];
    const float* p1w = (const float*)d_in[3];
    const float* p1b = (const float*)d_in[4];
    const float* d1w = (const float*)d_in[5];
    const float* c2w = (const float*)d_in[6];
    const float* c2b = (const float*)d_in[7];
    const float* p2w = (const float*)d_in[8];
    const float* p2b = (const float*)d_in[9];
    const float* d2w = (const float*)d_in[10];
    const float* c3w = (const float*)d_in[11];
    const float* c3b = (const float*)d_in[12];
    const float* p3w = (const float*)d_in[13];
    const float* p3b = (const float*)d_in[14];
    const float* d3w = (const float*)d_in[15];

    float* ws = (float*)d_ws;
    // region layout (float units) — total 23,403,520 floats = 93.6 MB
    float* x2    = ws + 0;          // 50176
    float* x1    = ws + 50176;      // 12544
    float* yh1f  = ws + 62720;      // 409600   (819200 halves)  [aliased by u1 later]
    float* yl1f  = ws + 472320;     // 409600
    float* yh2f  = ws + 881920;     // 1638400  [aliased by u2 later]
    float* yl2f  = ws + 2520320;    // 1638400
    float* yh3f  = ws + 4158720;    // 6553600  [aliased by u3 later]
    float* yl3f  = ws + 10712320;   // 6553600  [aliased by rwb after gemm3]
    float* wh1f  = ws + 17265920;   // 147456
    float* wl1f  = ws + 17413376;   // 147456
    float* wh2f  = ws + 17560832;   // 409600
    float* wl2f  = ws + 17970432;   // 409600
    float* wh3f  = ws + 18380032;   // 1327104  [aliased by p2 later]
    float* wl3f  = ws + 19707136;   // 1327104  [aliased by p1 later]
    float* p3    = ws + 21034240;   // 2359296
    float* bnp1  = ws + 23393536;   // 512 (x3: bnp2, bnp3 follow)
    float* bias1 = ws + 23395072;   // 256
    float* bias2 = ws + 23395328;   // 256
    float* bias3 = ws + 23395584;   // 256
    float* l1    = ws + 23395840;   // 2560
    float* l2    = ws + 23398400;   // 2560
    float* l3    = ws + 23400960;   // 2560

    ushort_t* yh1 = (ushort_t*)yh1f; ushort_t* yl1 = (ushort_t*)yl1f;
    ushort_t* yh2 = (ushort_t*)yh2f; ushort_t* yl2 = (ushort_t*)yl2f;
    ushort_t* yh3 = (ushort_t*)yh3f; ushort_t* yl3 = (ushort_t*)yl3f;
    ushort_t* wh1 = (ushort_t*)wh1f; ushort_t* wl1 = (ushort_t*)wl1f;
    ushort_t* wh2 = (ushort_t*)wh2f; ushort_t* wl2 = (ushort_t*)wl2f;
    ushort_t* wh3 = (ushort_t*)wh3f; ushort_t* wl3 = (ushort_t*)wl3f;
    // aliases (safe by stream ordering):
    float* u1 = yh1f;   // written after gemm1 reads yh1
    float* u2 = yh2f;
    float* u3 = yh3f;
    float* p2 = wh3f;   // written after gemm3 reads wh3
    float* p1 = wl3f;
    // bf16 routing weights live in dead yl3 region (converted after gemm3):
    ushort_t* rwb1 = (ushort_t*)yl3f;          // 163840 halves
    ushort_t* rwb2 = rwb1 + 163840;            // 368640 halves
    ushort_t* rwb3 = rwb2 + 368640;            // 1474560 halves (total 2,007,040 <= 13,107,200)

    pool_kernel<<<256, 256, 0, stream>>>(x, x2, x1, bnp1);

    conv_split_kernel<7, 7, 3, 5, 5><<<256, 256, 0, stream>>>(x1, c1w, c1b, yh1, yl1, bnp1);
    conv_split_kernel<14, 14, 5, 10, 10><<<256, 256, 0, stream>>>(x2, c2w, c2b, yh2, yl2, bnp1 + 512);
    conv_split_kernel<28, 28, 9, 20, 20><<<256, 256, 0, stream>>>(x, c3w, c3b, yh3, yl3, bnp1 + 1024);

    bn_final_kernel<<<3, 128, 0, stream>>>(bnp1);

    wtrans_all_kernel<<<14720, 256, 0, stream>>>(p1w, p2w, p3w, bnp1,
                                                 wh1, wl1, wh2, wl2, wh3, wl3);
    biasfold_all_kernel<<<768, 128, 0, stream>>>(p1w, p2w, p3w, bnp1,
                                                 p1b, p2b, p3b, bias1, bias2, bias3);

    // gemm3 first: afterwards wh3/wl3 are dead (reused for p2/p1) and yl3 is dead (reused for rwb)
    prim_gemm_mfma<36, 6, 20, 20, 9><<<dim3(144, 4), 256, 0, stream>>>(yh3, yl3, wh3, wl3, bias3, p3);
    rwtrans_kernel<<<7840, 256, 0, stream>>>(d1w, d2w, d3w, rwb1, rwb2, rwb3);
    prim_gemm_mfma<9, 3, 10, 10, 5><<<dim3(36, 4), 256, 0, stream>>>(yh2, yl2, wh2, wl2, bias2, p2);
    prim_gemm_mfma<4, 2, 5, 5, 3><<<dim3(16, 4), 256, 0, stream>>>(yh1, yl1, wh1, wl1, bias1, p1);

    squash_all_kernel<<<1568, 256, 0, stream>>>(p1, p2, p3, u1, u2, u3);

    routing_lds_kernel<128><<<dim3(10, 256), 256, 0, stream>>>(u1, rwb1, l1);
    routing_lds_kernel<288><<<dim3(10, 256), 256, 0, stream>>>(u2, rwb2, l2);
    routing_lds_kernel<1152><<<dim3(10, 256), 256, 0, stream>>>(u3, rwb3, l3);

    final_softmax_kernel<<<1, 256, 0, stream>>>(l1, l2, l3, (float*)d_out);
}

// Round 8
// 720.150 us; speedup vs baseline: 1.8250x; 1.1209x over previous
//
#include <hip/hip_runtime.h>
#include <math.h>

#define SQ_EPS 1e-12f
#define BN_EPS 1e-5f

typedef short short8 __attribute__((ext_vector_type(8)));
typedef float f32x4 __attribute__((ext_vector_type(4)));
typedef unsigned short ushort_t;

__device__ inline unsigned short f2bf(float x) {
    unsigned int u = __float_as_uint(x);
    unsigned int r = (u + 0x7fffu + ((u >> 16) & 1u)) >> 16;   // round-to-nearest-even
    return (unsigned short)r;
}
__device__ inline float bf2f(unsigned short h) {
    return __uint_as_float(((unsigned int)h) << 16);
}

// ---------------- pooling: img(28x28) -> x2(14x14) -> x1(7x7); blocks 0-2 also zero bn accum ----------------
__global__ void pool_kernel(const float* __restrict__ img,
                            float* __restrict__ x2, float* __restrict__ x1,
                            float* __restrict__ bnp_base) {
    __shared__ float s_img[784];
    __shared__ float s_x2[196];
    int b = blockIdx.x;
    if (b < 3) {  // zero sum/sq accumulators for the 3 branches (ws is poisoned)
        bnp_base[b * 512 + threadIdx.x] = 0.f;
        bnp_base[b * 512 + 256 + threadIdx.x] = 0.f;
    }
    const float* im = img + b * 784;
    for (int i = threadIdx.x; i < 784; i += 256) s_img[i] = im[i];
    __syncthreads();
    for (int idx = threadIdx.x; idx < 196; idx += 256) {
        int i = idx / 14, j = idx % 14;
        float v = 0.25f * (s_img[(2*i)*28 + 2*j]     + s_img[(2*i)*28 + 2*j + 1] +
                           s_img[(2*i+1)*28 + 2*j]   + s_img[(2*i+1)*28 + 2*j + 1]);
        s_x2[idx] = v;
        x2[b*196 + idx] = v;
    }
    __syncthreads();
    for (int idx = threadIdx.x; idx < 49; idx += 256) {
        int i = idx / 7, j = idx % 7;
        float v = 0.25f * (s_x2[(2*i)*14 + 2*j]     + s_x2[(2*i)*14 + 2*j + 1] +
                           s_x2[(2*i+1)*14 + 2*j]   + s_x2[(2*i+1)*14 + 2*j + 1]);
        x1[b*49 + idx] = v;
    }
}

// ---------------- conv (1->128ch, stride1, VALID) + relu, split-bf16 out [b][pos][c], BN stats ----------------
template<int IH, int IW, int KS, int OH, int OW>
__global__ __launch_bounds__(256) void conv_split_kernel(
        const float* __restrict__ in, const float* __restrict__ w,
        const float* __restrict__ bias,
        ushort_t* __restrict__ yh, ushort_t* __restrict__ yl,
        float* __restrict__ bnp) {
    constexpr int KK = KS * KS;
    constexpr int OS = OH * OW;
    __shared__ float s_img[IH * IW];
    __shared__ float s_w[128 * KK];
    __shared__ float s_red[256];
    int b = blockIdx.x, tid = threadIdx.x;
    const float* ip = in + b * IH * IW;
    for (int i = tid; i < IH * IW; i += 256) s_img[i] = ip[i];
    for (int i = tid; i < 128 * KK; i += 256) s_w[i] = w[i];
    __syncthreads();
    int c = tid & 127, half = tid >> 7;
    float bias_c = bias[c];
    float bsum = 0.f, bsq = 0.f;
    for (int r = half; r < OH; r += 2) {
        float acc[OW];
        #pragma unroll
        for (int j = 0; j < OW; ++j) acc[j] = bias_c;
        for (int u = 0; u < KS; ++u) {
            float rg[OW + KS - 1];
            #pragma unroll
            for (int j = 0; j < OW + KS - 1; ++j) rg[j] = s_img[(r + u) * IW + j];
            #pragma unroll
            for (int v = 0; v < KS; ++v) {
                float wv = s_w[c * KK + u * KS + v];
                #pragma unroll
                for (int j = 0; j < OW; ++j) acc[j] += wv * rg[j + v];
            }
        }
        #pragma unroll
        for (int j = 0; j < OW; ++j) {
            float val = fmaxf(acc[j], 0.f);
            bsum += val; bsq += val * val;
            unsigned short h = f2bf(val);
            unsigned short lo = f2bf(val - bf2f(h));
            int oidx = ((b * OS) + r * OW + j) * 128 + c;
            yh[oidx] = h; yl[oidx] = lo;
        }
    }
    s_red[tid] = bsum; __syncthreads();
    if (tid < 128) atomicAdd(&bnp[c], s_red[tid] + s_red[tid + 128]);
    __syncthreads();
    s_red[tid] = bsq; __syncthreads();
    if (tid < 128) atomicAdd(&bnp[128 + c], s_red[tid] + s_red[tid + 128]);
}

// ---------------- finalize BN: scale/shift per channel, 3 branches ----------------
__global__ void bn_final_kernel(float* __restrict__ bnp_base) {
    int br = blockIdx.x;
    float* bnp = bnp_base + br * 512;
    float N = (br == 0) ? 6400.f : ((br == 1) ? 25600.f : 102400.f);
    int c = threadIdx.x;  // 128
    float mean = bnp[c] / N;
    float var = bnp[128 + c] / N - mean * mean;
    float inv = rsqrtf(var + BN_EPS);
    bnp[256 + c] = inv;
    bnp[384 + c] = -mean * inv;
}

// ---------------- weight transform (all branches): W[ch][c][uv]*scale_c -> split bf16 [uv][ch][c] ----------------
__global__ void wtrans_all_kernel(const float* __restrict__ w1, const float* __restrict__ w2,
                                  const float* __restrict__ w3, const float* __restrict__ bnp_base,
                                  ushort_t* __restrict__ wh1, ushort_t* __restrict__ wl1,
                                  ushort_t* __restrict__ wh2, ushort_t* __restrict__ wl2,
                                  ushort_t* __restrict__ wh3, ushort_t* __restrict__ wl3) {
    int blk = blockIdx.x;
    const float* w; const float* bnp; ushort_t* wh; ushort_t* wl; int KK;
    if (blk < 1152)      { w = w1; bnp = bnp_base;        wh = wh1; wl = wl1; KK = 9;  }
    else if (blk < 4352) { w = w2; bnp = bnp_base + 512;  wh = wh2; wl = wl2; KK = 25; blk -= 1152; }
    else                 { w = w3; bnp = bnp_base + 1024; wh = wh3; wl = wl3; KK = 81; blk -= 4352; }
    int idx = blk * 256 + threadIdx.x;
    int c = idx & 127, ch = (idx >> 7) & 255, uv = idx >> 15;
    float val = w[((ch << 7) + c) * KK + uv] * bnp[256 + c];
    unsigned short h = f2bf(val);
    unsigned short lo = f2bf(val - bf2f(h));
    wh[idx] = h; wl[idx] = lo;
}

// ---------------- fold BN shift into per-channel bias (all branches) ----------------
__global__ void biasfold_all_kernel(const float* __restrict__ w1, const float* __restrict__ w2,
                                    const float* __restrict__ w3, const float* __restrict__ bnp_base,
                                    const float* __restrict__ pb1, const float* __restrict__ pb2,
                                    const float* __restrict__ pb3,
                                    float* __restrict__ b1, float* __restrict__ b2, float* __restrict__ b3) {
    int br = blockIdx.x >> 8, ch = blockIdx.x & 255, tid = threadIdx.x;  // 128 threads, c = tid
    const float* w  = (br == 0) ? w1  : (br == 1) ? w2  : w3;
    const float* pb = (br == 0) ? pb1 : (br == 1) ? pb2 : pb3;
    float* bf       = (br == 0) ? b1  : (br == 1) ? b2  : b3;
    int KK          = (br == 0) ? 9   : (br == 1) ? 25  : 81;
    const float* bnp = bnp_base + br * 512;
    const float* wrow = w + (ch * 128 + tid) * KK;
    float s = 0.f;
    for (int uv = 0; uv < KK; ++uv) s += wrow[uv];
    s *= bnp[384 + tid];
    for (int off = 32; off; off >>= 1) s += __shfl_down(s, off);
    __shared__ float r2[2];
    if ((tid & 63) == 0) r2[tid >> 6] = s;
    __syncthreads();
    if (tid == 0) bf[ch] = pb[ch] + r2[0] + r2[1];
}

// ---------------- zero kernels for split-K accumulators ----------------
__global__ void zero_p3_kernel(float* __restrict__ p3) {
    ((float4*)p3)[blockIdx.x * 256 + threadIdx.x] = (float4){0.f, 0.f, 0.f, 0.f};
}
__global__ void zero_p21_kernel(float* __restrict__ p2, float* __restrict__ p1) {
    int blk = blockIdx.x;
    if (blk < 576) ((float4*)p2)[blk * 256 + threadIdx.x] = (float4){0.f, 0.f, 0.f, 0.f};
    else           ((float4*)p1)[(blk - 576) * 256 + threadIdx.x] = (float4){0.f, 0.f, 0.f, 0.f};
}

// ---------------- primary-caps conv as split-bf16 MFMA GEMM, split-K x2 via atomicAdd ----------------
// 64x64 block tile, 4 waves as 2x2 (each 32x32 = 2x2 of 16x16), BK=32.
// LDS: pitch 32 halves, XOR swizzle chunk^=((row>>1)&3): writes AND reads both 2-lane/bank-window (free).
// Register prefetch of next k-chunk across the MFMA barrier.
template<int S, int WO, int IHg, int IWg, int KS>
__global__ __launch_bounds__(256, 4) void prim_gemm_mfma(
        const ushort_t* __restrict__ yh, const ushort_t* __restrict__ yl,
        const ushort_t* __restrict__ wh, const ushort_t* __restrict__ wl,
        float* __restrict__ p) {
    constexpr int KKTOT = KS * KS * 4;     // flat k-chunks of 32
    constexpr int HALF = KKTOT / 2;
    __shared__ ushort_t Ash[64 * 32], Asl[64 * 32];
    __shared__ ushort_t Bsh[64 * 32], Bsl[64 * 32];
    int tid = threadIdx.x;
    int bm = blockIdx.x * 64, ch0 = blockIdx.y * 64;
    int kk0 = blockIdx.z * HALF, kk1 = kk0 + HALF;
    // staging roles: row = tid>>2 (0..63), chunk = tid&3 (8 halves each), swizzled
    int arow = tid >> 2;
    int cch = tid & 3;
    int wL = arow * 32 + (cch ^ ((arow >> 1) & 3)) * 8;
    int cpart = cch * 8;
    int m0 = bm + arow;
    int b0 = m0 / S, s0 = m0 % S;
    int abase = ((b0 * IHg + 2 * (s0 / WO)) * IWg + 2 * (s0 % WO)) * 128 + cpart;
    int bbase = (ch0 + arow) * 128 + cpart;
    // compute roles
    int lane = tid & 63, wid = tid >> 6;
    int wm = wid & 1, wn = wid >> 1;
    int quad = lane >> 4, l16 = lane & 15;
    int rsw = (quad ^ ((l16 >> 1) & 3)) * 8;
    int aoffL[2], boffL[2];
    #pragma unroll
    for (int mi = 0; mi < 2; ++mi) aoffL[mi] = (wm * 32 + mi * 16 + l16) * 32 + rsw;
    #pragma unroll
    for (int ni = 0; ni < 2; ++ni) boffL[ni] = (wn * 32 + ni * 16 + l16) * 32 + rsw;
    f32x4 acc[2][2];
    #pragma unroll
    for (int mi = 0; mi < 2; ++mi)
        #pragma unroll
        for (int ni = 0; ni < 2; ++ni)
            acc[mi][ni] = (f32x4){0.f, 0.f, 0.f, 0.f};

    // prefetch first chunk
    int uv0 = kk0 >> 2, cs0 = (kk0 & 3) << 5;
    int ai = abase + ((uv0 / KS) * IWg + (uv0 % KS)) * 128 + cs0;
    int bi = bbase + uv0 * 32768 + cs0;
    int4 a4h = *reinterpret_cast<const int4*>(yh + ai);
    int4 a4l = *reinterpret_cast<const int4*>(yl + ai);
    int4 b4h = *reinterpret_cast<const int4*>(wh + bi);
    int4 b4l = *reinterpret_cast<const int4*>(wl + bi);

    for (int kk = kk0; kk < kk1; ++kk) {
        __syncthreads();
        *reinterpret_cast<int4*>(&Ash[wL]) = a4h;
        *reinterpret_cast<int4*>(&Asl[wL]) = a4l;
        *reinterpret_cast<int4*>(&Bsh[wL]) = b4h;
        *reinterpret_cast<int4*>(&Bsl[wL]) = b4l;
        if (kk + 1 < kk1) {   // prefetch next chunk (uniform branch)
            int uv = (kk + 1) >> 2, cs = ((kk + 1) & 3) << 5;
            int ai2 = abase + ((uv / KS) * IWg + (uv % KS)) * 128 + cs;
            int bi2 = bbase + uv * 32768 + cs;
            a4h = *reinterpret_cast<const int4*>(yh + ai2);
            a4l = *reinterpret_cast<const int4*>(yl + ai2);
            b4h = *reinterpret_cast<const int4*>(wh + bi2);
            b4l = *reinterpret_cast<const int4*>(wl + bi2);
        }
        __syncthreads();
        short8 ah[2], al[2], bh[2], bl[2];
        #pragma unroll
        for (int mi = 0; mi < 2; ++mi) {
            ah[mi] = *reinterpret_cast<const short8*>(&Ash[aoffL[mi]]);
            al[mi] = *reinterpret_cast<const short8*>(&Asl[aoffL[mi]]);
        }
        #pragma unroll
        for (int ni = 0; ni < 2; ++ni) {
            bh[ni] = *reinterpret_cast<const short8*>(&Bsh[boffL[ni]]);
            bl[ni] = *reinterpret_cast<const short8*>(&Bsl[boffL[ni]]);
        }
        #pragma unroll
        for (int mi = 0; mi < 2; ++mi)
            #pragma unroll
            for (int ni = 0; ni < 2; ++ni) {
                acc[mi][ni] = __builtin_amdgcn_mfma_f32_16x16x32_bf16(ah[mi], bh[ni], acc[mi][ni], 0, 0, 0);
                acc[mi][ni] = __builtin_amdgcn_mfma_f32_16x16x32_bf16(al[mi], bh[ni], acc[mi][ni], 0, 0, 0);
                acc[mi][ni] = __builtin_amdgcn_mfma_f32_16x16x32_bf16(ah[mi], bl[ni], acc[mi][ni], 0, 0, 0);
            }
    }
    #pragma unroll
    for (int mi = 0; mi < 2; ++mi)
        #pragma unroll
        for (int ni = 0; ni < 2; ++ni) {
            int col = ch0 + wn * 32 + ni * 16 + l16;
            #pragma unroll
            for (int reg = 0; reg < 4; ++reg) {
                int row = bm + wm * 32 + mi * 16 + quad * 4 + reg;
                atomicAdd(p + (size_t)row * 256 + col, acc[mi][ni][reg]);
            }
        }
}

// ---------------- squash primary caps (all branches): p(B*S,256)+bias -> u(B,32*S,8) ----------------
__global__ void squash_all_kernel(const float* __restrict__ p1, const float* __restrict__ p2,
                                  const float* __restrict__ p3,
                                  const float* __restrict__ bias1, const float* __restrict__ bias2,
                                  const float* __restrict__ bias3,
                                  float* __restrict__ u1, float* __restrict__ u2,
                                  float* __restrict__ u3) {
    int blk = blockIdx.x;
    const float* p; const float* bias; float* u; int S;
    if (blk < 128)      { p = p1; bias = bias1; u = u1; S = 4; }
    else if (blk < 416) { p = p2; bias = bias2; u = u2; S = 9;  blk -= 128; }
    else                { p = p3; bias = bias3; u = u3; S = 36; blk -= 416; }
    int idx = blk * 256 + threadIdx.x;   // over 256*S*32, o innermost
    int o = idx & 31, rest = idx >> 5;
    int s = rest % S, b = rest / S;
    const float* pp = p + (size_t)(b * S + s) * 256 + o;
    float t[8]; float sn = 0.f;
    #pragma unroll
    for (int i = 0; i < 8; ++i) { t[i] = pp[i * 32] + bias[o + i * 32]; sn += t[i] * t[i]; }
    float f = sn / ((1.f + sn) * sqrtf(sn + SQ_EPS));
    float* up = u + (size_t)(b * (32 * S) + o * S + s) * 8;
    float4 w0 = {t[0] * f, t[1] * f, t[2] * f, t[3] * f};
    float4 w1 = {t[4] * f, t[5] * f, t[6] * f, t[7] * f};
    *reinterpret_cast<float4*>(up) = w0;
    *reinterpret_cast<float4*>(up + 4) = w1;
}

// ---------------- routing weights -> bf16 (after gemm3 frees yl3 region) ----------------
__global__ void rwtrans_kernel(const float* __restrict__ w1, const float* __restrict__ w2,
                               const float* __restrict__ w3,
                               ushort_t* __restrict__ o1, ushort_t* __restrict__ o2,
                               ushort_t* __restrict__ o3) {
    int idx = blockIdx.x * 256 + threadIdx.x;  // 7840*256 = 2,007,040 exact
    const float* src; ushort_t* dst; int off;
    if (idx < 163840)      { src = w1; dst = o1; off = idx; }
    else if (idx < 532480) { src = w2; dst = o2; off = idx - 163840; }
    else                   { src = w3; dst = o3; off = idx - 532480; }
    dst[off] = f2bf(src[off]);
}

// ---------------- dynamic routing (3 iters): priors packed bf16x2 in LDS (transposed, conflict-free),
//                  blog in registers, weights bf16 (slab fits per-XCD L2) ----------------
template<int R>
__global__ __launch_bounds__(256, 4) void routing_lds_kernel(
        const float* __restrict__ u, const ushort_t* __restrict__ rwb,
        float* __restrict__ lens) {
    constexpr int KMAX = (R + 255) / 256;
    int n = blockIdx.x, b = blockIdx.y;
    int tid = threadIdx.x, lane = tid & 63, wv = tid >> 6;
    __shared__ unsigned int pri[8 * R];   // pri[j*R + r] = bf16(po[2j]) | bf16(po[2j+1])<<16
    __shared__ float red[4 * 16];
    __shared__ float vsh[16];
    __shared__ float sred[4];
    float blog[KMAX];
    #pragma unroll
    for (int k = 0; k < KMAX; ++k) {
        blog[k] = 0.f;
        int r = tid + k * 256;
        if (r < R) {
            const float4* up = (const float4*)(u + ((size_t)b * R + r) * 8);
            float4 ua = up[0], ub2 = up[1];
            float uu[8] = {ua.x, ua.y, ua.z, ua.w, ub2.x, ub2.y, ub2.z, ub2.w};
            const ushort_t* wr = rwb + ((size_t)n * R + r) * 128;
            float po[16] = {};
            #pragma unroll
            for (int i = 0; i < 8; ++i) {
                short8 wa = *reinterpret_cast<const short8*>(wr + i * 16);
                short8 wb = *reinterpret_cast<const short8*>(wr + i * 16 + 8);
                #pragma unroll
                for (int o = 0; o < 8; ++o) po[o]     += uu[i] * bf2f((unsigned short)wa[o]);
                #pragma unroll
                for (int o = 0; o < 8; ++o) po[8 + o] += uu[i] * bf2f((unsigned short)wb[o]);
            }
            #pragma unroll
            for (int j = 0; j < 8; ++j)
                pri[j * R + r] = (unsigned int)f2bf(po[2*j]) | ((unsigned int)f2bf(po[2*j+1]) << 16);
        }
    }
    __syncthreads();
    float v[16];
    for (int it = 0; it < 3; ++it) {
        float lmax = -1e30f;
        #pragma unroll
        for (int k = 0; k < KMAX; ++k)
            if (tid + k * 256 < R) lmax = fmaxf(lmax, blog[k]);
        for (int off = 32; off; off >>= 1) lmax = fmaxf(lmax, __shfl_down(lmax, off));
        if (lane == 0) sred[wv] = lmax;
        __syncthreads();
        float mx = fmaxf(fmaxf(sred[0], sred[1]), fmaxf(sred[2], sred[3]));
        __syncthreads();
        float ce[KMAX];
        float lsum = 0.f;
        #pragma unroll
        for (int k = 0; k < KMAX; ++k) {
            ce[k] = (tid + k * 256 < R) ? expf(blog[k] - mx) : 0.f;
            lsum += ce[k];
        }
        for (int off = 32; off; off >>= 1) lsum += __shfl_down(lsum, off);
        if (lane == 0) sred[wv] = lsum;
        __syncthreads();
        float inv = 1.f / (sred[0] + sred[1] + sred[2] + sred[3]);
        float sacc[16] = {};
        #pragma unroll
        for (int k = 0; k < KMAX; ++k) {
            int r = tid + k * 256;
            if (r < R) {
                float c = ce[k] * inv;
                #pragma unroll
                for (int j = 0; j < 8; ++j) {
                    unsigned int w = pri[j * R + r];
                    sacc[2*j]   += c * bf2f((unsigned short)(w & 0xffffu));
                    sacc[2*j+1] += c * bf2f((unsigned short)(w >> 16));
                }
            }
        }
        #pragma unroll
        for (int o = 0; o < 16; ++o) {
            float xv = sacc[o];
            for (int off = 32; off; off >>= 1) xv += __shfl_down(xv, off);
            if (lane == 0) red[wv * 16 + o] = xv;
        }
        __syncthreads();
        if (tid < 16) vsh[tid] = red[tid] + red[16 + tid] + red[32 + tid] + red[48 + tid];
        __syncthreads();
        if (tid == 0) {
            float sn = 0.f;
            #pragma unroll
            for (int o = 0; o < 16; ++o) sn += vsh[o] * vsh[o];
            float f = sn / ((1.f + sn) * sqrtf(sn + SQ_EPS));
            #pragma unroll
            for (int o = 0; o < 16; ++o) vsh[o] *= f;
        }
        __syncthreads();
        #pragma unroll
        for (int o = 0; o < 16; ++o) v[o] = vsh[o];
        if (it < 2) {
            #pragma unroll
            for (int k = 0; k < KMAX; ++k) {
                int r = tid + k * 256;
                if (r < R) {
                    float dot = 0.f;
                    #pragma unroll
                    for (int j = 0; j < 8; ++j) {
                        unsigned int w = pri[j * R + r];
                        dot += bf2f((unsigned short)(w & 0xffffu)) * v[2*j];
                        dot += bf2f((unsigned short)(w >> 16)) * v[2*j+1];
                    }
                    blog[k] += dot;
                }
            }
        }
    }
    if (tid == 0) {
        float sn = 0.f;
        #pragma unroll
        for (int o = 0; o < 16; ++o) sn += v[o] * v[o];
        lens[b * 10 + n] = sqrtf(sn + SQ_EPS);
    }
}

// ---------------- final: softmax over classes of l1+l2+l3 ----------------
__global__ void final_softmax_kernel(const float* __restrict__ l1, const float* __restrict__ l2,
                                     const float* __restrict__ l3, float* __restrict__ out) {
    int b = threadIdx.x;
    float v[10]; float mx = -1e30f;
    #pragma unroll
    for (int n = 0; n < 10; ++n) {
        v[n] = l1[b * 10 + n] + l2[b * 10 + n] + l3[b * 10 + n];
        mx = fmaxf(mx, v[n]);
    }
    float s = 0.f;
    #pragma unroll
    for (int n = 0; n < 10; ++n) { v[n] = expf(v[n] - mx); s += v[n]; }
    float inv = 1.f / s;
    #pragma unroll
    for (int n = 0; n < 10; ++n) out[b * 10 + n] = v[n] * inv;
}

extern "C" void kernel_launch(void* const* d_in, const int* in_sizes, int n_in,
                              void* d_out, int out_size, void* d_ws, size_t ws_size,
                              hipStream_t stream) {
    const float* x   = (const float*)d_in[0];
    const float* c1w = (const float*)d_in[1];
    const float* c1b = (const float*)d_in[2];
    const float* p1w = (const float*)d_in[3];
    const float* p1b = (const float*)d_in[4];
    const float* d1w = (const float*)d_in[5];
    const float* c2w = (const float*)d_in[6];
    const float* c2b = (const float*)d_in[7];
    const float* p2w = (const float*)d_in[8];
    const float* p2b = (const float*)d_in[9];
    const float* d2w = (const float*)d_in[10];
    const float* c3w = (const float*)d_in[11];
    const float* c3b = (const float*)d_in[12];
    const float* p3w = (const float*)d_in[13];
    const float* p3b = (const float*)d_in[14];
    const float* d3w = (const float*)d_in[15];

    float* ws = (float*)d_ws;
    // region layout (float units) — total 23,403,520 floats = 93.6 MB
    float* x2    = ws + 0;          // 50176
    float* x1    = ws + 50176;      // 12544
    float* yh1f  = ws + 62720;      // 409600   (819200 halves)  [aliased by u1 later]
    float* yl1f  = ws + 472320;     // 409600
    float* yh2f  = ws + 881920;     // 1638400  [aliased by u2 later]
    float* yl2f  = ws + 2520320;    // 1638400
    float* yh3f  = ws + 4158720;    // 6553600  [aliased by u3 later]
    float* yl3f  = ws + 10712320;   // 6553600  [aliased by rwb after gemm3]
    float* wh1f  = ws + 17265920;   // 147456
    float* wl1f  = ws + 17413376;   // 147456
    float* wh2f  = ws + 17560832;   // 409600
    float* wl2f  = ws + 17970432;   // 409600
    float* wh3f  = ws + 18380032;   // 1327104  [aliased by p2 later]
    float* wl3f  = ws + 19707136;   // 1327104  [aliased by p1 later]
    float* p3    = ws + 21034240;   // 2359296
    float* bnp1  = ws + 23393536;   // 512 (x3: bnp2, bnp3 follow)
    float* bias1 = ws + 23395072;   // 256
    float* bias2 = ws + 23395328;   // 256
    float* bias3 = ws + 23395584;   // 256
    float* l1    = ws + 23395840;   // 2560
    float* l2    = ws + 23398400;   // 2560
    float* l3    = ws + 23400960;   // 2560

    ushort_t* yh1 = (ushort_t*)yh1f; ushort_t* yl1 = (ushort_t*)yl1f;
    ushort_t* yh2 = (ushort_t*)yh2f; ushort_t* yl2 = (ushort_t*)yl2f;
    ushort_t* yh3 = (ushort_t*)yh3f; ushort_t* yl3 = (ushort_t*)yl3f;
    ushort_t* wh1 = (ushort_t*)wh1f; ushort_t* wl1 = (ushort_t*)wl1f;
    ushort_t* wh2 = (ushort_t*)wh2f; ushort_t* wl2 = (ushort_t*)wl2f;
    ushort_t* wh3 = (ushort_t*)wh3f; ushort_t* wl3 = (ushort_t*)wl3f;
    // aliases (safe by stream ordering):
    float* u1 = yh1f;   // written after gemm1 reads yh1
    float* u2 = yh2f;
    float* u3 = yh3f;
    float* p2 = wh3f;   // written (zero+atomic) after gemm3 reads wh3
    float* p1 = wl3f;
    // bf16 routing weights live in dead yl3 region (converted after gemm3):
    ushort_t* rwb1 = (ushort_t*)yl3f;          // 163840 halves
    ushort_t* rwb2 = rwb1 + 163840;            // 368640 halves
    ushort_t* rwb3 = rwb2 + 368640;            // 1474560 halves (total 2,007,040 <= 13,107,200)

    pool_kernel<<<256, 256, 0, stream>>>(x, x2, x1, bnp1);

    conv_split_kernel<7, 7, 3, 5, 5><<<256, 256, 0, stream>>>(x1, c1w, c1b, yh1, yl1, bnp1);
    conv_split_kernel<14, 14, 5, 10, 10><<<256, 256, 0, stream>>>(x2, c2w, c2b, yh2, yl2, bnp1 + 512);
    conv_split_kernel<28, 28, 9, 20, 20><<<256, 256, 0, stream>>>(x, c3w, c3b, yh3, yl3, bnp1 + 1024);

    bn_final_kernel<<<3, 128, 0, stream>>>(bnp1);

    wtrans_all_kernel<<<14720, 256, 0, stream>>>(p1w, p2w, p3w, bnp1,
                                                 wh1, wl1, wh2, wl2, wh3, wl3);
    biasfold_all_kernel<<<768, 128, 0, stream>>>(p1w, p2w, p3w, bnp1,
                                                 p1b, p2b, p3b, bias1, bias2, bias3);

    // gemm3 (split-K x2, atomic) first: afterwards wh3/wl3 dead (reused for p2/p1), yl3 dead (rwb)
    zero_p3_kernel<<<2304, 256, 0, stream>>>(p3);
    prim_gemm_mfma<36, 6, 20, 20, 9><<<dim3(144, 4, 2), 256, 0, stream>>>(yh3, yl3, wh3, wl3, p3);
    rwtrans_kernel<<<7840, 256, 0, stream>>>(d1w, d2w, d3w, rwb1, rwb2, rwb3);
    zero_p21_kernel<<<832, 256, 0, stream>>>(p2, p1);
    prim_gemm_mfma<9, 3, 10, 10, 5><<<dim3(36, 4, 2), 256, 0, stream>>>(yh2, yl2, wh2, wl2, p2);
    prim_gemm_mfma<4, 2, 5, 5, 3><<<dim3(16, 4, 2), 256, 0, stream>>>(yh1, yl1, wh1, wl1, p1);

    squash_all_kernel<<<1568, 256, 0, stream>>>(p1, p2, p3, bias1, bias2, bias3, u1, u2, u3);

    routing_lds_kernel<128><<<dim3(10, 256), 256, 0, stream>>>(u1, rwb1, l1);
    routing_lds_kernel<288><<<dim3(10, 256), 256, 0, stream>>>(u2, rwb2, l2);
    routing_lds_kernel<1152><<<dim3(10, 256), 256, 0, stream>>>(u3, rwb3, l3);

    final_softmax_kernel<<<1, 256, 0, stream>>>(l1, l2, l3, (float*)d_out);
}

// Round 9
// 716.244 us; speedup vs baseline: 1.8349x; 1.0055x over previous
//
#include <hip/hip_runtime.h>
#include <math.h>

#define SQ_EPS 1e-12f
#define BN_EPS 1e-5f

typedef short short8 __attribute__((ext_vector_type(8)));
typedef float f32x4 __attribute__((ext_vector_type(4)));
typedef float f32x16 __attribute__((ext_vector_type(16)));
typedef unsigned short ushort_t;

__device__ inline unsigned short f2bf(float x) {
    unsigned int u = __float_as_uint(x);
    unsigned int r = (u + 0x7fffu + ((u >> 16) & 1u)) >> 16;   // round-to-nearest-even
    return (unsigned short)r;
}
__device__ inline float bf2f(unsigned short h) {
    return __uint_as_float(((unsigned int)h) << 16);
}

// ---------------- pooling: img(28x28) -> x2(14x14) -> x1(7x7); blocks 0-2 also zero bn accum ----------------
__global__ void pool_kernel(const float* __restrict__ img,
                            float* __restrict__ x2, float* __restrict__ x1,
                            float* __restrict__ bnp_base) {
    __shared__ float s_img[784];
    __shared__ float s_x2[196];
    int b = blockIdx.x;
    if (b < 3) {  // zero sum/sq accumulators for the 3 branches (ws is poisoned)
        bnp_base[b * 512 + threadIdx.x] = 0.f;
        bnp_base[b * 512 + 256 + threadIdx.x] = 0.f;
    }
    const float* im = img + b * 784;
    for (int i = threadIdx.x; i < 784; i += 256) s_img[i] = im[i];
    __syncthreads();
    for (int idx = threadIdx.x; idx < 196; idx += 256) {
        int i = idx / 14, j = idx % 14;
        float v = 0.25f * (s_img[(2*i)*28 + 2*j]     + s_img[(2*i)*28 + 2*j + 1] +
                           s_img[(2*i+1)*28 + 2*j]   + s_img[(2*i+1)*28 + 2*j + 1]);
        s_x2[idx] = v;
        x2[b*196 + idx] = v;
    }
    __syncthreads();
    for (int idx = threadIdx.x; idx < 49; idx += 256) {
        int i = idx / 7, j = idx % 7;
        float v = 0.25f * (s_x2[(2*i)*14 + 2*j]     + s_x2[(2*i)*14 + 2*j + 1] +
                           s_x2[(2*i+1)*14 + 2*j]   + s_x2[(2*i+1)*14 + 2*j + 1]);
        x1[b*49 + idx] = v;
    }
}

// ---------------- conv (1->128ch, stride1, VALID) + relu, split-bf16 out [b][pos][c], BN stats ----------------
template<int IH, int IW, int KS, int OH, int OW>
__global__ __launch_bounds__(256) void conv_split_kernel(
        const float* __restrict__ in, const float* __restrict__ w,
        const float* __restrict__ bias,
        ushort_t* __restrict__ yh, ushort_t* __restrict__ yl,
        float* __restrict__ bnp) {
    constexpr int KK = KS * KS;
    constexpr int OS = OH * OW;
    __shared__ float s_img[IH * IW];
    __shared__ float s_w[128 * KK];
    __shared__ float s_red[256];
    int b = blockIdx.x, tid = threadIdx.x;
    const float* ip = in + b * IH * IW;
    for (int i = tid; i < IH * IW; i += 256) s_img[i] = ip[i];
    for (int i = tid; i < 128 * KK; i += 256) s_w[i] = w[i];
    __syncthreads();
    int c = tid & 127, half = tid >> 7;
    float bias_c = bias[c];
    float bsum = 0.f, bsq = 0.f;
    for (int r = half; r < OH; r += 2) {
        float acc[OW];
        #pragma unroll
        for (int j = 0; j < OW; ++j) acc[j] = bias_c;
        for (int u = 0; u < KS; ++u) {
            float rg[OW + KS - 1];
            #pragma unroll
            for (int j = 0; j < OW + KS - 1; ++j) rg[j] = s_img[(r + u) * IW + j];
            #pragma unroll
            for (int v = 0; v < KS; ++v) {
                float wv = s_w[c * KK + u * KS + v];
                #pragma unroll
                for (int j = 0; j < OW; ++j) acc[j] += wv * rg[j + v];
            }
        }
        #pragma unroll
        for (int j = 0; j < OW; ++j) {
            float val = fmaxf(acc[j], 0.f);
            bsum += val; bsq += val * val;
            unsigned short h = f2bf(val);
            unsigned short lo = f2bf(val - bf2f(h));
            int oidx = ((b * OS) + r * OW + j) * 128 + c;
            yh[oidx] = h; yl[oidx] = lo;
        }
    }
    s_red[tid] = bsum; __syncthreads();
    if (tid < 128) atomicAdd(&bnp[c], s_red[tid] + s_red[tid + 128]);
    __syncthreads();
    s_red[tid] = bsq; __syncthreads();
    if (tid < 128) atomicAdd(&bnp[128 + c], s_red[tid] + s_red[tid + 128]);
}

// ---------------- finalize BN: scale/shift per channel, 3 branches ----------------
__global__ void bn_final_kernel(float* __restrict__ bnp_base) {
    int br = blockIdx.x;
    float* bnp = bnp_base + br * 512;
    float N = (br == 0) ? 6400.f : ((br == 1) ? 25600.f : 102400.f);
    int c = threadIdx.x;  // 128
    float mean = bnp[c] / N;
    float var = bnp[128 + c] / N - mean * mean;
    float inv = rsqrtf(var + BN_EPS);
    bnp[256 + c] = inv;
    bnp[384 + c] = -mean * inv;
}

// ---------------- weight transform (all branches): W[ch][c][uv]*scale_c -> split bf16 [uv][ch][c] ----------------
__global__ void wtrans_all_kernel(const float* __restrict__ w1, const float* __restrict__ w2,
                                  const float* __restrict__ w3, const float* __restrict__ bnp_base,
                                  ushort_t* __restrict__ wh1, ushort_t* __restrict__ wl1,
                                  ushort_t* __restrict__ wh2, ushort_t* __restrict__ wl2,
                                  ushort_t* __restrict__ wh3, ushort_t* __restrict__ wl3) {
    int blk = blockIdx.x;
    const float* w; const float* bnp; ushort_t* wh; ushort_t* wl; int KK;
    if (blk < 1152)      { w = w1; bnp = bnp_base;        wh = wh1; wl = wl1; KK = 9;  }
    else if (blk < 4352) { w = w2; bnp = bnp_base + 512;  wh = wh2; wl = wl2; KK = 25; blk -= 1152; }
    else                 { w = w3; bnp = bnp_base + 1024; wh = wh3; wl = wl3; KK = 81; blk -= 4352; }
    int idx = blk * 256 + threadIdx.x;
    int c = idx & 127, ch = (idx >> 7) & 255, uv = idx >> 15;
    float val = w[((ch << 7) + c) * KK + uv] * bnp[256 + c];
    unsigned short h = f2bf(val);
    unsigned short lo = f2bf(val - bf2f(h));
    wh[idx] = h; wl[idx] = lo;
}

// ---------------- fold BN shift into per-channel bias (all branches) ----------------
__global__ void biasfold_all_kernel(const float* __restrict__ w1, const float* __restrict__ w2,
                                    const float* __restrict__ w3, const float* __restrict__ bnp_base,
                                    const float* __restrict__ pb1, const float* __restrict__ pb2,
                                    const float* __restrict__ pb3,
                                    float* __restrict__ b1, float* __restrict__ b2, float* __restrict__ b3) {
    int br = blockIdx.x >> 8, ch = blockIdx.x & 255, tid = threadIdx.x;  // 128 threads, c = tid
    const float* w  = (br == 0) ? w1  : (br == 1) ? w2  : w3;
    const float* pb = (br == 0) ? pb1 : (br == 1) ? pb2 : pb3;
    float* bf       = (br == 0) ? b1  : (br == 1) ? b2  : b3;
    int KK          = (br == 0) ? 9   : (br == 1) ? 25  : 81;
    const float* bnp = bnp_base + br * 512;
    const float* wrow = w + (ch * 128 + tid) * KK;
    float s = 0.f;
    for (int uv = 0; uv < KK; ++uv) s += wrow[uv];
    s *= bnp[384 + tid];
    for (int off = 32; off; off >>= 1) s += __shfl_down(s, off);
    __shared__ float r2[2];
    if ((tid & 63) == 0) r2[tid >> 6] = s;
    __syncthreads();
    if (tid == 0) bf[ch] = pb[ch] + r2[0] + r2[1];
}

// ---------------- zero kernels for split-K accumulators ----------------
__global__ void zero_p3_kernel(float* __restrict__ p3) {
    ((float4*)p3)[blockIdx.x * 256 + threadIdx.x] = (float4){0.f, 0.f, 0.f, 0.f};
}
__global__ void zero_p21_kernel(float* __restrict__ p2, float* __restrict__ p1) {
    int blk = blockIdx.x;
    if (blk < 576) ((float4*)p2)[blk * 256 + threadIdx.x] = (float4){0.f, 0.f, 0.f, 0.f};
    else           ((float4*)p1)[(blk - 576) * 256 + threadIdx.x] = (float4){0.f, 0.f, 0.f, 0.f};
}

// ---------------- primary-caps conv as split-bf16 MFMA GEMM, split-K x2 via atomicAdd ----------------
// 64x64 block tile, BK=64, 4 waves as 2x2; each wave one 32x32 output via mfma_f32_32x32x16_bf16.
// LDS pitch 64 halves (128B), XOR swizzle chunk^=(row&7): writes 2 lanes/bank, reads 2 lanes/bank (free).
// 8x int4 register prefetch of the next BK=64 chunk across the MFMA barrier.
template<int S, int WO, int IHg, int IWg, int KS>
__global__ __launch_bounds__(256, 4) void prim_gemm_mfma(
        const ushort_t* __restrict__ yh, const ushort_t* __restrict__ yl,
        const ushort_t* __restrict__ wh, const ushort_t* __restrict__ wl,
        float* __restrict__ p) {
    constexpr int ITER = KS * KS;   // BK=64 iterations per z-half (total 2*KS*KS)
    __shared__ ushort_t Ash[64 * 64], Asl[64 * 64];
    __shared__ ushort_t Bsh[64 * 64], Bsl[64 * 64];
    int tid = threadIdx.x;
    int bm = blockIdx.x * 64, ch0 = blockIdx.y * 64;
    // staging roles: row = tid>>2 (0..63), chunks c0 = tid&3 and c0+4 (8 halves each)
    int arow = tid >> 2;
    int c0 = tid & 3;
    int wL0 = arow * 64 + ((c0)     ^ (arow & 7)) * 8;
    int wL1 = arow * 64 + ((c0 + 4) ^ (arow & 7)) * 8;
    int m0 = bm + arow;
    int b0 = m0 / S, s0 = m0 % S;
    int arowbase = ((b0 * IHg + 2 * (s0 / WO)) * IWg + 2 * (s0 % WO)) * 128;
    int browbase = (ch0 + arow) * 128;
    // compute roles: 4 waves 2x2, each wave 32x32
    int lane = tid & 63, wid = tid >> 6;
    int wm = wid & 1, wn = wid >> 1;
    int r31 = lane & 31, khalf = lane >> 5;
    int arl = wm * 32 + r31;
    int brl = wn * 32 + r31;
    int aoffL[4], boffL[4];
    #pragma unroll
    for (int s = 0; s < 4; ++s) {
        aoffL[s] = arl * 64 + ((2 * s + khalf) ^ (arl & 7)) * 8;
        boffL[s] = brl * 64 + ((2 * s + khalf) ^ (brl & 7)) * 8;
    }
    f32x16 acc;
    #pragma unroll
    for (int i = 0; i < 16; ++i) acc[i] = 0.f;

    // flat-64 index: idx in [z*ITER, (z+1)*ITER); uv = idx>>1, h = idx&1
    int idx0 = blockIdx.z * ITER;
    int uv = idx0 >> 1, h = idx0 & 1;
    int u = uv / KS, v = uv - u * KS;
    int aoff = arowbase + (u * IWg + v) * 128 + h * 64 + c0 * 8;
    int boff = browbase + uv * 32768 + h * 64 + c0 * 8;
    int4 a0h = *reinterpret_cast<const int4*>(yh + aoff);
    int4 a1h = *reinterpret_cast<const int4*>(yh + aoff + 32);
    int4 a0l = *reinterpret_cast<const int4*>(yl + aoff);
    int4 a1l = *reinterpret_cast<const int4*>(yl + aoff + 32);
    int4 b0h = *reinterpret_cast<const int4*>(wh + boff);
    int4 b1h = *reinterpret_cast<const int4*>(wh + boff + 32);
    int4 b0l = *reinterpret_cast<const int4*>(wl + boff);
    int4 b1l = *reinterpret_cast<const int4*>(wl + boff + 32);

    for (int it = 0; it < ITER; ++it) {
        __syncthreads();
        *reinterpret_cast<int4*>(&Ash[wL0]) = a0h;
        *reinterpret_cast<int4*>(&Ash[wL1]) = a1h;
        *reinterpret_cast<int4*>(&Asl[wL0]) = a0l;
        *reinterpret_cast<int4*>(&Asl[wL1]) = a1l;
        *reinterpret_cast<int4*>(&Bsh[wL0]) = b0h;
        *reinterpret_cast<int4*>(&Bsh[wL1]) = b1h;
        *reinterpret_cast<int4*>(&Bsl[wL0]) = b0l;
        *reinterpret_cast<int4*>(&Bsl[wL1]) = b1l;
        if (it + 1 < ITER) {   // prefetch next BK=64 chunk (uniform branch)
            h ^= 1;
            if (h == 0) { ++uv; ++v; if (v == KS) { v = 0; ++u; } }
            aoff = arowbase + (u * IWg + v) * 128 + h * 64 + c0 * 8;
            boff = browbase + uv * 32768 + h * 64 + c0 * 8;
            a0h = *reinterpret_cast<const int4*>(yh + aoff);
            a1h = *reinterpret_cast<const int4*>(yh + aoff + 32);
            a0l = *reinterpret_cast<const int4*>(yl + aoff);
            a1l = *reinterpret_cast<const int4*>(yl + aoff + 32);
            b0h = *reinterpret_cast<const int4*>(wh + boff);
            b1h = *reinterpret_cast<const int4*>(wh + boff + 32);
            b0l = *reinterpret_cast<const int4*>(wl + boff);
            b1l = *reinterpret_cast<const int4*>(wl + boff + 32);
        }
        __syncthreads();
        #pragma unroll
        for (int s = 0; s < 4; ++s) {
            short8 fah = *reinterpret_cast<const short8*>(&Ash[aoffL[s]]);
            short8 fal = *reinterpret_cast<const short8*>(&Asl[aoffL[s]]);
            short8 fbh = *reinterpret_cast<const short8*>(&Bsh[boffL[s]]);
            short8 fbl = *reinterpret_cast<const short8*>(&Bsl[boffL[s]]);
            acc = __builtin_amdgcn_mfma_f32_32x32x16_bf16(fah, fbh, acc, 0, 0, 0);
            acc = __builtin_amdgcn_mfma_f32_32x32x16_bf16(fal, fbh, acc, 0, 0, 0);
            acc = __builtin_amdgcn_mfma_f32_32x32x16_bf16(fah, fbl, acc, 0, 0, 0);
        }
    }
    // C/D layout (measured m74/m101): col = lane&31, row = (reg&3) + 8*(reg>>2) + 4*(lane>>5)
    int col = ch0 + wn * 32 + r31;
    #pragma unroll
    for (int reg = 0; reg < 16; ++reg) {
        int row = bm + wm * 32 + (reg & 3) + 8 * (reg >> 2) + 4 * khalf;
        atomicAdd(p + (size_t)row * 256 + col, acc[reg]);
    }
}

// ---------------- squash primary caps (all branches): p(B*S,256)+bias -> u(B,32*S,8) ----------------
__global__ void squash_all_kernel(const float* __restrict__ p1, const float* __restrict__ p2,
                                  const float* __restrict__ p3,
                                  const float* __restrict__ bias1, const float* __restrict__ bias2,
                                  const float* __restrict__ bias3,
                                  float* __restrict__ u1, float* __restrict__ u2,
                                  float* __restrict__ u3) {
    int blk = blockIdx.x;
    const float* p; const float* bias; float* u; int S;
    if (blk < 128)      { p = p1; bias = bias1; u = u1; S = 4; }
    else if (blk < 416) { p = p2; bias = bias2; u = u2; S = 9;  blk -= 128; }
    else                { p = p3; bias = bias3; u = u3; S = 36; blk -= 416; }
    int idx = blk * 256 + threadIdx.x;   // over 256*S*32, o innermost
    int o = idx & 31, rest = idx >> 5;
    int s = rest % S, b = rest / S;
    const float* pp = p + (size_t)(b * S + s) * 256 + o;
    float t[8]; float sn = 0.f;
    #pragma unroll
    for (int i = 0; i < 8; ++i) { t[i] = pp[i * 32] + bias[o + i * 32]; sn += t[i] * t[i]; }
    float f = sn / ((1.f + sn) * sqrtf(sn + SQ_EPS));
    float* up = u + (size_t)(b * (32 * S) + o * S + s) * 8;
    float4 w0 = {t[0] * f, t[1] * f, t[2] * f, t[3] * f};
    float4 w1 = {t[4] * f, t[5] * f, t[6] * f, t[7] * f};
    *reinterpret_cast<float4*>(up) = w0;
    *reinterpret_cast<float4*>(up + 4) = w1;
}

// ---------------- routing weights -> bf16 (after gemm3 frees yl3 region) ----------------
__global__ void rwtrans_kernel(const float* __restrict__ w1, const float* __restrict__ w2,
                               const float* __restrict__ w3,
                               ushort_t* __restrict__ o1, ushort_t* __restrict__ o2,
                               ushort_t* __restrict__ o3) {
    int idx = blockIdx.x * 256 + threadIdx.x;  // 7840*256 = 2,007,040 exact
    const float* src; ushort_t* dst; int off;
    if (idx < 163840)      { src = w1; dst = o1; off = idx; }
    else if (idx < 532480) { src = w2; dst = o2; off = idx - 163840; }
    else                   { src = w3; dst = o3; off = idx - 532480; }
    dst[off] = f2bf(src[off]);
}

// ---------------- dynamic routing (3 iters): priors packed bf16x2 in LDS (transposed, conflict-free),
//                  blog in registers, weights bf16 (slab fits per-XCD L2) ----------------
template<int R>
__global__ __launch_bounds__(256, 4) void routing_lds_kernel(
        const float* __restrict__ u, const ushort_t* __restrict__ rwb,
        float* __restrict__ lens) {
    constexpr int KMAX = (R + 255) / 256;
    int n = blockIdx.x, b = blockIdx.y;
    int tid = threadIdx.x, lane = tid & 63, wv = tid >> 6;
    __shared__ unsigned int pri[8 * R];   // pri[j*R + r] = bf16(po[2j]) | bf16(po[2j+1])<<16
    __shared__ float red[4 * 16];
    __shared__ float vsh[16];
    __shared__ float sred[4];
    float blog[KMAX];
    #pragma unroll
    for (int k = 0; k < KMAX; ++k) {
        blog[k] = 0.f;
        int r = tid + k * 256;
        if (r < R) {
            const float4* up = (const float4*)(u + ((size_t)b * R + r) * 8);
            float4 ua = up[0], ub2 = up[1];
            float uu[8] = {ua.x, ua.y, ua.z, ua.w, ub2.x, ub2.y, ub2.z, ub2.w};
            const ushort_t* wr = rwb + ((size_t)n * R + r) * 128;
            float po[16] = {};
            #pragma unroll
            for (int i = 0; i < 8; ++i) {
                short8 wa = *reinterpret_cast<const short8*>(wr + i * 16);
                short8 wb = *reinterpret_cast<const short8*>(wr + i * 16 + 8);
                #pragma unroll
                for (int o = 0; o < 8; ++o) po[o]     += uu[i] * bf2f((unsigned short)wa[o]);
                #pragma unroll
                for (int o = 0; o < 8; ++o) po[8 + o] += uu[i] * bf2f((unsigned short)wb[o]);
            }
            #pragma unroll
            for (int j = 0; j < 8; ++j)
                pri[j * R + r] = (unsigned int)f2bf(po[2*j]) | ((unsigned int)f2bf(po[2*j+1]) << 16);
        }
    }
    __syncthreads();
    float v[16];
    for (int it = 0; it < 3; ++it) {
        float lmax = -1e30f;
        #pragma unroll
        for (int k = 0; k < KMAX; ++k)
            if (tid + k * 256 < R) lmax = fmaxf(lmax, blog[k]);
        for (int off = 32; off; off >>= 1) lmax = fmaxf(lmax, __shfl_down(lmax, off));
        if (lane == 0) sred[wv] = lmax;
        __syncthreads();
        float mx = fmaxf(fmaxf(sred[0], sred[1]), fmaxf(sred[2], sred[3]));
        __syncthreads();
        float ce[KMAX];
        float lsum = 0.f;
        #pragma unroll
        for (int k = 0; k < KMAX; ++k) {
            ce[k] = (tid + k * 256 < R) ? expf(blog[k] - mx) : 0.f;
            lsum += ce[k];
        }
        for (int off = 32; off; off >>= 1) lsum += __shfl_down(lsum, off);
        if (lane == 0) sred[wv] = lsum;
        __syncthreads();
        float inv = 1.f / (sred[0] + sred[1] + sred[2] + sred[3]);
        float sacc[16] = {};
        #pragma unroll
        for (int k = 0; k < KMAX; ++k) {
            int r = tid + k * 256;
            if (r < R) {
                float c = ce[k] * inv;
                #pragma unroll
                for (int j = 0; j < 8; ++j) {
                    unsigned int w = pri[j * R + r];
                    sacc[2*j]   += c * bf2f((unsigned short)(w & 0xffffu));
                    sacc[2*j+1] += c * bf2f((unsigned short)(w >> 16));
                }
            }
        }
        #pragma unroll
        for (int o = 0; o < 16; ++o) {
            float xv = sacc[o];
            for (int off = 32; off; off >>= 1) xv += __shfl_down(xv, off);
            if (lane == 0) red[wv * 16 + o] = xv;
        }
        __syncthreads();
        if (tid < 16) vsh[tid] = red[tid] + red[16 + tid] + red[32 + tid] + red[48 + tid];
        __syncthreads();
        if (tid == 0) {
            float sn = 0.f;
            #pragma unroll
            for (int o = 0; o < 16; ++o) sn += vsh[o] * vsh[o];
            float f = sn / ((1.f + sn) * sqrtf(sn + SQ_EPS));
            #pragma unroll
            for (int o = 0; o < 16; ++o) vsh[o] *= f;
        }
        __syncthreads();
        #pragma unroll
        for (int o = 0; o < 16; ++o) v[o] = vsh[o];
        if (it < 2) {
            #pragma unroll
            for (int k = 0; k < KMAX; ++k) {
                int r = tid + k * 256;
                if (r < R) {
                    float dot = 0.f;
                    #pragma unroll
                    for (int j = 0; j < 8; ++j) {
                        unsigned int w = pri[j * R + r];
                        dot += bf2f((unsigned short)(w & 0xffffu)) * v[2*j];
                        dot += bf2f((unsigned short)(w >> 16)) * v[2*j+1];
                    }
                    blog[k] += dot;
                }
            }
        }
    }
    if (tid == 0) {
        float sn = 0.f;
        #pragma unroll
        for (int o = 0; o < 16; ++o) sn += v[o] * v[o];
        lens[b * 10 + n] = sqrtf(sn + SQ_EPS);
    }
}

// ---------------- final: softmax over classes of l1+l2+l3 ----------------
__global__ void final_softmax_kernel(const float* __restrict__ l1, const float* __restrict__ l2,
                                     const float* __restrict__ l3, float* __restrict__ out) {
    int b = threadIdx.x;
    float v[10]; float mx = -1e30f;
    #pragma unroll
    for (int n = 0; n < 10; ++n) {
        v[n] = l1[b * 10 + n] + l2[b * 10 + n] + l3[b * 10 + n];
        mx = fmaxf(mx, v[n]);
    }
    float s = 0.f;
    #pragma unroll
    for (int n = 0; n < 10; ++n) { v[n] = expf(v[n] - mx); s += v[n]; }
    float inv = 1.f / s;
    #pragma unroll
    for (int n = 0; n < 10; ++n) out[b * 10 + n] = v[n] * inv;
}

extern "C" void kernel_launch(void* const* d_in, const int* in_sizes, int n_in,
                              void* d_out, int out_size, void* d_ws, size_t ws_size,
                              hipStream_t stream) {
    const float* x   = (const float*)d_in[0];
    const float* c1w = (const float*)d_in[1];
    const float* c1b = (const float*)d_in[2];
    const float* p1w = (const float*)d_in[3];
    const float* p1b = (const float*)d_in[4];
    const float* d1w = (const float*)d_in[5];
    const float* c2w = (const float*)d_in[6];
    const float* c2b = (const float*)d_in[7];
    const float* p2w = (const float*)d_in[8];
    const float* p2b = (const float*)d_in[9];
    const float* d2w = (const float*)d_in[10];
    const float* c3w = (const float*)d_in[11];
    const float* c3b = (const float*)d_in[12];
    const float* p3w = (const float*)d_in[13];
    const float* p3b = (const float*)d_in[14];
    const float* d3w = (const float*)d_in[15];

    float* ws = (float*)d_ws;
    // region layout (float units) — total 23,403,520 floats = 93.6 MB
    float* x2    = ws + 0;          // 50176
    float* x1    = ws + 50176;      // 12544
    float* yh1f  = ws + 62720;      // 409600   (819200 halves)  [aliased by u1 later]
    float* yl1f  = ws + 472320;     // 409600
    float* yh2f  = ws + 881920;     // 1638400  [aliased by u2 later]
    float* yl2f  = ws + 2520320;    // 1638400
    float* yh3f  = ws + 4158720;    // 6553600  [aliased by u3 later]
    float* yl3f  = ws + 10712320;   // 6553600  [aliased by rwb after gemm3]
    float* wh1f  = ws + 17265920;   // 147456
    float* wl1f  = ws + 17413376;   // 147456
    float* wh2f  = ws + 17560832;   // 409600
    float* wl2f  = ws + 17970432;   // 409600
    float* wh3f  = ws + 18380032;   // 1327104  [aliased by p2 later]
    float* wl3f  = ws + 19707136;   // 1327104  [aliased by p1 later]
    float* p3    = ws + 21034240;   // 2359296
    float* bnp1  = ws + 23393536;   // 512 (x3: bnp2, bnp3 follow)
    float* bias1 = ws + 23395072;   // 256
    float* bias2 = ws + 23395328;   // 256
    float* bias3 = ws + 23395584;   // 256
    float* l1    = ws + 23395840;   // 2560
    float* l2    = ws + 23398400;   // 2560
    float* l3    = ws + 23400960;   // 2560

    ushort_t* yh1 = (ushort_t*)yh1f; ushort_t* yl1 = (ushort_t*)yl1f;
    ushort_t* yh2 = (ushort_t*)yh2f; ushort_t* yl2 = (ushort_t*)yl2f;
    ushort_t* yh3 = (ushort_t*)yh3f; ushort_t* yl3 = (ushort_t*)yl3f;
    ushort_t* wh1 = (ushort_t*)wh1f; ushort_t* wl1 = (ushort_t*)wl1f;
    ushort_t* wh2 = (ushort_t*)wh2f; ushort_t* wl2 = (ushort_t*)wl2f;
    ushort_t* wh3 = (ushort_t*)wh3f; ushort_t* wl3 = (ushort_t*)wl3f;
    // aliases (safe by stream ordering):
    float* u1 = yh1f;   // written after gemm1 reads yh1
    float* u2 = yh2f;
    float* u3 = yh3f;
    float* p2 = wh3f;   // written (zero+atomic) after gemm3 reads wh3
    float* p1 = wl3f;
    // bf16 routing weights live in dead yl3 region (converted after gemm3):
    ushort_t* rwb1 = (ushort_t*)yl3f;          // 163840 halves
    ushort_t* rwb2 = rwb1 + 163840;            // 368640 halves
    ushort_t* rwb3 = rwb2 + 368640;            // 1474560 halves (total 2,007,040 <= 13,107,200)

    pool_kernel<<<256, 256, 0, stream>>>(x, x2, x1, bnp1);

    conv_split_kernel<7, 7, 3, 5, 5><<<256, 256, 0, stream>>>(x1, c1w, c1b, yh1, yl1, bnp1);
    conv_split_kernel<14, 14, 5, 10, 10><<<256, 256, 0, stream>>>(x2, c2w, c2b, yh2, yl2, bnp1 + 512);
    conv_split_kernel<28, 28, 9, 20, 20><<<256, 256, 0, stream>>>(x, c3w, c3b, yh3, yl3, bnp1 + 1024);

    bn_final_kernel<<<3, 128, 0, stream>>>(bnp1);

    wtrans_all_kernel<<<14720, 256, 0, stream>>>(p1w, p2w, p3w, bnp1,
                                                 wh1, wl1, wh2, wl2, wh3, wl3);
    biasfold_all_kernel<<<768, 128, 0, stream>>>(p1w, p2w, p3w, bnp1,
                                                 p1b, p2b, p3b, bias1, bias2, bias3);

    // gemm3 (split-K x2, atomic) first: afterwards wh3/wl3 dead (reused for p2/p1), yl3 dead (rwb)
    zero_p3_kernel<<<2304, 256, 0, stream>>>(p3);
    prim_gemm_mfma<36, 6, 20, 20, 9><<<dim3(144, 4, 2), 256, 0, stream>>>(yh3, yl3, wh3, wl3, p3);
    rwtrans_kernel<<<7840, 256, 0, stream>>>(d1w, d2w, d3w, rwb1, rwb2, rwb3);
    zero_p21_kernel<<<832, 256, 0, stream>>>(p2, p1);
    prim_gemm_mfma<9, 3, 10, 10, 5><<<dim3(36, 4, 2), 256, 0, stream>>>(yh2, yl2, wh2, wl2, p2);
    prim_gemm_mfma<4, 2, 5, 5, 3><<<dim3(16, 4, 2), 256, 0, stream>>>(yh1, yl1, wh1, wl1, p1);

    squash_all_kernel<<<1568, 256, 0, stream>>>(p1, p2, p3, bias1, bias2, bias3, u1, u2, u3);

    routing_lds_kernel<128><<<dim3(10, 256), 256, 0, stream>>>(u1, rwb1, l1);
    routing_lds_kernel<288><<<dim3(10, 256), 256, 0, stream>>>(u2, rwb2, l2);
    routing_lds_kernel<1152><<<dim3(10, 256), 256, 0, stream>>>(u3, rwb3, l3);

    final_softmax_kernel<<<1, 256, 0, stream>>>(l1, l2, l3, (float*)d_out);
}

// Round 10
// 668.368 us; speedup vs baseline: 1.9663x; 1.0716x over previous
//
#include <hip/hip_runtime.h>
#include <math.h>

#define SQ_EPS 1e-12f
#define BN_EPS 1e-5f

typedef short short8 __attribute__((ext_vector_type(8)));
typedef float f32x4 __attribute__((ext_vector_type(4)));
typedef unsigned short ushort_t;

__device__ inline unsigned short f2bf(float x) {
    unsigned int u = __float_as_uint(x);
    unsigned int r = (u + 0x7fffu + ((u >> 16) & 1u)) >> 16;   // round-to-nearest-even
    return (unsigned short)r;
}
__device__ inline float bf2f(unsigned short h) {
    return __uint_as_float(((unsigned int)h) << 16);
}

// ---------------- pooling: img(28x28) -> x2(14x14) -> x1(7x7); blocks 0-2 also zero bn accum ----------------
__global__ void pool_kernel(const float* __restrict__ img,
                            float* __restrict__ x2, float* __restrict__ x1,
                            float* __restrict__ bnp_base) {
    __shared__ float s_img[784];
    __shared__ float s_x2[196];
    int b = blockIdx.x;
    if (b < 3) {  // zero sum/sq accumulators for the 3 branches (ws is poisoned)
        bnp_base[b * 512 + threadIdx.x] = 0.f;
        bnp_base[b * 512 + 256 + threadIdx.x] = 0.f;
    }
    const float* im = img + b * 784;
    for (int i = threadIdx.x; i < 784; i += 256) s_img[i] = im[i];
    __syncthreads();
    for (int idx = threadIdx.x; idx < 196; idx += 256) {
        int i = idx / 14, j = idx % 14;
        float v = 0.25f * (s_img[(2*i)*28 + 2*j]     + s_img[(2*i)*28 + 2*j + 1] +
                           s_img[(2*i+1)*28 + 2*j]   + s_img[(2*i+1)*28 + 2*j + 1]);
        s_x2[idx] = v;
        x2[b*196 + idx] = v;
    }
    __syncthreads();
    for (int idx = threadIdx.x; idx < 49; idx += 256) {
        int i = idx / 7, j = idx % 7;
        float v = 0.25f * (s_x2[(2*i)*14 + 2*j]     + s_x2[(2*i)*14 + 2*j + 1] +
                           s_x2[(2*i+1)*14 + 2*j]   + s_x2[(2*i+1)*14 + 2*j + 1]);
        x1[b*49 + idx] = v;
    }
}

// ---------------- conv (1->128ch, stride1, VALID) + relu, split-bf16 out [b][pos][c], BN stats ----------------
template<int IH, int IW, int KS, int OH, int OW>
__global__ __launch_bounds__(256) void conv_split_kernel(
        const float* __restrict__ in, const float* __restrict__ w,
        const float* __restrict__ bias,
        ushort_t* __restrict__ yh, ushort_t* __restrict__ yl,
        float* __restrict__ bnp) {
    constexpr int KK = KS * KS;
    constexpr int OS = OH * OW;
    __shared__ float s_img[IH * IW];
    __shared__ float s_w[128 * KK];
    __shared__ float s_red[256];
    int b = blockIdx.x, tid = threadIdx.x;
    const float* ip = in + b * IH * IW;
    for (int i = tid; i < IH * IW; i += 256) s_img[i] = ip[i];
    for (int i = tid; i < 128 * KK; i += 256) s_w[i] = w[i];
    __syncthreads();
    int c = tid & 127, half = tid >> 7;
    float bias_c = bias[c];
    float bsum = 0.f, bsq = 0.f;
    for (int r = half; r < OH; r += 2) {
        float acc[OW];
        #pragma unroll
        for (int j = 0; j < OW; ++j) acc[j] = bias_c;
        for (int u = 0; u < KS; ++u) {
            float rg[OW + KS - 1];
            #pragma unroll
            for (int j = 0; j < OW + KS - 1; ++j) rg[j] = s_img[(r + u) * IW + j];
            #pragma unroll
            for (int v = 0; v < KS; ++v) {
                float wv = s_w[c * KK + u * KS + v];
                #pragma unroll
                for (int j = 0; j < OW; ++j) acc[j] += wv * rg[j + v];
            }
        }
        #pragma unroll
        for (int j = 0; j < OW; ++j) {
            float val = fmaxf(acc[j], 0.f);
            bsum += val; bsq += val * val;
            unsigned short h = f2bf(val);
            unsigned short lo = f2bf(val - bf2f(h));
            int oidx = ((b * OS) + r * OW + j) * 128 + c;
            yh[oidx] = h; yl[oidx] = lo;
        }
    }
    s_red[tid] = bsum; __syncthreads();
    if (tid < 128) atomicAdd(&bnp[c], s_red[tid] + s_red[tid + 128]);
    __syncthreads();
    s_red[tid] = bsq; __syncthreads();
    if (tid < 128) atomicAdd(&bnp[128 + c], s_red[tid] + s_red[tid + 128]);
}

// ---------------- finalize BN: scale/shift per channel, 3 branches ----------------
__global__ void bn_final_kernel(float* __restrict__ bnp_base) {
    int br = blockIdx.x;
    float* bnp = bnp_base + br * 512;
    float N = (br == 0) ? 6400.f : ((br == 1) ? 25600.f : 102400.f);
    int c = threadIdx.x;  // 128
    float mean = bnp[c] / N;
    float var = bnp[128 + c] / N - mean * mean;
    float inv = rsqrtf(var + BN_EPS);
    bnp[256 + c] = inv;
    bnp[384 + c] = -mean * inv;
}

// ---------------- weight transform (all branches): W[ch][c][uv]*scale_c -> split bf16 [uv][ch][c] ----------------
__global__ void wtrans_all_kernel(const float* __restrict__ w1, const float* __restrict__ w2,
                                  const float* __restrict__ w3, const float* __restrict__ bnp_base,
                                  ushort_t* __restrict__ wh1, ushort_t* __restrict__ wl1,
                                  ushort_t* __restrict__ wh2, ushort_t* __restrict__ wl2,
                                  ushort_t* __restrict__ wh3, ushort_t* __restrict__ wl3) {
    int blk = blockIdx.x;
    const float* w; const float* bnp; ushort_t* wh; ushort_t* wl; int KK;
    if (blk < 1152)      { w = w1; bnp = bnp_base;        wh = wh1; wl = wl1; KK = 9;  }
    else if (blk < 4352) { w = w2; bnp = bnp_base + 512;  wh = wh2; wl = wl2; KK = 25; blk -= 1152; }
    else                 { w = w3; bnp = bnp_base + 1024; wh = wh3; wl = wl3; KK = 81; blk -= 4352; }
    int idx = blk * 256 + threadIdx.x;
    int c = idx & 127, ch = (idx >> 7) & 255, uv = idx >> 15;
    float val = w[((ch << 7) + c) * KK + uv] * bnp[256 + c];
    unsigned short h = f2bf(val);
    unsigned short lo = f2bf(val - bf2f(h));
    wh[idx] = h; wl[idx] = lo;
}

// ---------------- fold BN shift into per-channel bias (all branches) ----------------
__global__ void biasfold_all_kernel(const float* __restrict__ w1, const float* __restrict__ w2,
                                    const float* __restrict__ w3, const float* __restrict__ bnp_base,
                                    const float* __restrict__ pb1, const float* __restrict__ pb2,
                                    const float* __restrict__ pb3,
                                    float* __restrict__ b1, float* __restrict__ b2, float* __restrict__ b3) {
    int br = blockIdx.x >> 8, ch = blockIdx.x & 255, tid = threadIdx.x;  // 128 threads, c = tid
    const float* w  = (br == 0) ? w1  : (br == 1) ? w2  : w3;
    const float* pb = (br == 0) ? pb1 : (br == 1) ? pb2 : pb3;
    float* bf       = (br == 0) ? b1  : (br == 1) ? b2  : b3;
    int KK          = (br == 0) ? 9   : (br == 1) ? 25  : 81;
    const float* bnp = bnp_base + br * 512;
    const float* wrow = w + (ch * 128 + tid) * KK;
    float s = 0.f;
    for (int uv = 0; uv < KK; ++uv) s += wrow[uv];
    s *= bnp[384 + tid];
    for (int off = 32; off; off >>= 1) s += __shfl_down(s, off);
    __shared__ float r2[2];
    if ((tid & 63) == 0) r2[tid >> 6] = s;
    __syncthreads();
    if (tid == 0) bf[ch] = pb[ch] + r2[0] + r2[1];
}

// ---------------- zero kernels for split-K accumulators ----------------
__global__ void zero_p3_kernel(float* __restrict__ p3) {
    ((float4*)p3)[blockIdx.x * 256 + threadIdx.x] = (float4){0.f, 0.f, 0.f, 0.f};
}
__global__ void zero_p21_kernel(float* __restrict__ p2, float* __restrict__ p1) {
    int blk = blockIdx.x;
    if (blk < 576) ((float4*)p2)[blk * 256 + threadIdx.x] = (float4){0.f, 0.f, 0.f, 0.f};
    else           ((float4*)p1)[(blk - 576) * 256 + threadIdx.x] = (float4){0.f, 0.f, 0.f, 0.f};
}

// ---------------- primary-caps conv as split-bf16 MFMA GEMM, split-K x4 via atomicAdd ----------------
// 128(M) x 64(N) block tile, BK=32, 4 waves as 2x2; each wave 64x32 (4x2 of 16x16), 24 MFMA/iter.
// LDS: round-8-verified addressing (pitch 32 halves, XOR swizzle chunk^((row>>1)&3)) -> 0 bank conflicts.
// A rows r and r+64 share one thread (identical swizzle: 64 == 0 mod 4 after >>1,&3).
template<int S, int WO, int IHg, int IWg, int KS>
__global__ __launch_bounds__(256, 4) void prim_gemm_mfma(
        const ushort_t* __restrict__ yh, const ushort_t* __restrict__ yl,
        const ushort_t* __restrict__ wh, const ushort_t* __restrict__ wl,
        float* __restrict__ p) {
    constexpr int CHUNKS = KS * KS * 4;     // total BK=32 chunks
    constexpr int QUARTER = CHUNKS / 4;     // per z block
    __shared__ ushort_t Ash[128 * 32], Asl[128 * 32];
    __shared__ ushort_t Bsh[64 * 32],  Bsl[64 * 32];
    int tid = threadIdx.x;
    int bm = blockIdx.x * 128, ch0 = blockIdx.y * 64;
    // staging roles: arow = tid>>2 (0..63) plus arow+64; chunk c0 = tid&3 (8 halves)
    int arow = tid >> 2;
    int c0 = tid & 3;
    int sw0 = (c0 ^ ((arow >> 1) & 3)) * 8;
    int wA0 = arow * 32 + sw0;
    int wA1 = (arow + 64) * 32 + sw0;
    int m0 = bm + arow;
    int b0 = m0 / S, s0 = m0 % S;
    int abase0 = ((b0 * IHg + 2 * (s0 / WO)) * IWg + 2 * (s0 % WO)) * 128 + c0 * 8;
    int m1 = m0 + 64;
    int b1 = m1 / S, s1 = m1 % S;
    int abase1 = ((b1 * IHg + 2 * (s1 / WO)) * IWg + 2 * (s1 % WO)) * 128 + c0 * 8;
    int bbase = (ch0 + arow) * 128 + c0 * 8;
    // compute roles: waves 2x2, wave (wm,wn) owns rows wm*64..+63, cols wn*32..+31
    int lane = tid & 63, wid = tid >> 6;
    int wm = wid & 1, wn = wid >> 1;
    int quad = lane >> 4, l16 = lane & 15;
    int aoffL[4], boffL[2];
    #pragma unroll
    for (int mi = 0; mi < 4; ++mi) {
        int row = wm * 64 + mi * 16 + l16;
        aoffL[mi] = row * 32 + ((quad ^ ((row >> 1) & 3)) * 8);
    }
    #pragma unroll
    for (int ni = 0; ni < 2; ++ni) {
        int row = wn * 32 + ni * 16 + l16;
        boffL[ni] = row * 32 + ((quad ^ ((row >> 1) & 3)) * 8);
    }
    f32x4 acc[4][2];
    #pragma unroll
    for (int mi = 0; mi < 4; ++mi)
        #pragma unroll
        for (int ni = 0; ni < 2; ++ni)
            acc[mi][ni] = (f32x4){0.f, 0.f, 0.f, 0.f};

    // k-chunk index kc = z*QUARTER + t ; uv = kc>>2, cs = (kc&3)*32
    int kc = blockIdx.z * QUARTER;
    int uv = kc >> 2, ci = kc & 3;
    int u = uv / KS, v = uv - u * KS;
    int aoff = (u * IWg + v) * 128 + (ci << 5);
    int boff = uv * 32768 + (ci << 5);
    int4 a0h = *reinterpret_cast<const int4*>(yh + abase0 + aoff);
    int4 a0l = *reinterpret_cast<const int4*>(yl + abase0 + aoff);
    int4 a1h = *reinterpret_cast<const int4*>(yh + abase1 + aoff);
    int4 a1l = *reinterpret_cast<const int4*>(yl + abase1 + aoff);
    int4 b4h = *reinterpret_cast<const int4*>(wh + bbase + boff);
    int4 b4l = *reinterpret_cast<const int4*>(wl + bbase + boff);

    for (int t = 0; t < QUARTER; ++t) {
        __syncthreads();
        *reinterpret_cast<int4*>(&Ash[wA0]) = a0h;
        *reinterpret_cast<int4*>(&Asl[wA0]) = a0l;
        *reinterpret_cast<int4*>(&Ash[wA1]) = a1h;
        *reinterpret_cast<int4*>(&Asl[wA1]) = a1l;
        *reinterpret_cast<int4*>(&Bsh[wA0]) = b4h;
        *reinterpret_cast<int4*>(&Bsl[wA0]) = b4l;
        if (t + 1 < QUARTER) {   // prefetch next chunk (uniform branch)
            ci = (ci + 1) & 3;
            if (ci == 0) { ++uv; ++v; if (v == KS) { v = 0; ++u; } }
            aoff = (u * IWg + v) * 128 + (ci << 5);
            boff = uv * 32768 + (ci << 5);
            a0h = *reinterpret_cast<const int4*>(yh + abase0 + aoff);
            a0l = *reinterpret_cast<const int4*>(yl + abase0 + aoff);
            a1h = *reinterpret_cast<const int4*>(yh + abase1 + aoff);
            a1l = *reinterpret_cast<const int4*>(yl + abase1 + aoff);
            b4h = *reinterpret_cast<const int4*>(wh + bbase + boff);
            b4l = *reinterpret_cast<const int4*>(wl + bbase + boff);
        }
        __syncthreads();
        short8 bh[2], bl[2];
        #pragma unroll
        for (int ni = 0; ni < 2; ++ni) {
            bh[ni] = *reinterpret_cast<const short8*>(&Bsh[boffL[ni]]);
            bl[ni] = *reinterpret_cast<const short8*>(&Bsl[boffL[ni]]);
        }
        #pragma unroll
        for (int mi = 0; mi < 4; ++mi) {
            short8 ah = *reinterpret_cast<const short8*>(&Ash[aoffL[mi]]);
            short8 al = *reinterpret_cast<const short8*>(&Asl[aoffL[mi]]);
            #pragma unroll
            for (int ni = 0; ni < 2; ++ni) {
                acc[mi][ni] = __builtin_amdgcn_mfma_f32_16x16x32_bf16(ah, bh[ni], acc[mi][ni], 0, 0, 0);
                acc[mi][ni] = __builtin_amdgcn_mfma_f32_16x16x32_bf16(al, bh[ni], acc[mi][ni], 0, 0, 0);
                acc[mi][ni] = __builtin_amdgcn_mfma_f32_16x16x32_bf16(ah, bl[ni], acc[mi][ni], 0, 0, 0);
            }
        }
    }
    // C/D layout (measured m89): col = lane&15, row = quad*4 + reg
    #pragma unroll
    for (int mi = 0; mi < 4; ++mi)
        #pragma unroll
        for (int ni = 0; ni < 2; ++ni) {
            int col = ch0 + wn * 32 + ni * 16 + l16;
            #pragma unroll
            for (int reg = 0; reg < 4; ++reg) {
                int row = bm + wm * 64 + mi * 16 + quad * 4 + reg;
                atomicAdd(p + (size_t)row * 256 + col, acc[mi][ni][reg]);
            }
        }
}

// ---------------- squash primary caps (all branches): p(B*S,256)+bias -> u(B,32*S,8) ----------------
__global__ void squash_all_kernel(const float* __restrict__ p1, const float* __restrict__ p2,
                                  const float* __restrict__ p3,
                                  const float* __restrict__ bias1, const float* __restrict__ bias2,
                                  const float* __restrict__ bias3,
                                  float* __restrict__ u1, float* __restrict__ u2,
                                  float* __restrict__ u3) {
    int blk = blockIdx.x;
    const float* p; const float* bias; float* u; int S;
    if (blk < 128)      { p = p1; bias = bias1; u = u1; S = 4; }
    else if (blk < 416) { p = p2; bias = bias2; u = u2; S = 9;  blk -= 128; }
    else                { p = p3; bias = bias3; u = u3; S = 36; blk -= 416; }
    int idx = blk * 256 + threadIdx.x;   // over 256*S*32, o innermost
    int o = idx & 31, rest = idx >> 5;
    int s = rest % S, b = rest / S;
    const float* pp = p + (size_t)(b * S + s) * 256 + o;
    float t[8]; float sn = 0.f;
    #pragma unroll
    for (int i = 0; i < 8; ++i) { t[i] = pp[i * 32] + bias[o + i * 32]; sn += t[i] * t[i]; }
    float f = sn / ((1.f + sn) * sqrtf(sn + SQ_EPS));
    float* up = u + (size_t)(b * (32 * S) + o * S + s) * 8;
    float4 w0 = {t[0] * f, t[1] * f, t[2] * f, t[3] * f};
    float4 w1 = {t[4] * f, t[5] * f, t[6] * f, t[7] * f};
    *reinterpret_cast<float4*>(up) = w0;
    *reinterpret_cast<float4*>(up + 4) = w1;
}

// ---------------- routing weights -> bf16 (after gemm3 frees yl3 region) ----------------
__global__ void rwtrans_kernel(const float* __restrict__ w1, const float* __restrict__ w2,
                               const float* __restrict__ w3,
                               ushort_t* __restrict__ o1, ushort_t* __restrict__ o2,
                               ushort_t* __restrict__ o3) {
    int idx = blockIdx.x * 256 + threadIdx.x;  // 7840*256 = 2,007,040 exact
    const float* src; ushort_t* dst; int off;
    if (idx < 163840)      { src = w1; dst = o1; off = idx; }
    else if (idx < 532480) { src = w2; dst = o2; off = idx - 163840; }
    else                   { src = w3; dst = o3; off = idx - 532480; }
    dst[off] = f2bf(src[off]);
}

// ---------------- dynamic routing (3 iters): priors packed bf16x2 in LDS (transposed, conflict-free),
//                  blog in registers, weights bf16 (slab fits per-XCD L2) ----------------
template<int R>
__global__ __launch_bounds__(256, 4) void routing_lds_kernel(
        const float* __restrict__ u, const ushort_t* __restrict__ rwb,
        float* __restrict__ lens) {
    constexpr int KMAX = (R + 255) / 256;
    int n = blockIdx.x, b = blockIdx.y;
    int tid = threadIdx.x, lane = tid & 63, wv = tid >> 6;
    __shared__ unsigned int pri[8 * R];   // pri[j*R + r] = bf16(po[2j]) | bf16(po[2j+1])<<16
    __shared__ float red[4 * 16];
    __shared__ float vsh[16];
    __shared__ float sred[4];
    float blog[KMAX];
    #pragma unroll
    for (int k = 0; k < KMAX; ++k) {
        blog[k] = 0.f;
        int r = tid + k * 256;
        if (r < R) {
            const float4* up = (const float4*)(u + ((size_t)b * R + r) * 8);
            float4 ua = up[0], ub2 = up[1];
            float uu[8] = {ua.x, ua.y, ua.z, ua.w, ub2.x, ub2.y, ub2.z, ub2.w};
            const ushort_t* wr = rwb + ((size_t)n * R + r) * 128;
            float po[16] = {};
            #pragma unroll
            for (int i = 0; i < 8; ++i) {
                short8 wa = *reinterpret_cast<const short8*>(wr + i * 16);
                short8 wb = *reinterpret_cast<const short8*>(wr + i * 16 + 8);
                #pragma unroll
                for (int o = 0; o < 8; ++o) po[o]     += uu[i] * bf2f((unsigned short)wa[o]);
                #pragma unroll
                for (int o = 0; o < 8; ++o) po[8 + o] += uu[i] * bf2f((unsigned short)wb[o]);
            }
            #pragma unroll
            for (int j = 0; j < 8; ++j)
                pri[j * R + r] = (unsigned int)f2bf(po[2*j]) | ((unsigned int)f2bf(po[2*j+1]) << 16);
        }
    }
    __syncthreads();
    float v[16];
    for (int it = 0; it < 3; ++it) {
        float lmax = -1e30f;
        #pragma unroll
        for (int k = 0; k < KMAX; ++k)
            if (tid + k * 256 < R) lmax = fmaxf(lmax, blog[k]);
        for (int off = 32; off; off >>= 1) lmax = fmaxf(lmax, __shfl_down(lmax, off));
        if (lane == 0) sred[wv] = lmax;
        __syncthreads();
        float mx = fmaxf(fmaxf(sred[0], sred[1]), fmaxf(sred[2], sred[3]));
        __syncthreads();
        float ce[KMAX];
        float lsum = 0.f;
        #pragma unroll
        for (int k = 0; k < KMAX; ++k) {
            ce[k] = (tid + k * 256 < R) ? expf(blog[k] - mx) : 0.f;
            lsum += ce[k];
        }
        for (int off = 32; off; off >>= 1) lsum += __shfl_down(lsum, off);
        if (lane == 0) sred[wv] = lsum;
        __syncthreads();
        float inv = 1.f / (sred[0] + sred[1] + sred[2] + sred[3]);
        float sacc[16] = {};
        #pragma unroll
        for (int k = 0; k < KMAX; ++k) {
            int r = tid + k * 256;
            if (r < R) {
                float c = ce[k] * inv;
                #pragma unroll
                for (int j = 0; j < 8; ++j) {
                    unsigned int w = pri[j * R + r];
                    sacc[2*j]   += c * bf2f((unsigned short)(w & 0xffffu));
                    sacc[2*j+1] += c * bf2f((unsigned short)(w >> 16));
                }
            }
        }
        #pragma unroll
        for (int o = 0; o < 16; ++o) {
            float xv = sacc[o];
            for (int off = 32; off; off >>= 1) xv += __shfl_down(xv, off);
            if (lane == 0) red[wv * 16 + o] = xv;
        }
        __syncthreads();
        if (tid < 16) vsh[tid] = red[tid] + red[16 + tid] + red[32 + tid] + red[48 + tid];
        __syncthreads();
        if (tid == 0) {
            float sn = 0.f;
            #pragma unroll
            for (int o = 0; o < 16; ++o) sn += vsh[o] * vsh[o];
            float f = sn / ((1.f + sn) * sqrtf(sn + SQ_EPS));
            #pragma unroll
            for (int o = 0; o < 16; ++o) vsh[o] *= f;
        }
        __syncthreads();
        #pragma unroll
        for (int o = 0; o < 16; ++o) v[o] = vsh[o];
        if (it < 2) {
            #pragma unroll
            for (int k = 0; k < KMAX; ++k) {
                int r = tid + k * 256;
                if (r < R) {
                    float dot = 0.f;
                    #pragma unroll
                    for (int j = 0; j < 8; ++j) {
                        unsigned int w = pri[j * R + r];
                        dot += bf2f((unsigned short)(w & 0xffffu)) * v[2*j];
                        dot += bf2f((unsigned short)(w >> 16)) * v[2*j+1];
                    }
                    blog[k] += dot;
                }
            }
        }
    }
    if (tid == 0) {
        float sn = 0.f;
        #pragma unroll
        for (int o = 0; o < 16; ++o) sn += v[o] * v[o];
        lens[b * 10 + n] = sqrtf(sn + SQ_EPS);
    }
}

// ---------------- final: softmax over classes of l1+l2+l3 ----------------
__global__ void final_softmax_kernel(const float* __restrict__ l1, const float* __restrict__ l2,
                                     const float* __restrict__ l3, float* __restrict__ out) {
    int b = threadIdx.x;
    float v[10]; float mx = -1e30f;
    #pragma unroll
    for (int n = 0; n < 10; ++n) {
        v[n] = l1[b * 10 + n] + l2[b * 10 + n] + l3[b * 10 + n];
        mx = fmaxf(mx, v[n]);
    }
    float s = 0.f;
    #pragma unroll
    for (int n = 0; n < 10; ++n) { v[n] = expf(v[n] - mx); s += v[n]; }
    float inv = 1.f / s;
    #pragma unroll
    for (int n = 0; n < 10; ++n) out[b * 10 + n] = v[n] * inv;
}

extern "C" void kernel_launch(void* const* d_in, const int* in_sizes, int n_in,
                              void* d_out, int out_size, void* d_ws, size_t ws_size,
                              hipStream_t stream) {
    const float* x   = (const float*)d_in[0];
    const float* c1w = (const float*)d_in[1];
    const float* c1b = (const float*)d_in[2];
    const float* p1w = (const float*)d_in[3];
    const float* p1b = (const float*)d_in[4];
    const float* d1w = (const float*)d_in[5];
    const float* c2w = (const float*)d_in[6];
    const float* c2b = (const float*)d_in[7];
    const float* p2w = (const float*)d_in[8];
    const float* p2b = (const float*)d_in[9];
    const float* d2w = (const float*)d_in[10];
    const float* c3w = (const float*)d_in[11];
    const float* c3b = (const float*)d_in[12];
    const float* p3w = (const float*)d_in[13];
    const float* p3b = (const float*)d_in[14];
    const float* d3w = (const float*)d_in[15];

    float* ws = (float*)d_ws;
    // region layout (float units) — total 23,403,520 floats = 93.6 MB
    float* x2    = ws + 0;          // 50176
    float* x1    = ws + 50176;      // 12544
    float* yh1f  = ws + 62720;      // 409600   (819200 halves)  [aliased by u1 later]
    float* yl1f  = ws + 472320;     // 409600
    float* yh2f  = ws + 881920;     // 1638400  [aliased by u2 later]
    float* yl2f  = ws + 2520320;    // 1638400
    float* yh3f  = ws + 4158720;    // 6553600  [aliased by u3 later]
    float* yl3f  = ws + 10712320;   // 6553600  [aliased by rwb after gemm3]
    float* wh1f  = ws + 17265920;   // 147456
    float* wl1f  = ws + 17413376;   // 147456
    float* wh2f  = ws + 17560832;   // 409600
    float* wl2f  = ws + 17970432;   // 409600
    float* wh3f  = ws + 18380032;   // 1327104  [aliased by p2 later]
    float* wl3f  = ws + 19707136;   // 1327104  [aliased by p1 later]
    float* p3    = ws + 21034240;   // 2359296
    float* bnp1  = ws + 23393536;   // 512 (x3: bnp2, bnp3 follow)
    float* bias1 = ws + 23395072;   // 256
    float* bias2 = ws + 23395328;   // 256
    float* bias3 = ws + 23395584;   // 256
    float* l1    = ws + 23395840;   // 2560
    float* l2    = ws + 23398400;   // 2560
    float* l3    = ws + 23400960;   // 2560

    ushort_t* yh1 = (ushort_t*)yh1f; ushort_t* yl1 = (ushort_t*)yl1f;
    ushort_t* yh2 = (ushort_t*)yh2f; ushort_t* yl2 = (ushort_t*)yl2f;
    ushort_t* yh3 = (ushort_t*)yh3f; ushort_t* yl3 = (ushort_t*)yl3f;
    ushort_t* wh1 = (ushort_t*)wh1f; ushort_t* wl1 = (ushort_t*)wl1f;
    ushort_t* wh2 = (ushort_t*)wh2f; ushort_t* wl2 = (ushort_t*)wl2f;
    ushort_t* wh3 = (ushort_t*)wh3f; ushort_t* wl3 = (ushort_t*)wl3f;
    // aliases (safe by stream ordering):
    float* u1 = yh1f;   // written after gemm1 reads yh1
    float* u2 = yh2f;
    float* u3 = yh3f;
    float* p2 = wh3f;   // written (zero+atomic) after gemm3 reads wh3
    float* p1 = wl3f;
    // bf16 routing weights live in dead yl3 region (converted after gemm3):
    ushort_t* rwb1 = (ushort_t*)yl3f;          // 163840 halves
    ushort_t* rwb2 = rwb1 + 163840;            // 368640 halves
    ushort_t* rwb3 = rwb2 + 368640;            // 1474560 halves (total 2,007,040 <= 13,107,200)

    pool_kernel<<<256, 256, 0, stream>>>(x, x2, x1, bnp1);

    conv_split_kernel<7, 7, 3, 5, 5><<<256, 256, 0, stream>>>(x1, c1w, c1b, yh1, yl1, bnp1);
    conv_split_kernel<14, 14, 5, 10, 10><<<256, 256, 0, stream>>>(x2, c2w, c2b, yh2, yl2, bnp1 + 512);
    conv_split_kernel<28, 28, 9, 20, 20><<<256, 256, 0, stream>>>(x, c3w, c3b, yh3, yl3, bnp1 + 1024);

    bn_final_kernel<<<3, 128, 0, stream>>>(bnp1);

    wtrans_all_kernel<<<14720, 256, 0, stream>>>(p1w, p2w, p3w, bnp1,
                                                 wh1, wl1, wh2, wl2, wh3, wl3);
    biasfold_all_kernel<<<768, 128, 0, stream>>>(p1w, p2w, p3w, bnp1,
                                                 p1b, p2b, p3b, bias1, bias2, bias3);

    // gemm3 (split-K x4, atomic) first: afterwards wh3/wl3 dead (reused for p2/p1), yl3 dead (rwb)
    zero_p3_kernel<<<2304, 256, 0, stream>>>(p3);
    prim_gemm_mfma<36, 6, 20, 20, 9><<<dim3(72, 4, 4), 256, 0, stream>>>(yh3, yl3, wh3, wl3, p3);
    rwtrans_kernel<<<7840, 256, 0, stream>>>(d1w, d2w, d3w, rwb1, rwb2, rwb3);
    zero_p21_kernel<<<832, 256, 0, stream>>>(p2, p1);
    prim_gemm_mfma<9, 3, 10, 10, 5><<<dim3(18, 4, 4), 256, 0, stream>>>(yh2, yl2, wh2, wl2, p2);
    prim_gemm_mfma<4, 2, 5, 5, 3><<<dim3(8, 4, 4), 256, 0, stream>>>(yh1, yl1, wh1, wl1, p1);

    squash_all_kernel<<<1568, 256, 0, stream>>>(p1, p2, p3, bias1, bias2, bias3, u1, u2, u3);

    routing_lds_kernel<128><<<dim3(10, 256), 256, 0, stream>>>(u1, rwb1, l1);
    routing_lds_kernel<288><<<dim3(10, 256), 256, 0, stream>>>(u2, rwb2, l2);
    routing_lds_kernel<1152><<<dim3(10, 256), 256, 0, stream>>>(u3, rwb3, l3);

    final_softmax_kernel<<<1, 256, 0, stream>>>(l1, l2, l3, (float*)d_out);
}

// Round 11
// 640.485 us; speedup vs baseline: 2.0519x; 1.0435x over previous
//
#include <hip/hip_runtime.h>
#include <math.h>

#define SQ_EPS 1e-12f
#define BN_EPS 1e-5f

typedef short short8 __attribute__((ext_vector_type(8)));
typedef float f32x4 __attribute__((ext_vector_type(4)));
typedef unsigned short ushort_t;

__device__ inline unsigned short f2bf(float x) {
    unsigned int u = __float_as_uint(x);
    unsigned int r = (u + 0x7fffu + ((u >> 16) & 1u)) >> 16;   // round-to-nearest-even
    return (unsigned short)r;
}
__device__ inline float bf2f(unsigned short h) {
    return __uint_as_float(((unsigned int)h) << 16);
}

// ---------------- pooling: img(28x28) -> x2(14x14) -> x1(7x7); blocks 0-2 also zero bn accum ----------------
__global__ void pool_kernel(const float* __restrict__ img,
                            float* __restrict__ x2, float* __restrict__ x1,
                            float* __restrict__ bnp_base) {
    __shared__ float s_img[784];
    __shared__ float s_x2[196];
    int b = blockIdx.x;
    if (b < 3) {  // zero sum/sq accumulators for the 3 branches (ws is poisoned)
        bnp_base[b * 512 + threadIdx.x] = 0.f;
        bnp_base[b * 512 + 256 + threadIdx.x] = 0.f;
    }
    const float* im = img + b * 784;
    for (int i = threadIdx.x; i < 784; i += 256) s_img[i] = im[i];
    __syncthreads();
    for (int idx = threadIdx.x; idx < 196; idx += 256) {
        int i = idx / 14, j = idx % 14;
        float v = 0.25f * (s_img[(2*i)*28 + 2*j]     + s_img[(2*i)*28 + 2*j + 1] +
                           s_img[(2*i+1)*28 + 2*j]   + s_img[(2*i+1)*28 + 2*j + 1]);
        s_x2[idx] = v;
        x2[b*196 + idx] = v;
    }
    __syncthreads();
    for (int idx = threadIdx.x; idx < 49; idx += 256) {
        int i = idx / 7, j = idx % 7;
        float v = 0.25f * (s_x2[(2*i)*14 + 2*j]     + s_x2[(2*i)*14 + 2*j + 1] +
                           s_x2[(2*i+1)*14 + 2*j]   + s_x2[(2*i+1)*14 + 2*j + 1]);
        x1[b*49 + idx] = v;
    }
}

// ---------------- conv (1->128ch, stride1, VALID) + relu, split-bf16 out [b][pos][c], BN stats ----------------
template<int IH, int IW, int KS, int OH, int OW>
__global__ __launch_bounds__(256) void conv_split_kernel(
        const float* __restrict__ in, const float* __restrict__ w,
        const float* __restrict__ bias,
        ushort_t* __restrict__ yh, ushort_t* __restrict__ yl,
        float* __restrict__ bnp) {
    constexpr int KK = KS * KS;
    constexpr int OS = OH * OW;
    __shared__ float s_img[IH * IW];
    __shared__ float s_w[128 * KK];
    __shared__ float s_red[256];
    int b = blockIdx.x, tid = threadIdx.x;
    const float* ip = in + b * IH * IW;
    for (int i = tid; i < IH * IW; i += 256) s_img[i] = ip[i];
    for (int i = tid; i < 128 * KK; i += 256) s_w[i] = w[i];
    __syncthreads();
    int c = tid & 127, half = tid >> 7;
    float bias_c = bias[c];
    float bsum = 0.f, bsq = 0.f;
    for (int r = half; r < OH; r += 2) {
        float acc[OW];
        #pragma unroll
        for (int j = 0; j < OW; ++j) acc[j] = bias_c;
        for (int u = 0; u < KS; ++u) {
            float rg[OW + KS - 1];
            #pragma unroll
            for (int j = 0; j < OW + KS - 1; ++j) rg[j] = s_img[(r + u) * IW + j];
            #pragma unroll
            for (int v = 0; v < KS; ++v) {
                float wv = s_w[c * KK + u * KS + v];
                #pragma unroll
                for (int j = 0; j < OW; ++j) acc[j] += wv * rg[j + v];
            }
        }
        #pragma unroll
        for (int j = 0; j < OW; ++j) {
            float val = fmaxf(acc[j], 0.f);
            bsum += val; bsq += val * val;
            unsigned short h = f2bf(val);
            unsigned short lo = f2bf(val - bf2f(h));
            int oidx = ((b * OS) + r * OW + j) * 128 + c;
            yh[oidx] = h; yl[oidx] = lo;
        }
    }
    s_red[tid] = bsum; __syncthreads();
    if (tid < 128) atomicAdd(&bnp[c], s_red[tid] + s_red[tid + 128]);
    __syncthreads();
    s_red[tid] = bsq; __syncthreads();
    if (tid < 128) atomicAdd(&bnp[128 + c], s_red[tid] + s_red[tid + 128]);
}

// ---------------- finalize BN: scale/shift per channel, 3 branches ----------------
__global__ void bn_final_kernel(float* __restrict__ bnp_base) {
    int br = blockIdx.x;
    float* bnp = bnp_base + br * 512;
    float N = (br == 0) ? 6400.f : ((br == 1) ? 25600.f : 102400.f);
    int c = threadIdx.x;  // 128
    float mean = bnp[c] / N;
    float var = bnp[128 + c] / N - mean * mean;
    float inv = rsqrtf(var + BN_EPS);
    bnp[256 + c] = inv;
    bnp[384 + c] = -mean * inv;
}

// ---------------- weight transform + bias fold (fused, coalesced via LDS transpose) ----------------
// block = (branch, ch). Read w[ch][c][uv] coalesced -> LDS [c][uv]; write split-bf16 [uv][ch][c]
// coalesced; fold BN shift into bias from the same tile.
__global__ __launch_bounds__(256) void wtrans_bias_kernel(
        const float* __restrict__ w1, const float* __restrict__ w2,
        const float* __restrict__ w3, const float* __restrict__ bnp_base,
        const float* __restrict__ pb1, const float* __restrict__ pb2,
        const float* __restrict__ pb3,
        ushort_t* __restrict__ wh1, ushort_t* __restrict__ wl1,
        ushort_t* __restrict__ wh2, ushort_t* __restrict__ wl2,
        ushort_t* __restrict__ wh3, ushort_t* __restrict__ wl3,
        float* __restrict__ b1, float* __restrict__ b2, float* __restrict__ b3) {
    int br = blockIdx.x >> 8, ch = blockIdx.x & 255, tid = threadIdx.x;
    const float* w; const float* pb; ushort_t* wh; ushort_t* wl; float* bf; int KK;
    if (br == 0)      { w = w1; pb = pb1; wh = wh1; wl = wl1; bf = b1; KK = 9;  }
    else if (br == 1) { w = w2; pb = pb2; wh = wh2; wl = wl2; bf = b2; KK = 25; }
    else              { w = w3; pb = pb3; wh = wh3; wl = wl3; bf = b3; KK = 81; }
    const float* bnp = bnp_base + br * 512;
    __shared__ float tile[128 * 81];
    __shared__ float r2[2];
    int n = 128 * KK;
    const float* wrow = w + ch * n;
    for (int i = tid; i < n; i += 256) tile[i] = wrow[i];   // coalesced fp32 read
    __syncthreads();
    for (int j = tid; j < n; j += 256) {                    // coalesced u16 writes (c innermost)
        int uv = j >> 7, c = j & 127;
        float val = tile[c * KK + uv] * bnp[256 + c];       // stride KK odd -> conflict-free
        unsigned short h = f2bf(val);
        unsigned short lo = f2bf(val - bf2f(h));
        int oidx = uv * 32768 + (ch << 7) + c;
        wh[oidx] = h; wl[oidx] = lo;
    }
    float s = 0.f;
    if (tid < 128) {
        for (int uv = 0; uv < KK; ++uv) s += tile[tid * KK + uv];
        s *= bnp[384 + tid];
    }
    for (int off = 32; off; off >>= 1) s += __shfl_down(s, off);
    if (tid < 128 && (tid & 63) == 0) r2[tid >> 6] = s;
    __syncthreads();
    if (tid == 0) bf[ch] = pb[ch] + r2[0] + r2[1];
}

// ---------------- zero kernels for split-K accumulators ----------------
__global__ void zero_p3_kernel(float* __restrict__ p3) {
    ((float4*)p3)[blockIdx.x * 256 + threadIdx.x] = (float4){0.f, 0.f, 0.f, 0.f};
}
__global__ void zero_p21_kernel(float* __restrict__ p2, float* __restrict__ p1) {
    int blk = blockIdx.x;
    if (blk < 576) ((float4*)p2)[blk * 256 + threadIdx.x] = (float4){0.f, 0.f, 0.f, 0.f};
    else           ((float4*)p1)[(blk - 576) * 256 + threadIdx.x] = (float4){0.f, 0.f, 0.f, 0.f};
}

// ---------------- primary-caps conv as split-bf16 MFMA GEMM, split-K via atomicAdd ----------------
// 128(M) x 128(N) block tile, BK=32, 4 waves as 2x2; each wave 64x64 (4x4 of 16x16), 48 MFMA/iter.
// LDS: round-8-verified addressing (pitch 32 halves, XOR swizzle chunk^((row>>1)&3)) -> 0 bank conflicts.
// Rows r and r+64 share one thread's swizzle ((r+64)>>1 == r>>1 mod 4).
template<int S, int WO, int IHg, int IWg, int KS, int ZCH>
__global__ __launch_bounds__(256, 3) void prim_gemm_mfma(
        const ushort_t* __restrict__ yh, const ushort_t* __restrict__ yl,
        const ushort_t* __restrict__ wh, const ushort_t* __restrict__ wl,
        float* __restrict__ p) {
    __shared__ ushort_t Ash[128 * 32], Asl[128 * 32];
    __shared__ ushort_t Bsh[128 * 32], Bsl[128 * 32];
    int tid = threadIdx.x;
    int bm = blockIdx.x * 128, ch0 = blockIdx.y * 128;
    // staging roles: rows arow and arow+64 for both A and B; chunk c0 = tid&3 (8 halves)
    int arow = tid >> 2;
    int c0 = tid & 3;
    int sw0 = (c0 ^ ((arow >> 1) & 3)) * 8;
    int wA0 = arow * 32 + sw0;
    int wA1 = (arow + 64) * 32 + sw0;
    int m0 = bm + arow;
    int b0 = m0 / S, s0 = m0 % S;
    int abase0 = ((b0 * IHg + 2 * (s0 / WO)) * IWg + 2 * (s0 % WO)) * 128 + c0 * 8;
    int m1 = m0 + 64;
    int b1 = m1 / S, s1 = m1 % S;
    int abase1 = ((b1 * IHg + 2 * (s1 / WO)) * IWg + 2 * (s1 % WO)) * 128 + c0 * 8;
    int bbase0 = (ch0 + arow) * 128 + c0 * 8;
    int bbase1 = (ch0 + arow + 64) * 128 + c0 * 8;
    // compute roles: waves 2x2, wave (wm,wn) owns rows wm*64..+63, cols wn*64..+63
    int lane = tid & 63, wid = tid >> 6;
    int wm = wid & 1, wn = wid >> 1;
    int quad = lane >> 4, l16 = lane & 15;
    int aoffL[4], boffL[4];
    #pragma unroll
    for (int mi = 0; mi < 4; ++mi) {
        int row = wm * 64 + mi * 16 + l16;
        aoffL[mi] = row * 32 + ((quad ^ ((row >> 1) & 3)) * 8);
    }
    #pragma unroll
    for (int ni = 0; ni < 4; ++ni) {
        int row = wn * 64 + ni * 16 + l16;
        boffL[ni] = row * 32 + ((quad ^ ((row >> 1) & 3)) * 8);
    }
    f32x4 acc[4][4];
    #pragma unroll
    for (int mi = 0; mi < 4; ++mi)
        #pragma unroll
        for (int ni = 0; ni < 4; ++ni)
            acc[mi][ni] = (f32x4){0.f, 0.f, 0.f, 0.f};

    // k-chunk index kc = z*ZCH + t ; uv = kc>>2, cs = (kc&3)*32
    int kc = blockIdx.z * ZCH;
    int uv = kc >> 2, ci = kc & 3;
    int u = uv / KS, v = uv - u * KS;
    int aoff = (u * IWg + v) * 128 + (ci << 5);
    int boff = uv * 32768 + (ci << 5);
    int4 a0h = *reinterpret_cast<const int4*>(yh + abase0 + aoff);
    int4 a0l = *reinterpret_cast<const int4*>(yl + abase0 + aoff);
    int4 a1h = *reinterpret_cast<const int4*>(yh + abase1 + aoff);
    int4 a1l = *reinterpret_cast<const int4*>(yl + abase1 + aoff);
    int4 b0h = *reinterpret_cast<const int4*>(wh + bbase0 + boff);
    int4 b0l = *reinterpret_cast<const int4*>(wl + bbase0 + boff);
    int4 b1h = *reinterpret_cast<const int4*>(wh + bbase1 + boff);
    int4 b1l = *reinterpret_cast<const int4*>(wl + bbase1 + boff);

    for (int t = 0; t < ZCH; ++t) {
        __syncthreads();
        *reinterpret_cast<int4*>(&Ash[wA0]) = a0h;
        *reinterpret_cast<int4*>(&Asl[wA0]) = a0l;
        *reinterpret_cast<int4*>(&Ash[wA1]) = a1h;
        *reinterpret_cast<int4*>(&Asl[wA1]) = a1l;
        *reinterpret_cast<int4*>(&Bsh[wA0]) = b0h;
        *reinterpret_cast<int4*>(&Bsl[wA0]) = b0l;
        *reinterpret_cast<int4*>(&Bsh[wA1]) = b1h;
        *reinterpret_cast<int4*>(&Bsl[wA1]) = b1l;
        if (t + 1 < ZCH) {   // prefetch next chunk (uniform branch)
            ci = (ci + 1) & 3;
            if (ci == 0) { ++uv; ++v; if (v == KS) { v = 0; ++u; } }
            aoff = (u * IWg + v) * 128 + (ci << 5);
            boff = uv * 32768 + (ci << 5);
            a0h = *reinterpret_cast<const int4*>(yh + abase0 + aoff);
            a0l = *reinterpret_cast<const int4*>(yl + abase0 + aoff);
            a1h = *reinterpret_cast<const int4*>(yh + abase1 + aoff);
            a1l = *reinterpret_cast<const int4*>(yl + abase1 + aoff);
            b0h = *reinterpret_cast<const int4*>(wh + bbase0 + boff);
            b0l = *reinterpret_cast<const int4*>(wl + bbase0 + boff);
            b1h = *reinterpret_cast<const int4*>(wh + bbase1 + boff);
            b1l = *reinterpret_cast<const int4*>(wl + bbase1 + boff);
        }
        __syncthreads();
        short8 bh[4], bl[4];
        #pragma unroll
        for (int ni = 0; ni < 4; ++ni) {
            bh[ni] = *reinterpret_cast<const short8*>(&Bsh[boffL[ni]]);
            bl[ni] = *reinterpret_cast<const short8*>(&Bsl[boffL[ni]]);
        }
        #pragma unroll
        for (int mi = 0; mi < 4; ++mi) {
            short8 ah = *reinterpret_cast<const short8*>(&Ash[aoffL[mi]]);
            short8 al = *reinterpret_cast<const short8*>(&Asl[aoffL[mi]]);
            #pragma unroll
            for (int ni = 0; ni < 4; ++ni) {
                acc[mi][ni] = __builtin_amdgcn_mfma_f32_16x16x32_bf16(ah, bh[ni], acc[mi][ni], 0, 0, 0);
                acc[mi][ni] = __builtin_amdgcn_mfma_f32_16x16x32_bf16(al, bh[ni], acc[mi][ni], 0, 0, 0);
                acc[mi][ni] = __builtin_amdgcn_mfma_f32_16x16x32_bf16(ah, bl[ni], acc[mi][ni], 0, 0, 0);
            }
        }
    }
    // C/D layout (measured m89): col = lane&15, row = quad*4 + reg
    #pragma unroll
    for (int mi = 0; mi < 4; ++mi)
        #pragma unroll
        for (int ni = 0; ni < 4; ++ni) {
            int col = ch0 + wn * 64 + ni * 16 + l16;
            #pragma unroll
            for (int reg = 0; reg < 4; ++reg) {
                int row = bm + wm * 64 + mi * 16 + quad * 4 + reg;
                atomicAdd(p + (size_t)row * 256 + col, acc[mi][ni][reg]);
            }
        }
}

// ---------------- squash primary caps (all branches): p(B*S,256)+bias -> u(B,32*S,8) ----------------
__global__ void squash_all_kernel(const float* __restrict__ p1, const float* __restrict__ p2,
                                  const float* __restrict__ p3,
                                  const float* __restrict__ bias1, const float* __restrict__ bias2,
                                  const float* __restrict__ bias3,
                                  float* __restrict__ u1, float* __restrict__ u2,
                                  float* __restrict__ u3) {
    int blk = blockIdx.x;
    const float* p; const float* bias; float* u; int S;
    if (blk < 128)      { p = p1; bias = bias1; u = u1; S = 4; }
    else if (blk < 416) { p = p2; bias = bias2; u = u2; S = 9;  blk -= 128; }
    else                { p = p3; bias = bias3; u = u3; S = 36; blk -= 416; }
    int idx = blk * 256 + threadIdx.x;   // over 256*S*32, o innermost
    int o = idx & 31, rest = idx >> 5;
    int s = rest % S, b = rest / S;
    const float* pp = p + (size_t)(b * S + s) * 256 + o;
    float t[8]; float sn = 0.f;
    #pragma unroll
    for (int i = 0; i < 8; ++i) { t[i] = pp[i * 32] + bias[o + i * 32]; sn += t[i] * t[i]; }
    float f = sn / ((1.f + sn) * sqrtf(sn + SQ_EPS));
    float* up = u + (size_t)(b * (32 * S) + o * S + s) * 8;
    float4 w0 = {t[0] * f, t[1] * f, t[2] * f, t[3] * f};
    float4 w1 = {t[4] * f, t[5] * f, t[6] * f, t[7] * f};
    *reinterpret_cast<float4*>(up) = w0;
    *reinterpret_cast<float4*>(up + 4) = w1;
}

// ---------------- routing weights -> bf16 (after gemm3 frees yl3 region) ----------------
__global__ void rwtrans_kernel(const float* __restrict__ w1, const float* __restrict__ w2,
                               const float* __restrict__ w3,
                               ushort_t* __restrict__ o1, ushort_t* __restrict__ o2,
                               ushort_t* __restrict__ o3) {
    int idx = blockIdx.x * 256 + threadIdx.x;  // 7840*256 = 2,007,040 exact
    const float* src; ushort_t* dst; int off;
    if (idx < 163840)      { src = w1; dst = o1; off = idx; }
    else if (idx < 532480) { src = w2; dst = o2; off = idx - 163840; }
    else                   { src = w3; dst = o3; off = idx - 532480; }
    dst[off] = f2bf(src[off]);
}

// ---------------- dynamic routing (3 iters): priors packed bf16x2 in LDS (transposed, conflict-free),
//                  blog in registers, weights bf16 (slab fits per-XCD L2) ----------------
template<int R>
__global__ __launch_bounds__(256, 4) void routing_lds_kernel(
        const float* __restrict__ u, const ushort_t* __restrict__ rwb,
        float* __restrict__ lens) {
    constexpr int KMAX = (R + 255) / 256;
    int n = blockIdx.x, b = blockIdx.y;
    int tid = threadIdx.x, lane = tid & 63, wv = tid >> 6;
    __shared__ unsigned int pri[8 * R];   // pri[j*R + r] = bf16(po[2j]) | bf16(po[2j+1])<<16
    __shared__ float red[4 * 16];
    __shared__ float vsh[16];
    __shared__ float sred[4];
    float blog[KMAX];
    #pragma unroll
    for (int k = 0; k < KMAX; ++k) {
        blog[k] = 0.f;
        int r = tid + k * 256;
        if (r < R) {
            const float4* up = (const float4*)(u + ((size_t)b * R + r) * 8);
            float4 ua = up[0], ub2 = up[1];
            float uu[8] = {ua.x, ua.y, ua.z, ua.w, ub2.x, ub2.y, ub2.z, ub2.w};
            const ushort_t* wr = rwb + ((size_t)n * R + r) * 128;
            float po[16] = {};
            #pragma unroll
            for (int i = 0; i < 8; ++i) {
                short8 wa = *reinterpret_cast<const short8*>(wr + i * 16);
                short8 wb = *reinterpret_cast<const short8*>(wr + i * 16 + 8);
                #pragma unroll
                for (int o = 0; o < 8; ++o) po[o]     += uu[i] * bf2f((unsigned short)wa[o]);
                #pragma unroll
                for (int o = 0; o < 8; ++o) po[8 + o] += uu[i] * bf2f((unsigned short)wb[o]);
            }
            #pragma unroll
            for (int j = 0; j < 8; ++j)
                pri[j * R + r] = (unsigned int)f2bf(po[2*j]) | ((unsigned int)f2bf(po[2*j+1]) << 16);
        }
    }
    __syncthreads();
    float v[16];
    for (int it = 0; it < 3; ++it) {
        float lmax = -1e30f;
        #pragma unroll
        for (int k = 0; k < KMAX; ++k)
            if (tid + k * 256 < R) lmax = fmaxf(lmax, blog[k]);
        for (int off = 32; off; off >>= 1) lmax = fmaxf(lmax, __shfl_down(lmax, off));
        if (lane == 0) sred[wv] = lmax;
        __syncthreads();
        float mx = fmaxf(fmaxf(sred[0], sred[1]), fmaxf(sred[2], sred[3]));
        __syncthreads();
        float ce[KMAX];
        float lsum = 0.f;
        #pragma unroll
        for (int k = 0; k < KMAX; ++k) {
            ce[k] = (tid + k * 256 < R) ? expf(blog[k] - mx) : 0.f;
            lsum += ce[k];
        }
        for (int off = 32; off; off >>= 1) lsum += __shfl_down(lsum, off);
        if (lane == 0) sred[wv] = lsum;
        __syncthreads();
        float inv = 1.f / (sred[0] + sred[1] + sred[2] + sred[3]);
        float sacc[16] = {};
        #pragma unroll
        for (int k = 0; k < KMAX; ++k) {
            int r = tid + k * 256;
            if (r < R) {
                float c = ce[k] * inv;
                #pragma unroll
                for (int j = 0; j < 8; ++j) {
                    unsigned int w = pri[j * R + r];
                    sacc[2*j]   += c * bf2f((unsigned short)(w & 0xffffu));
                    sacc[2*j+1] += c * bf2f((unsigned short)(w >> 16));
                }
            }
        }
        #pragma unroll
        for (int o = 0; o < 16; ++o) {
            float xv = sacc[o];
            for (int off = 32; off; off >>= 1) xv += __shfl_down(xv, off);
            if (lane == 0) red[wv * 16 + o] = xv;
        }
        __syncthreads();
        if (tid < 16) vsh[tid] = red[tid] + red[16 + tid] + red[32 + tid] + red[48 + tid];
        __syncthreads();
        if (tid == 0) {
            float sn = 0.f;
            #pragma unroll
            for (int o = 0; o < 16; ++o) sn += vsh[o] * vsh[o];
            float f = sn / ((1.f + sn) * sqrtf(sn + SQ_EPS));
            #pragma unroll
            for (int o = 0; o < 16; ++o) vsh[o] *= f;
        }
        __syncthreads();
        #pragma unroll
        for (int o = 0; o < 16; ++o) v[o] = vsh[o];
        if (it < 2) {
            #pragma unroll
            for (int k = 0; k < KMAX; ++k) {
                int r = tid + k * 256;
                if (r < R) {
                    float dot = 0.f;
                    #pragma unroll
                    for (int j = 0; j < 8; ++j) {
                        unsigned int w = pri[j * R + r];
                        dot += bf2f((unsigned short)(w & 0xffffu)) * v[2*j];
                        dot += bf2f((unsigned short)(w >> 16)) * v[2*j+1];
                    }
                    blog[k] += dot;
                }
            }
        }
    }
    if (tid == 0) {
        float sn = 0.f;
        #pragma unroll
        for (int o = 0; o < 16; ++o) sn += v[o] * v[o];
        lens[b * 10 + n] = sqrtf(sn + SQ_EPS);
    }
}

// ---------------- final: softmax over classes of l1+l2+l3 ----------------
__global__ void final_softmax_kernel(const float* __restrict__ l1, const float* __restrict__ l2,
                                     const float* __restrict__ l3, float* __restrict__ out) {
    int b = threadIdx.x;
    float v[10]; float mx = -1e30f;
    #pragma unroll
    for (int n = 0; n < 10; ++n) {
        v[n] = l1[b * 10 + n] + l2[b * 10 + n] + l3[b * 10 + n];
        mx = fmaxf(mx, v[n]);
    }
    float s = 0.f;
    #pragma unroll
    for (int n = 0; n < 10; ++n) { v[n] = expf(v[n] - mx); s += v[n]; }
    float inv = 1.f / s;
    #pragma unroll
    for (int n = 0; n < 10; ++n) out[b * 10 + n] = v[n] * inv;
}

extern "C" void kernel_launch(void* const* d_in, const int* in_sizes, int n_in,
                              void* d_out, int out_size, void* d_ws, size_t ws_size,
                              hipStream_t stream) {
    const float* x   = (const float*)d_in[0];
    const float* c1w = (const float*)d_in[1];
    const float* c1b = (const float*)d_in[2];
    const float* p1w = (const float*)d_in[3];
    const float* p1b = (const float*)d_in[4];
    const float* d1w = (const float*)d_in[5];
    const float* c2w = (const float*)d_in[6];
    const float* c2b = (const float*)d_in[7];
    const float* p2w = (const float*)d_in[8];
    const float* p2b = (const float*)d_in[9];
    const float* d2w = (const float*)d_in[10];
    const float* c3w = (const float*)d_in[11];
    const float* c3b = (const float*)d_in[12];
    const float* p3w = (const float*)d_in[13];
    const float* p3b = (const float*)d_in[14];
    const float* d3w = (const float*)d_in[15];

    float* ws = (float*)d_ws;
    // region layout (float units) — total 23,403,520 floats = 93.6 MB
    float* x2    = ws + 0;          // 50176
    float* x1    = ws + 50176;      // 12544
    float* yh1f  = ws + 62720;      // 409600   (819200 halves)  [aliased by u1 later]
    float* yl1f  = ws + 472320;     // 409600
    float* yh2f  = ws + 881920;     // 1638400  [aliased by u2 later]
    float* yl2f  = ws + 2520320;    // 1638400
    float* yh3f  = ws + 4158720;    // 6553600  [aliased by u3 later]
    float* yl3f  = ws + 10712320;   // 6553600  [aliased by rwb after gemm3]
    float* wh1f  = ws + 17265920;   // 147456
    float* wl1f  = ws + 17413376;   // 147456
    float* wh2f  = ws + 17560832;   // 409600
    float* wl2f  = ws + 17970432;   // 409600
    float* wh3f  = ws + 18380032;   // 1327104  [aliased by p2 later]
    float* wl3f  = ws + 19707136;   // 1327104  [aliased by p1 later]
    float* p3    = ws + 21034240;   // 2359296
    float* bnp1  = ws + 23393536;   // 512 (x3: bnp2, bnp3 follow)
    float* bias1 = ws + 23395072;   // 256
    float* bias2 = ws + 23395328;   // 256
    float* bias3 = ws + 23395584;   // 256
    float* l1    = ws + 23395840;   // 2560
    float* l2    = ws + 23398400;   // 2560
    float* l3    = ws + 23400960;   // 2560

    ushort_t* yh1 = (ushort_t*)yh1f; ushort_t* yl1 = (ushort_t*)yl1f;
    ushort_t* yh2 = (ushort_t*)yh2f; ushort_t* yl2 = (ushort_t*)yl2f;
    ushort_t* yh3 = (ushort_t*)yh3f; ushort_t* yl3 = (ushort_t*)yl3f;
    ushort_t* wh1 = (ushort_t*)wh1f; ushort_t* wl1 = (ushort_t*)wl1f;
    ushort_t* wh2 = (ushort_t*)wh2f; ushort_t* wl2 = (ushort_t*)wl2f;
    ushort_t* wh3 = (ushort_t*)wh3f; ushort_t* wl3 = (ushort_t*)wl3f;
    // aliases (safe by stream ordering):
    float* u1 = yh1f;   // written after gemm1 reads yh1
    float* u2 = yh2f;
    float* u3 = yh3f;
    float* p2 = wh3f;   // written (zero+atomic) after gemm3 reads wh3
    float* p1 = wl3f;
    // bf16 routing weights live in dead yl3 region (converted after gemm3):
    ushort_t* rwb1 = (ushort_t*)yl3f;          // 163840 halves
    ushort_t* rwb2 = rwb1 + 163840;            // 368640 halves
    ushort_t* rwb3 = rwb2 + 368640;            // 1474560 halves (total 2,007,040 <= 13,107,200)

    pool_kernel<<<256, 256, 0, stream>>>(x, x2, x1, bnp1);

    conv_split_kernel<7, 7, 3, 5, 5><<<256, 256, 0, stream>>>(x1, c1w, c1b, yh1, yl1, bnp1);
    conv_split_kernel<14, 14, 5, 10, 10><<<256, 256, 0, stream>>>(x2, c2w, c2b, yh2, yl2, bnp1 + 512);
    conv_split_kernel<28, 28, 9, 20, 20><<<256, 256, 0, stream>>>(x, c3w, c3b, yh3, yl3, bnp1 + 1024);

    bn_final_kernel<<<3, 128, 0, stream>>>(bnp1);

    wtrans_bias_kernel<<<768, 256, 0, stream>>>(p1w, p2w, p3w, bnp1, p1b, p2b, p3b,
                                                wh1, wl1, wh2, wl2, wh3, wl3,
                                                bias1, bias2, bias3);

    // gemm3 (split-K, atomic) first: afterwards wh3/wl3 dead (reused for p2/p1), yl3 dead (rwb)
    zero_p3_kernel<<<2304, 256, 0, stream>>>(p3);
    prim_gemm_mfma<36, 6, 20, 20, 9, 54><<<dim3(72, 2, 6), 256, 0, stream>>>(yh3, yl3, wh3, wl3, p3);
    rwtrans_kernel<<<7840, 256, 0, stream>>>(d1w, d2w, d3w, rwb1, rwb2, rwb3);
    zero_p21_kernel<<<832, 256, 0, stream>>>(p2, p1);
    prim_gemm_mfma<9, 3, 10, 10, 5, 25><<<dim3(18, 2, 4), 256, 0, stream>>>(yh2, yl2, wh2, wl2, p2);
    prim_gemm_mfma<4, 2, 5, 5, 3, 9><<<dim3(8, 2, 4), 256, 0, stream>>>(yh1, yl1, wh1, wl1, p1);

    squash_all_kernel<<<1568, 256, 0, stream>>>(p1, p2, p3, bias1, bias2, bias3, u1, u2, u3);

    routing_lds_kernel<128><<<dim3(10, 256), 256, 0, stream>>>(u1, rwb1, l1);
    routing_lds_kernel<288><<<dim3(10, 256), 256, 0, stream>>>(u2, rwb2, l2);
    routing_lds_kernel<1152><<<dim3(10, 256), 256, 0, stream>>>(u3, rwb3, l3);

    final_softmax_kernel<<<1, 256, 0, stream>>>(l1, l2, l3, (float*)d_out);
}

// Round 12
// 581.327 us; speedup vs baseline: 2.2608x; 1.1018x over previous
//
#include <hip/hip_runtime.h>
#include <math.h>

#define SQ_EPS 1e-12f
#define BN_EPS 1e-5f

typedef short short8 __attribute__((ext_vector_type(8)));
typedef float f32x4 __attribute__((ext_vector_type(4)));
typedef unsigned short ushort_t;

__device__ inline unsigned short f2bf(float x) {
    unsigned int u = __float_as_uint(x);
    unsigned int r = (u + 0x7fffu + ((u >> 16) & 1u)) >> 16;   // round-to-nearest-even
    return (unsigned short)r;
}
__device__ inline float bf2f(unsigned short h) {
    return __uint_as_float(((unsigned int)h) << 16);
}

// ================= fused conv (3 branches, pooling inline) =================
// partial[b*256 + c] = per-block BN sum, [b*256+128+c] = sumsq (no atomics, no pre-zero)
template<int IH, int IW, int KS, int OH, int OW>
__device__ void conv_body(const float* __restrict__ w, const float* __restrict__ bias,
                          ushort_t* __restrict__ yh, ushort_t* __restrict__ yl,
                          float* __restrict__ partial,
                          int b, int tid, float* s_img, float* s_w, float* s_red) {
    constexpr int KK = KS * KS;
    constexpr int OS = OH * OW;
    for (int i = tid; i < 128 * KK; i += 256) s_w[i] = w[i];
    __syncthreads();
    int c = tid & 127, half = tid >> 7;
    float bias_c = bias[c];
    float bsum = 0.f, bsq = 0.f;
    for (int r = half; r < OH; r += 2) {
        float acc[OW];
        #pragma unroll
        for (int j = 0; j < OW; ++j) acc[j] = bias_c;
        for (int u = 0; u < KS; ++u) {
            float rg[OW + KS - 1];
            #pragma unroll
            for (int j = 0; j < OW + KS - 1; ++j) rg[j] = s_img[(r + u) * IW + j];
            #pragma unroll
            for (int v = 0; v < KS; ++v) {
                float wv = s_w[c * KK + u * KS + v];
                #pragma unroll
                for (int j = 0; j < OW; ++j) acc[j] += wv * rg[j + v];
            }
        }
        #pragma unroll
        for (int j = 0; j < OW; ++j) {
            float val = fmaxf(acc[j], 0.f);
            bsum += val; bsq += val * val;
            unsigned short h = f2bf(val);
            unsigned short lo = f2bf(val - bf2f(h));
            int oidx = ((b * OS) + r * OW + j) * 128 + c;
            yh[oidx] = h; yl[oidx] = lo;
        }
    }
    s_red[tid] = bsum; __syncthreads();
    if (tid < 128) partial[b * 256 + c] = s_red[tid] + s_red[tid + 128];
    __syncthreads();
    s_red[tid] = bsq; __syncthreads();
    if (tid < 128) partial[b * 256 + 128 + c] = s_red[tid] + s_red[tid + 128];
}

__global__ __launch_bounds__(256) void conv_all_kernel(
        const float* __restrict__ img,
        const float* __restrict__ c1w, const float* __restrict__ c1b,
        const float* __restrict__ c2w, const float* __restrict__ c2b,
        const float* __restrict__ c3w, const float* __restrict__ c3b,
        ushort_t* __restrict__ yh1, ushort_t* __restrict__ yl1,
        ushort_t* __restrict__ yh2, ushort_t* __restrict__ yl2,
        ushort_t* __restrict__ yh3, ushort_t* __restrict__ yl3,
        float* __restrict__ partial_base) {
    __shared__ float s_img[784];
    __shared__ float s_tmp[196];
    __shared__ float s_w[128 * 81];
    __shared__ float s_red[256];
    int br = blockIdx.x >> 8, b = blockIdx.x & 255, tid = threadIdx.x;
    const float* im = img + b * 784;
    for (int i = tid; i < 784; i += 256) s_img[i] = im[i];
    __syncthreads();
    if (br <= 1) {
        for (int idx = tid; idx < 196; idx += 256) {
            int i = idx / 14, j = idx % 14;
            s_tmp[idx] = 0.25f * (s_img[(2*i)*28 + 2*j]   + s_img[(2*i)*28 + 2*j + 1] +
                                  s_img[(2*i+1)*28 + 2*j] + s_img[(2*i+1)*28 + 2*j + 1]);
        }
        __syncthreads();
        if (br == 0) {
            for (int idx = tid; idx < 49; idx += 256) {
                int i = idx / 7, j = idx % 7;
                s_img[idx] = 0.25f * (s_tmp[(2*i)*14 + 2*j]   + s_tmp[(2*i)*14 + 2*j + 1] +
                                      s_tmp[(2*i+1)*14 + 2*j] + s_tmp[(2*i+1)*14 + 2*j + 1]);
            }
        } else {
            for (int idx = tid; idx < 196; idx += 256) s_img[idx] = s_tmp[idx];
        }
        __syncthreads();
    }
    if (br == 0)      conv_body<7, 7, 3, 5, 5>(c1w, c1b, yh1, yl1, partial_base, b, tid, s_img, s_w, s_red);
    else if (br == 1) conv_body<14, 14, 5, 10, 10>(c2w, c2b, yh2, yl2, partial_base + 65536, b, tid, s_img, s_w, s_red);
    else              conv_body<28, 28, 9, 20, 20>(c3w, c3b, yh3, yl3, partial_base + 131072, b, tid, s_img, s_w, s_red);
}

// ---------------- finalize BN from per-block partials ----------------
__global__ void bn_final_kernel(const float* __restrict__ partial_base, float* __restrict__ bnp_base) {
    int br = blockIdx.x;
    const float* pp = partial_base + br * 65536;
    float* bnp = bnp_base + br * 512;
    float N = (br == 0) ? 6400.f : ((br == 1) ? 25600.f : 102400.f);
    int c = threadIdx.x;  // 128
    float s = 0.f, q = 0.f;
    for (int blk = 0; blk < 256; ++blk) {
        s += pp[blk * 256 + c];
        q += pp[blk * 256 + 128 + c];
    }
    float mean = s / N;
    float var = q / N - mean * mean;
    float inv = rsqrtf(var + BN_EPS);
    bnp[256 + c] = inv;
    bnp[384 + c] = -mean * inv;
}

// ---------------- weight transform + bias fold + p3 zeroing (fused) ----------------
__global__ __launch_bounds__(256) void wtrans_zero_kernel(
        const float* __restrict__ w1, const float* __restrict__ w2,
        const float* __restrict__ w3, const float* __restrict__ bnp_base,
        const float* __restrict__ pb1, const float* __restrict__ pb2,
        const float* __restrict__ pb3,
        ushort_t* __restrict__ wh1, ushort_t* __restrict__ wl1,
        ushort_t* __restrict__ wh2, ushort_t* __restrict__ wl2,
        ushort_t* __restrict__ wh3, ushort_t* __restrict__ wl3,
        float* __restrict__ b1, float* __restrict__ b2, float* __restrict__ b3,
        float* __restrict__ p3zero) {
    __shared__ float tile[128 * 81];
    __shared__ float r2[2];
    int blk = blockIdx.x, tid = threadIdx.x;
    if (blk >= 768) {   // zero p3: 2304 blocks x 256 x float4 = 2,359,296 floats
        ((float4*)p3zero)[(blk - 768) * 256 + tid] = (float4){0.f, 0.f, 0.f, 0.f};
        return;
    }
    int br = blk >> 8, ch = blk & 255;
    const float* w; const float* pb; ushort_t* wh; ushort_t* wl; float* bf; int KK;
    if (br == 0)      { w = w1; pb = pb1; wh = wh1; wl = wl1; bf = b1; KK = 9;  }
    else if (br == 1) { w = w2; pb = pb2; wh = wh2; wl = wl2; bf = b2; KK = 25; }
    else              { w = w3; pb = pb3; wh = wh3; wl = wl3; bf = b3; KK = 81; }
    const float* bnp = bnp_base + br * 512;
    int n = 128 * KK;
    const float* wrow = w + ch * n;
    for (int i = tid; i < n; i += 256) tile[i] = wrow[i];   // coalesced fp32 read
    __syncthreads();
    for (int j = tid; j < n; j += 256) {                    // coalesced u16 writes (c innermost)
        int uv = j >> 7, c = j & 127;
        float val = tile[c * KK + uv] * bnp[256 + c];       // stride KK odd -> conflict-free
        unsigned short h = f2bf(val);
        unsigned short lo = f2bf(val - bf2f(h));
        int oidx = uv * 32768 + (ch << 7) + c;
        wh[oidx] = h; wl[oidx] = lo;
    }
    float s = 0.f;
    if (tid < 128) {
        for (int uv = 0; uv < KK; ++uv) s += tile[tid * KK + uv];
        s *= bnp[384 + tid];
    }
    for (int off = 32; off; off >>= 1) s += __shfl_down(s, off);
    if (tid < 128 && (tid & 63) == 0) r2[tid >> 6] = s;
    __syncthreads();
    if (tid == 0) bf[ch] = pb[ch] + r2[0] + r2[1];
}

// ================= split-bf16 MFMA GEMM body (device fn) =================
// 128x128 tile, BK=32, 4 waves 2x2 (wave 64x64 = 4x4 of 16x16), split-K atomics.
// LDS: round-8-verified addressing (pitch 32 halves, XOR swizzle chunk^((row>>1)&3)) -> 0 conflicts.
template<int S, int WO, int IHg, int IWg, int KS, int ZCH>
__device__ void gemm_body(const ushort_t* __restrict__ yh, const ushort_t* __restrict__ yl,
                          const ushort_t* __restrict__ wh, const ushort_t* __restrict__ wl,
                          float* __restrict__ p, int bx, int by, int bz, int tid,
                          ushort_t* Ash, ushort_t* Asl, ushort_t* Bsh, ushort_t* Bsl) {
    int bm = bx * 128, ch0 = by * 128;
    int arow = tid >> 2;
    int c0 = tid & 3;
    int sw0 = (c0 ^ ((arow >> 1) & 3)) * 8;
    int wA0 = arow * 32 + sw0;
    int wA1 = (arow + 64) * 32 + sw0;
    int m0 = bm + arow;
    int b0 = m0 / S, s0 = m0 % S;
    int abase0 = ((b0 * IHg + 2 * (s0 / WO)) * IWg + 2 * (s0 % WO)) * 128 + c0 * 8;
    int m1 = m0 + 64;
    int b1 = m1 / S, s1 = m1 % S;
    int abase1 = ((b1 * IHg + 2 * (s1 / WO)) * IWg + 2 * (s1 % WO)) * 128 + c0 * 8;
    int bbase0 = (ch0 + arow) * 128 + c0 * 8;
    int bbase1 = (ch0 + arow + 64) * 128 + c0 * 8;
    int lane = tid & 63, wid = tid >> 6;
    int wm = wid & 1, wn = wid >> 1;
    int quad = lane >> 4, l16 = lane & 15;
    int aoffL[4], boffL[4];
    #pragma unroll
    for (int mi = 0; mi < 4; ++mi) {
        int row = wm * 64 + mi * 16 + l16;
        aoffL[mi] = row * 32 + ((quad ^ ((row >> 1) & 3)) * 8);
    }
    #pragma unroll
    for (int ni = 0; ni < 4; ++ni) {
        int row = wn * 64 + ni * 16 + l16;
        boffL[ni] = row * 32 + ((quad ^ ((row >> 1) & 3)) * 8);
    }
    f32x4 acc[4][4];
    #pragma unroll
    for (int mi = 0; mi < 4; ++mi)
        #pragma unroll
        for (int ni = 0; ni < 4; ++ni)
            acc[mi][ni] = (f32x4){0.f, 0.f, 0.f, 0.f};

    int kc = bz * ZCH;
    int uv = kc >> 2, ci = kc & 3;
    int u = uv / KS, v = uv - u * KS;
    int aoff = (u * IWg + v) * 128 + (ci << 5);
    int boff = uv * 32768 + (ci << 5);
    int4 a0h = *reinterpret_cast<const int4*>(yh + abase0 + aoff);
    int4 a0l = *reinterpret_cast<const int4*>(yl + abase0 + aoff);
    int4 a1h = *reinterpret_cast<const int4*>(yh + abase1 + aoff);
    int4 a1l = *reinterpret_cast<const int4*>(yl + abase1 + aoff);
    int4 b0h = *reinterpret_cast<const int4*>(wh + bbase0 + boff);
    int4 b0l = *reinterpret_cast<const int4*>(wl + bbase0 + boff);
    int4 b1h = *reinterpret_cast<const int4*>(wh + bbase1 + boff);
    int4 b1l = *reinterpret_cast<const int4*>(wl + bbase1 + boff);

    for (int t = 0; t < ZCH; ++t) {
        __syncthreads();
        *reinterpret_cast<int4*>(&Ash[wA0]) = a0h;
        *reinterpret_cast<int4*>(&Asl[wA0]) = a0l;
        *reinterpret_cast<int4*>(&Ash[wA1]) = a1h;
        *reinterpret_cast<int4*>(&Asl[wA1]) = a1l;
        *reinterpret_cast<int4*>(&Bsh[wA0]) = b0h;
        *reinterpret_cast<int4*>(&Bsl[wA0]) = b0l;
        *reinterpret_cast<int4*>(&Bsh[wA1]) = b1h;
        *reinterpret_cast<int4*>(&Bsl[wA1]) = b1l;
        if (t + 1 < ZCH) {   // prefetch next chunk (uniform branch)
            ci = (ci + 1) & 3;
            if (ci == 0) { ++uv; ++v; if (v == KS) { v = 0; ++u; } }
            aoff = (u * IWg + v) * 128 + (ci << 5);
            boff = uv * 32768 + (ci << 5);
            a0h = *reinterpret_cast<const int4*>(yh + abase0 + aoff);
            a0l = *reinterpret_cast<const int4*>(yl + abase0 + aoff);
            a1h = *reinterpret_cast<const int4*>(yh + abase1 + aoff);
            a1l = *reinterpret_cast<const int4*>(yl + abase1 + aoff);
            b0h = *reinterpret_cast<const int4*>(wh + bbase0 + boff);
            b0l = *reinterpret_cast<const int4*>(wl + bbase0 + boff);
            b1h = *reinterpret_cast<const int4*>(wh + bbase1 + boff);
            b1l = *reinterpret_cast<const int4*>(wl + bbase1 + boff);
        }
        __syncthreads();
        short8 bh[4], bl[4];
        #pragma unroll
        for (int ni = 0; ni < 4; ++ni) {
            bh[ni] = *reinterpret_cast<const short8*>(&Bsh[boffL[ni]]);
            bl[ni] = *reinterpret_cast<const short8*>(&Bsl[boffL[ni]]);
        }
        #pragma unroll
        for (int mi = 0; mi < 4; ++mi) {
            short8 ah = *reinterpret_cast<const short8*>(&Ash[aoffL[mi]]);
            short8 al = *reinterpret_cast<const short8*>(&Asl[aoffL[mi]]);
            #pragma unroll
            for (int ni = 0; ni < 4; ++ni) {
                acc[mi][ni] = __builtin_amdgcn_mfma_f32_16x16x32_bf16(ah, bh[ni], acc[mi][ni], 0, 0, 0);
                acc[mi][ni] = __builtin_amdgcn_mfma_f32_16x16x32_bf16(al, bh[ni], acc[mi][ni], 0, 0, 0);
                acc[mi][ni] = __builtin_amdgcn_mfma_f32_16x16x32_bf16(ah, bl[ni], acc[mi][ni], 0, 0, 0);
            }
        }
    }
    // C/D layout (measured m89): col = lane&15, row = quad*4 + reg
    #pragma unroll
    for (int mi = 0; mi < 4; ++mi)
        #pragma unroll
        for (int ni = 0; ni < 4; ++ni) {
            int col = ch0 + wn * 64 + ni * 16 + l16;
            #pragma unroll
            for (int reg = 0; reg < 4; ++reg) {
                int row = bm + wm * 64 + mi * 16 + quad * 4 + reg;
                atomicAdd(p + (size_t)row * 256 + col, acc[mi][ni][reg]);
            }
        }
}

// gemm3: grid (72, 2, 6)
__global__ __launch_bounds__(256, 3) void gemm3_kernel(
        const ushort_t* __restrict__ yh, const ushort_t* __restrict__ yl,
        const ushort_t* __restrict__ wh, const ushort_t* __restrict__ wl,
        float* __restrict__ p) {
    __shared__ ushort_t Ash[128 * 32], Asl[128 * 32];
    __shared__ ushort_t Bsh[128 * 32], Bsl[128 * 32];
    gemm_body<36, 6, 20, 20, 9, 54>(yh, yl, wh, wl, p,
                                    blockIdx.x, blockIdx.y, blockIdx.z, threadIdx.x,
                                    Ash, Asl, Bsh, Bsl);
}

// gemm2 + gemm1 fused: blocks 0..359 = branch2 (18x2x10, ZCH=10); 360..503 = branch1 (8x2x9, ZCH=4)
__global__ __launch_bounds__(256, 3) void gemm21_kernel(
        const ushort_t* __restrict__ yh2, const ushort_t* __restrict__ yl2,
        const ushort_t* __restrict__ wh2, const ushort_t* __restrict__ wl2, float* __restrict__ p2,
        const ushort_t* __restrict__ yh1, const ushort_t* __restrict__ yl1,
        const ushort_t* __restrict__ wh1, const ushort_t* __restrict__ wl1, float* __restrict__ p1) {
    __shared__ ushort_t Ash[128 * 32], Asl[128 * 32];
    __shared__ ushort_t Bsh[128 * 32], Bsl[128 * 32];
    int blk = blockIdx.x, tid = threadIdx.x;
    if (blk < 360) {
        int z = blk / 36, rem = blk % 36, y = rem / 18, x = rem % 18;
        gemm_body<9, 3, 10, 10, 5, 10>(yh2, yl2, wh2, wl2, p2, x, y, z, tid, Ash, Asl, Bsh, Bsl);
    } else {
        int b = blk - 360;
        int z = b / 16, rem = b % 16, y = rem / 8, x = rem % 8;
        gemm_body<4, 2, 5, 5, 3, 4>(yh1, yl1, wh1, wl1, p1, x, y, z, tid, Ash, Asl, Bsh, Bsl);
    }
}

// ---------------- squash primary caps (all branches): p(B*S,256)+bias -> u(B,32*S,8) ----------------
__global__ void squash_all_kernel(const float* __restrict__ p1, const float* __restrict__ p2,
                                  const float* __restrict__ p3,
                                  const float* __restrict__ bias1, const float* __restrict__ bias2,
                                  const float* __restrict__ bias3,
                                  float* __restrict__ u1, float* __restrict__ u2,
                                  float* __restrict__ u3) {
    int blk = blockIdx.x;
    const float* p; const float* bias; float* u; int S;
    if (blk < 128)      { p = p1; bias = bias1; u = u1; S = 4; }
    else if (blk < 416) { p = p2; bias = bias2; u = u2; S = 9;  blk -= 128; }
    else                { p = p3; bias = bias3; u = u3; S = 36; blk -= 416; }
    int idx = blk * 256 + threadIdx.x;   // over 256*S*32, o innermost
    int o = idx & 31, rest = idx >> 5;
    int s = rest % S, b = rest / S;
    const float* pp = p + (size_t)(b * S + s) * 256 + o;
    float t[8]; float sn = 0.f;
    #pragma unroll
    for (int i = 0; i < 8; ++i) { t[i] = pp[i * 32] + bias[o + i * 32]; sn += t[i] * t[i]; }
    float f = sn / ((1.f + sn) * sqrtf(sn + SQ_EPS));
    float* up = u + (size_t)(b * (32 * S) + o * S + s) * 8;
    float4 w0 = {t[0] * f, t[1] * f, t[2] * f, t[3] * f};
    float4 w1 = {t[4] * f, t[5] * f, t[6] * f, t[7] * f};
    *reinterpret_cast<float4*>(up) = w0;
    *reinterpret_cast<float4*>(up + 4) = w1;
}

// ---------------- routing weights -> bf16 + zero p2/p1 (fused) ----------------
__global__ void rwtrans_zero_kernel(const float* __restrict__ w1, const float* __restrict__ w2,
                                    const float* __restrict__ w3,
                                    ushort_t* __restrict__ o1, ushort_t* __restrict__ o2,
                                    ushort_t* __restrict__ o3,
                                    float* __restrict__ p2, float* __restrict__ p1) {
    int blk = blockIdx.x;
    if (blk >= 7840) {   // zero p2 (576 blocks) then p1 (256 blocks)
        int zb = blk - 7840;
        if (zb < 576) ((float4*)p2)[zb * 256 + threadIdx.x] = (float4){0.f, 0.f, 0.f, 0.f};
        else          ((float4*)p1)[(zb - 576) * 256 + threadIdx.x] = (float4){0.f, 0.f, 0.f, 0.f};
        return;
    }
    int idx = blk * 256 + threadIdx.x;  // 7840*256 = 2,007,040 exact
    const float* src; ushort_t* dst; int off;
    if (idx < 163840)      { src = w1; dst = o1; off = idx; }
    else if (idx < 532480) { src = w2; dst = o2; off = idx - 163840; }
    else                   { src = w3; dst = o3; off = idx - 532480; }
    dst[off] = f2bf(src[off]);
}

// ================= routing (3 iters), all branches fused =================
template<int R>
__device__ void routing_body(const float* __restrict__ u, const ushort_t* __restrict__ rwb,
                             float* __restrict__ lens, int n, int b, int tid,
                             unsigned int* pri, float* red, float* vsh, float* sred) {
    constexpr int KMAX = (R + 255) / 256;
    int lane = tid & 63, wv = tid >> 6;
    float blog[KMAX];
    #pragma unroll
    for (int k = 0; k < KMAX; ++k) {
        blog[k] = 0.f;
        int r = tid + k * 256;
        if (r < R) {
            const float4* up = (const float4*)(u + ((size_t)b * R + r) * 8);
            float4 ua = up[0], ub2 = up[1];
            float uu[8] = {ua.x, ua.y, ua.z, ua.w, ub2.x, ub2.y, ub2.z, ub2.w};
            const ushort_t* wr = rwb + ((size_t)n * R + r) * 128;
            float po[16] = {};
            #pragma unroll
            for (int i = 0; i < 8; ++i) {
                short8 wa = *reinterpret_cast<const short8*>(wr + i * 16);
                short8 wb = *reinterpret_cast<const short8*>(wr + i * 16 + 8);
                #pragma unroll
                for (int o = 0; o < 8; ++o) po[o]     += uu[i] * bf2f((unsigned short)wa[o]);
                #pragma unroll
                for (int o = 0; o < 8; ++o) po[8 + o] += uu[i] * bf2f((unsigned short)wb[o]);
            }
            #pragma unroll
            for (int j = 0; j < 8; ++j)
                pri[j * R + r] = (unsigned int)f2bf(po[2*j]) | ((unsigned int)f2bf(po[2*j+1]) << 16);
        }
    }
    __syncthreads();
    float v[16];
    for (int it = 0; it < 3; ++it) {
        float lmax = -1e30f;
        #pragma unroll
        for (int k = 0; k < KMAX; ++k)
            if (tid + k * 256 < R) lmax = fmaxf(lmax, blog[k]);
        for (int off = 32; off; off >>= 1) lmax = fmaxf(lmax, __shfl_down(lmax, off));
        if (lane == 0) sred[wv] = lmax;
        __syncthreads();
        float mx = fmaxf(fmaxf(sred[0], sred[1]), fmaxf(sred[2], sred[3]));
        __syncthreads();
        float ce[KMAX];
        float lsum = 0.f;
        #pragma unroll
        for (int k = 0; k < KMAX; ++k) {
            ce[k] = (tid + k * 256 < R) ? expf(blog[k] - mx) : 0.f;
            lsum += ce[k];
        }
        for (int off = 32; off; off >>= 1) lsum += __shfl_down(lsum, off);
        if (lane == 0) sred[wv] = lsum;
        __syncthreads();
        float inv = 1.f / (sred[0] + sred[1] + sred[2] + sred[3]);
        float sacc[16] = {};
        #pragma unroll
        for (int k = 0; k < KMAX; ++k) {
            int r = tid + k * 256;
            if (r < R) {
                float c = ce[k] * inv;
                #pragma unroll
                for (int j = 0; j < 8; ++j) {
                    unsigned int w = pri[j * R + r];
                    sacc[2*j]   += c * bf2f((unsigned short)(w & 0xffffu));
                    sacc[2*j+1] += c * bf2f((unsigned short)(w >> 16));
                }
            }
        }
        #pragma unroll
        for (int o = 0; o < 16; ++o) {
            float xv = sacc[o];
            for (int off = 32; off; off >>= 1) xv += __shfl_down(xv, off);
            if (lane == 0) red[wv * 16 + o] = xv;
        }
        __syncthreads();
        if (tid < 16) vsh[tid] = red[tid] + red[16 + tid] + red[32 + tid] + red[48 + tid];
        __syncthreads();
        if (tid == 0) {
            float sn = 0.f;
            #pragma unroll
            for (int o = 0; o < 16; ++o) sn += vsh[o] * vsh[o];
            float f = sn / ((1.f + sn) * sqrtf(sn + SQ_EPS));
            #pragma unroll
            for (int o = 0; o < 16; ++o) vsh[o] *= f;
        }
        __syncthreads();
        #pragma unroll
        for (int o = 0; o < 16; ++o) v[o] = vsh[o];
        if (it < 2) {
            #pragma unroll
            for (int k = 0; k < KMAX; ++k) {
                int r = tid + k * 256;
                if (r < R) {
                    float dot = 0.f;
                    #pragma unroll
                    for (int j = 0; j < 8; ++j) {
                        unsigned int w = pri[j * R + r];
                        dot += bf2f((unsigned short)(w & 0xffffu)) * v[2*j];
                        dot += bf2f((unsigned short)(w >> 16)) * v[2*j+1];
                    }
                    blog[k] += dot;
                }
            }
        }
    }
    if (tid == 0) {
        float sn = 0.f;
        #pragma unroll
        for (int o = 0; o < 16; ++o) sn += v[o] * v[o];
        lens[b * 10 + n] = sqrtf(sn + SQ_EPS);
    }
}

__global__ __launch_bounds__(256, 4) void routing_all_kernel(
        const float* __restrict__ u1, const float* __restrict__ u2, const float* __restrict__ u3,
        const ushort_t* __restrict__ rwb1, const ushort_t* __restrict__ rwb2,
        const ushort_t* __restrict__ rwb3,
        float* __restrict__ l1, float* __restrict__ l2, float* __restrict__ l3) {
    __shared__ unsigned int pri[8 * 1152];
    __shared__ float red[4 * 16];
    __shared__ float vsh[16];
    __shared__ float sred[4];
    int n = blockIdx.x, b = blockIdx.y, br = blockIdx.z, tid = threadIdx.x;
    if (br == 0)      routing_body<128>(u1, rwb1, l1, n, b, tid, pri, red, vsh, sred);
    else if (br == 1) routing_body<288>(u2, rwb2, l2, n, b, tid, pri, red, vsh, sred);
    else              routing_body<1152>(u3, rwb3, l3, n, b, tid, pri, red, vsh, sred);
}

// ---------------- final: softmax over classes of l1+l2+l3 ----------------
__global__ void final_softmax_kernel(const float* __restrict__ l1, const float* __restrict__ l2,
                                     const float* __restrict__ l3, float* __restrict__ out) {
    int b = threadIdx.x;
    float v[10]; float mx = -1e30f;
    #pragma unroll
    for (int n = 0; n < 10; ++n) {
        v[n] = l1[b * 10 + n] + l2[b * 10 + n] + l3[b * 10 + n];
        mx = fmaxf(mx, v[n]);
    }
    float s = 0.f;
    #pragma unroll
    for (int n = 0; n < 10; ++n) { v[n] = expf(v[n] - mx); s += v[n]; }
    float inv = 1.f / s;
    #pragma unroll
    for (int n = 0; n < 10; ++n) out[b * 10 + n] = v[n] * inv;
}

extern "C" void kernel_launch(void* const* d_in, const int* in_sizes, int n_in,
                              void* d_out, int out_size, void* d_ws, size_t ws_size,
                              hipStream_t stream) {
    const float* x   = (const float*)d_in[0];
    const float* c1w = (const float*)d_in[1];
    const float* c1b = (const float*)d_in[2];
    const float* p1w = (const float*)d_in[3];
    const float* p1b = (const float*)d_in[4];
    const float* d1w = (const float*)d_in[5];
    const float* c2w = (const float*)d_in[6];
    const float* c2b = (const float*)d_in[7];
    const float* p2w = (const float*)d_in[8];
    const float* p2b = (const float*)d_in[9];
    const float* d2w = (const float*)d_in[10];
    const float* c3w = (const float*)d_in[11];
    const float* c3b = (const float*)d_in[12];
    const float* p3w = (const float*)d_in[13];
    const float* p3b = (const float*)d_in[14];
    const float* d3w = (const float*)d_in[15];

    float* ws = (float*)d_ws;
    // region layout (float units) — total 23,403,520 floats = 93.6 MB
    float* x2    = ws + 0;          // 50176 (unused now; kept for layout stability)
    float* x1    = ws + 50176;      // 12544 (unused)
    float* yh1f  = ws + 62720;      // 409600   [aliased by u1 later]
    float* yl1f  = ws + 472320;     // 409600
    float* yh2f  = ws + 881920;     // 1638400  [aliased by u2 later]
    float* yl2f  = ws + 2520320;    // 1638400
    float* yh3f  = ws + 4158720;    // 6553600  [aliased by u3 later]
    float* yl3f  = ws + 10712320;   // 6553600  [aliased by rwb after gemm3]
    float* wh1f  = ws + 17265920;   // 147456
    float* wl1f  = ws + 17413376;   // 147456
    float* wh2f  = ws + 17560832;   // 409600
    float* wl2f  = ws + 17970432;   // 409600
    float* wh3f  = ws + 18380032;   // 1327104  [aliased by p2 later]
    float* wl3f  = ws + 19707136;   // 1327104  [aliased by p1 later]
    float* p3    = ws + 21034240;   // 2359296  [bn partials scratch until zeroed]
    float* bnp1  = ws + 23393536;   // 512 x3
    float* bias1 = ws + 23395072;   // 256
    float* bias2 = ws + 23395328;   // 256
    float* bias3 = ws + 23395584;   // 256
    float* l1    = ws + 23395840;   // 2560
    float* l2    = ws + 23398400;   // 2560
    float* l3    = ws + 23400960;   // 2560
    (void)x2; (void)x1;

    ushort_t* yh1 = (ushort_t*)yh1f; ushort_t* yl1 = (ushort_t*)yl1f;
    ushort_t* yh2 = (ushort_t*)yh2f; ushort_t* yl2 = (ushort_t*)yl2f;
    ushort_t* yh3 = (ushort_t*)yh3f; ushort_t* yl3 = (ushort_t*)yl3f;
    ushort_t* wh1 = (ushort_t*)wh1f; ushort_t* wl1 = (ushort_t*)wl1f;
    ushort_t* wh2 = (ushort_t*)wh2f; ushort_t* wl2 = (ushort_t*)wl2f;
    ushort_t* wh3 = (ushort_t*)wh3f; ushort_t* wl3 = (ushort_t*)wl3f;
    // aliases (safe by stream ordering):
    float* u1 = yh1f;   // written after gemm21 reads yh1
    float* u2 = yh2f;
    float* u3 = yh3f;
    float* p2 = wh3f;   // zero+atomic after gemm3 reads wh3
    float* p1 = wl3f;
    ushort_t* rwb1 = (ushort_t*)yl3f;          // 163840 halves (after gemm3 frees yl3)
    ushort_t* rwb2 = rwb1 + 163840;            // 368640
    ushort_t* rwb3 = rwb2 + 368640;            // 1474560 (total 2,007,040 <= 13,107,200)

    // 1. conv all branches (pooling inline; BN partials -> p3 scratch)
    conv_all_kernel<<<768, 256, 0, stream>>>(x, c1w, c1b, c2w, c2b, c3w, c3b,
                                             yh1, yl1, yh2, yl2, yh3, yl3, p3);
    // 2. BN finalize from partials
    bn_final_kernel<<<3, 128, 0, stream>>>(p3, bnp1);
    // 3. weight transform + bias fold + zero p3
    wtrans_zero_kernel<<<3072, 256, 0, stream>>>(p1w, p2w, p3w, bnp1, p1b, p2b, p3b,
                                                 wh1, wl1, wh2, wl2, wh3, wl3,
                                                 bias1, bias2, bias3, p3);
    // 4. gemm3 (after: wh3/wl3 dead -> p2/p1; yl3 dead -> rwb)
    gemm3_kernel<<<dim3(72, 2, 6), 256, 0, stream>>>(yh3, yl3, wh3, wl3, p3);
    // 5. routing weights -> bf16 + zero p2/p1
    rwtrans_zero_kernel<<<8672, 256, 0, stream>>>(d1w, d2w, d3w, rwb1, rwb2, rwb3, p2, p1);
    // 6. gemm2 + gemm1 fused
    gemm21_kernel<<<504, 256, 0, stream>>>(yh2, yl2, wh2, wl2, p2, yh1, yl1, wh1, wl1, p1);
    // 7. squash all branches
    squash_all_kernel<<<1568, 256, 0, stream>>>(p1, p2, p3, bias1, bias2, bias3, u1, u2, u3);
    // 8. routing all branches
    routing_all_kernel<<<dim3(10, 256, 3), 256, 0, stream>>>(u1, u2, u3, rwb1, rwb2, rwb3, l1, l2, l3);
    // 9. final softmax
    final_softmax_kernel<<<1, 256, 0, stream>>>(l1, l2, l3, (float*)d_out);
}

// Round 13
// 555.838 us; speedup vs baseline: 2.3644x; 1.0459x over previous
//
#include <hip/hip_runtime.h>
#include <math.h>

#define SQ_EPS 1e-12f
#define BN_EPS 1e-5f

typedef short short8 __attribute__((ext_vector_type(8)));
typedef float f32x4 __attribute__((ext_vector_type(4)));
typedef unsigned short ushort_t;

__device__ inline unsigned short f2bf(float x) {
    unsigned int u = __float_as_uint(x);
    unsigned int r = (u + 0x7fffu + ((u >> 16) & 1u)) >> 16;   // round-to-nearest-even
    return (unsigned short)r;
}
__device__ inline float bf2f(unsigned short h) {
    return __uint_as_float(((unsigned int)h) << 16);
}

// ================= fused conv (3 branches, pooling inline) =================
template<int IH, int IW, int KS, int OH, int OW>
__device__ void conv_body(const float* __restrict__ w, const float* __restrict__ bias,
                          ushort_t* __restrict__ yh, ushort_t* __restrict__ yl,
                          float* __restrict__ partial,
                          int b, int tid, float* s_img, float* s_w, float* s_red) {
    constexpr int KK = KS * KS;
    constexpr int OS = OH * OW;
    for (int i = tid; i < 128 * KK; i += 256) s_w[i] = w[i];
    __syncthreads();
    int c = tid & 127, half = tid >> 7;
    float bias_c = bias[c];
    float bsum = 0.f, bsq = 0.f;
    for (int r = half; r < OH; r += 2) {
        float acc[OW];
        #pragma unroll
        for (int j = 0; j < OW; ++j) acc[j] = bias_c;
        for (int u = 0; u < KS; ++u) {
            float rg[OW + KS - 1];
            #pragma unroll
            for (int j = 0; j < OW + KS - 1; ++j) rg[j] = s_img[(r + u) * IW + j];
            #pragma unroll
            for (int v = 0; v < KS; ++v) {
                float wv = s_w[c * KK + u * KS + v];
                #pragma unroll
                for (int j = 0; j < OW; ++j) acc[j] += wv * rg[j + v];
            }
        }
        #pragma unroll
        for (int j = 0; j < OW; ++j) {
            float val = fmaxf(acc[j], 0.f);
            bsum += val; bsq += val * val;
            unsigned short h = f2bf(val);
            unsigned short lo = f2bf(val - bf2f(h));
            int oidx = ((b * OS) + r * OW + j) * 128 + c;
            yh[oidx] = h; yl[oidx] = lo;
        }
    }
    s_red[tid] = bsum; __syncthreads();
    if (tid < 128) partial[b * 256 + c] = s_red[tid] + s_red[tid + 128];
    __syncthreads();
    s_red[tid] = bsq; __syncthreads();
    if (tid < 128) partial[b * 256 + 128 + c] = s_red[tid] + s_red[tid + 128];
}

__global__ __launch_bounds__(256) void conv_all_kernel(
        const float* __restrict__ img,
        const float* __restrict__ c1w, const float* __restrict__ c1b,
        const float* __restrict__ c2w, const float* __restrict__ c2b,
        const float* __restrict__ c3w, const float* __restrict__ c3b,
        ushort_t* __restrict__ yh1, ushort_t* __restrict__ yl1,
        ushort_t* __restrict__ yh2, ushort_t* __restrict__ yl2,
        ushort_t* __restrict__ yh3, ushort_t* __restrict__ yl3,
        float* __restrict__ partial_base) {
    __shared__ float s_img[784];
    __shared__ float s_tmp[196];
    __shared__ float s_w[128 * 81];
    __shared__ float s_red[256];
    int br = blockIdx.x >> 8, b = blockIdx.x & 255, tid = threadIdx.x;
    const float* im = img + b * 784;
    for (int i = tid; i < 784; i += 256) s_img[i] = im[i];
    __syncthreads();
    if (br <= 1) {
        for (int idx = tid; idx < 196; idx += 256) {
            int i = idx / 14, j = idx % 14;
            s_tmp[idx] = 0.25f * (s_img[(2*i)*28 + 2*j]   + s_img[(2*i)*28 + 2*j + 1] +
                                  s_img[(2*i+1)*28 + 2*j] + s_img[(2*i+1)*28 + 2*j + 1]);
        }
        __syncthreads();
        if (br == 0) {
            for (int idx = tid; idx < 49; idx += 256) {
                int i = idx / 7, j = idx % 7;
                s_img[idx] = 0.25f * (s_tmp[(2*i)*14 + 2*j]   + s_tmp[(2*i)*14 + 2*j + 1] +
                                      s_tmp[(2*i+1)*14 + 2*j] + s_tmp[(2*i+1)*14 + 2*j + 1]);
            }
        } else {
            for (int idx = tid; idx < 196; idx += 256) s_img[idx] = s_tmp[idx];
        }
        __syncthreads();
    }
    if (br == 0)      conv_body<7, 7, 3, 5, 5>(c1w, c1b, yh1, yl1, partial_base, b, tid, s_img, s_w, s_red);
    else if (br == 1) conv_body<14, 14, 5, 10, 10>(c2w, c2b, yh2, yl2, partial_base + 65536, b, tid, s_img, s_w, s_red);
    else              conv_body<28, 28, 9, 20, 20>(c3w, c3b, yh3, yl3, partial_base + 131072, b, tid, s_img, s_w, s_red);
}

// ---------------- finalize BN from per-block partials ----------------
__global__ void bn_final_kernel(const float* __restrict__ partial_base, float* __restrict__ bnp_base) {
    int br = blockIdx.x;
    const float* pp = partial_base + br * 65536;
    float* bnp = bnp_base + br * 512;
    float N = (br == 0) ? 6400.f : ((br == 1) ? 25600.f : 102400.f);
    int c = threadIdx.x;  // 128
    float s = 0.f, q = 0.f;
    for (int blk = 0; blk < 256; ++blk) {
        s += pp[blk * 256 + c];
        q += pp[blk * 256 + 128 + c];
    }
    float mean = s / N;
    float var = q / N - mean * mean;
    float inv = rsqrtf(var + BN_EPS);
    bnp[256 + c] = inv;
    bnp[384 + c] = -mean * inv;
}

// ---------------- weight transform + bias fold + p3 zeroing (fused) ----------------
__global__ __launch_bounds__(256) void wtrans_zero_kernel(
        const float* __restrict__ w1, const float* __restrict__ w2,
        const float* __restrict__ w3, const float* __restrict__ bnp_base,
        const float* __restrict__ pb1, const float* __restrict__ pb2,
        const float* __restrict__ pb3,
        ushort_t* __restrict__ wh1, ushort_t* __restrict__ wl1,
        ushort_t* __restrict__ wh2, ushort_t* __restrict__ wl2,
        ushort_t* __restrict__ wh3, ushort_t* __restrict__ wl3,
        float* __restrict__ b1, float* __restrict__ b2, float* __restrict__ b3,
        float* __restrict__ p3zero) {
    __shared__ float tile[128 * 81];
    __shared__ float r2[2];
    int blk = blockIdx.x, tid = threadIdx.x;
    if (blk >= 768) {   // zero p3: 2304 blocks x 256 x float4 = 2,359,296 floats
        ((float4*)p3zero)[(blk - 768) * 256 + tid] = (float4){0.f, 0.f, 0.f, 0.f};
        return;
    }
    int br = blk >> 8, ch = blk & 255;
    const float* w; const float* pb; ushort_t* wh; ushort_t* wl; float* bf; int KK;
    if (br == 0)      { w = w1; pb = pb1; wh = wh1; wl = wl1; bf = b1; KK = 9;  }
    else if (br == 1) { w = w2; pb = pb2; wh = wh2; wl = wl2; bf = b2; KK = 25; }
    else              { w = w3; pb = pb3; wh = wh3; wl = wl3; bf = b3; KK = 81; }
    const float* bnp = bnp_base + br * 512;
    int n = 128 * KK;
    const float* wrow = w + ch * n;
    for (int i = tid; i < n; i += 256) tile[i] = wrow[i];   // coalesced fp32 read
    __syncthreads();
    for (int j = tid; j < n; j += 256) {                    // coalesced u16 writes (c innermost)
        int uv = j >> 7, c = j & 127;
        float val = tile[c * KK + uv] * bnp[256 + c];       // stride KK odd -> conflict-free
        unsigned short h = f2bf(val);
        unsigned short lo = f2bf(val - bf2f(h));
        int oidx = uv * 32768 + (ch << 7) + c;
        wh[oidx] = h; wl[oidx] = lo;
    }
    float s = 0.f;
    if (tid < 128) {
        for (int uv = 0; uv < KK; ++uv) s += tile[tid * KK + uv];
        s *= bnp[384 + tid];
    }
    for (int off = 32; off; off >>= 1) s += __shfl_down(s, off);
    if (tid < 128 && (tid & 63) == 0) r2[tid >> 6] = s;
    __syncthreads();
    if (tid == 0) bf[ch] = pb[ch] + r2[0] + r2[1];
}

// ================= split-bf16 MFMA GEMM body (device fn) =================
template<int S, int WO, int IHg, int IWg, int KS, int ZCH>
__device__ void gemm_body(const ushort_t* __restrict__ yh, const ushort_t* __restrict__ yl,
                          const ushort_t* __restrict__ wh, const ushort_t* __restrict__ wl,
                          float* __restrict__ p, int bx, int by, int bz, int tid,
                          ushort_t* Ash, ushort_t* Asl, ushort_t* Bsh, ushort_t* Bsl) {
    int bm = bx * 128, ch0 = by * 128;
    int arow = tid >> 2;
    int c0 = tid & 3;
    int sw0 = (c0 ^ ((arow >> 1) & 3)) * 8;
    int wA0 = arow * 32 + sw0;
    int wA1 = (arow + 64) * 32 + sw0;
    int m0 = bm + arow;
    int b0 = m0 / S, s0 = m0 % S;
    int abase0 = ((b0 * IHg + 2 * (s0 / WO)) * IWg + 2 * (s0 % WO)) * 128 + c0 * 8;
    int m1 = m0 + 64;
    int b1 = m1 / S, s1 = m1 % S;
    int abase1 = ((b1 * IHg + 2 * (s1 / WO)) * IWg + 2 * (s1 % WO)) * 128 + c0 * 8;
    int bbase0 = (ch0 + arow) * 128 + c0 * 8;
    int bbase1 = (ch0 + arow + 64) * 128 + c0 * 8;
    int lane = tid & 63, wid = tid >> 6;
    int wm = wid & 1, wn = wid >> 1;
    int quad = lane >> 4, l16 = lane & 15;
    int aoffL[4], boffL[4];
    #pragma unroll
    for (int mi = 0; mi < 4; ++mi) {
        int row = wm * 64 + mi * 16 + l16;
        aoffL[mi] = row * 32 + ((quad ^ ((row >> 1) & 3)) * 8);
    }
    #pragma unroll
    for (int ni = 0; ni < 4; ++ni) {
        int row = wn * 64 + ni * 16 + l16;
        boffL[ni] = row * 32 + ((quad ^ ((row >> 1) & 3)) * 8);
    }
    f32x4 acc[4][4];
    #pragma unroll
    for (int mi = 0; mi < 4; ++mi)
        #pragma unroll
        for (int ni = 0; ni < 4; ++ni)
            acc[mi][ni] = (f32x4){0.f, 0.f, 0.f, 0.f};

    int kc = bz * ZCH;
    int uv = kc >> 2, ci = kc & 3;
    int u = uv / KS, v = uv - u * KS;
    int aoff = (u * IWg + v) * 128 + (ci << 5);
    int boff = uv * 32768 + (ci << 5);
    int4 a0h = *reinterpret_cast<const int4*>(yh + abase0 + aoff);
    int4 a0l = *reinterpret_cast<const int4*>(yl + abase0 + aoff);
    int4 a1h = *reinterpret_cast<const int4*>(yh + abase1 + aoff);
    int4 a1l = *reinterpret_cast<const int4*>(yl + abase1 + aoff);
    int4 b0h = *reinterpret_cast<const int4*>(wh + bbase0 + boff);
    int4 b0l = *reinterpret_cast<const int4*>(wl + bbase0 + boff);
    int4 b1h = *reinterpret_cast<const int4*>(wh + bbase1 + boff);
    int4 b1l = *reinterpret_cast<const int4*>(wl + bbase1 + boff);

    for (int t = 0; t < ZCH; ++t) {
        __syncthreads();
        *reinterpret_cast<int4*>(&Ash[wA0]) = a0h;
        *reinterpret_cast<int4*>(&Asl[wA0]) = a0l;
        *reinterpret_cast<int4*>(&Ash[wA1]) = a1h;
        *reinterpret_cast<int4*>(&Asl[wA1]) = a1l;
        *reinterpret_cast<int4*>(&Bsh[wA0]) = b0h;
        *reinterpret_cast<int4*>(&Bsl[wA0]) = b0l;
        *reinterpret_cast<int4*>(&Bsh[wA1]) = b1h;
        *reinterpret_cast<int4*>(&Bsl[wA1]) = b1l;
        if (t + 1 < ZCH) {   // prefetch next chunk (uniform branch)
            ci = (ci + 1) & 3;
            if (ci == 0) { ++uv; ++v; if (v == KS) { v = 0; ++u; } }
            aoff = (u * IWg + v) * 128 + (ci << 5);
            boff = uv * 32768 + (ci << 5);
            a0h = *reinterpret_cast<const int4*>(yh + abase0 + aoff);
            a0l = *reinterpret_cast<const int4*>(yl + abase0 + aoff);
            a1h = *reinterpret_cast<const int4*>(yh + abase1 + aoff);
            a1l = *reinterpret_cast<const int4*>(yl + abase1 + aoff);
            b0h = *reinterpret_cast<const int4*>(wh + bbase0 + boff);
            b0l = *reinterpret_cast<const int4*>(wl + bbase0 + boff);
            b1h = *reinterpret_cast<const int4*>(wh + bbase1 + boff);
            b1l = *reinterpret_cast<const int4*>(wl + bbase1 + boff);
        }
        __syncthreads();
        short8 bh[4], bl[4];
        #pragma unroll
        for (int ni = 0; ni < 4; ++ni) {
            bh[ni] = *reinterpret_cast<const short8*>(&Bsh[boffL[ni]]);
            bl[ni] = *reinterpret_cast<const short8*>(&Bsl[boffL[ni]]);
        }
        #pragma unroll
        for (int mi = 0; mi < 4; ++mi) {
            short8 ah = *reinterpret_cast<const short8*>(&Ash[aoffL[mi]]);
            short8 al = *reinterpret_cast<const short8*>(&Asl[aoffL[mi]]);
            #pragma unroll
            for (int ni = 0; ni < 4; ++ni) {
                acc[mi][ni] = __builtin_amdgcn_mfma_f32_16x16x32_bf16(ah, bh[ni], acc[mi][ni], 0, 0, 0);
                acc[mi][ni] = __builtin_amdgcn_mfma_f32_16x16x32_bf16(al, bh[ni], acc[mi][ni], 0, 0, 0);
                acc[mi][ni] = __builtin_amdgcn_mfma_f32_16x16x32_bf16(ah, bl[ni], acc[mi][ni], 0, 0, 0);
            }
        }
    }
    // C/D layout (measured m89): col = lane&15, row = quad*4 + reg
    #pragma unroll
    for (int mi = 0; mi < 4; ++mi)
        #pragma unroll
        for (int ni = 0; ni < 4; ++ni) {
            int col = ch0 + wn * 64 + ni * 16 + l16;
            #pragma unroll
            for (int reg = 0; reg < 4; ++reg) {
                int row = bm + wm * 64 + mi * 16 + quad * 4 + reg;
                atomicAdd(p + (size_t)row * 256 + col, acc[mi][ni][reg]);
            }
        }
}

// gemm3: grid (72, 2, 6)
__global__ __launch_bounds__(256, 3) void gemm3_kernel(
        const ushort_t* __restrict__ yh, const ushort_t* __restrict__ yl,
        const ushort_t* __restrict__ wh, const ushort_t* __restrict__ wl,
        float* __restrict__ p) {
    __shared__ ushort_t Ash[128 * 32], Asl[128 * 32];
    __shared__ ushort_t Bsh[128 * 32], Bsl[128 * 32];
    gemm_body<36, 6, 20, 20, 9, 54>(yh, yl, wh, wl, p,
                                    blockIdx.x, blockIdx.y, blockIdx.z, threadIdx.x,
                                    Ash, Asl, Bsh, Bsl);
}

// gemm2 + gemm1 fused: blocks 0..359 = branch2 (18x2x10, ZCH=10); 360..503 = branch1 (8x2x9, ZCH=4)
__global__ __launch_bounds__(256, 3) void gemm21_kernel(
        const ushort_t* __restrict__ yh2, const ushort_t* __restrict__ yl2,
        const ushort_t* __restrict__ wh2, const ushort_t* __restrict__ wl2, float* __restrict__ p2,
        const ushort_t* __restrict__ yh1, const ushort_t* __restrict__ yl1,
        const ushort_t* __restrict__ wh1, const ushort_t* __restrict__ wl1, float* __restrict__ p1) {
    __shared__ ushort_t Ash[128 * 32], Asl[128 * 32];
    __shared__ ushort_t Bsh[128 * 32], Bsl[128 * 32];
    int blk = blockIdx.x, tid = threadIdx.x;
    if (blk < 360) {
        int z = blk / 36, rem = blk % 36, y = rem / 18, x = rem % 18;
        gemm_body<9, 3, 10, 10, 5, 10>(yh2, yl2, wh2, wl2, p2, x, y, z, tid, Ash, Asl, Bsh, Bsl);
    } else {
        int b = blk - 360;
        int z = b / 16, rem = b % 16, y = rem / 8, x = rem % 8;
        gemm_body<4, 2, 5, 5, 3, 4>(yh1, yl1, wh1, wl1, p1, x, y, z, tid, Ash, Asl, Bsh, Bsl);
    }
}

// ---------------- squash primary caps (all branches): p(B*S,256)+bias -> u(B,32*S,8) ----------------
__global__ void squash_all_kernel(const float* __restrict__ p1, const float* __restrict__ p2,
                                  const float* __restrict__ p3,
                                  const float* __restrict__ bias1, const float* __restrict__ bias2,
                                  const float* __restrict__ bias3,
                                  float* __restrict__ u1, float* __restrict__ u2,
                                  float* __restrict__ u3) {
    int blk = blockIdx.x;
    const float* p; const float* bias; float* u; int S;
    if (blk < 128)      { p = p1; bias = bias1; u = u1; S = 4; }
    else if (blk < 416) { p = p2; bias = bias2; u = u2; S = 9;  blk -= 128; }
    else                { p = p3; bias = bias3; u = u3; S = 36; blk -= 416; }
    int idx = blk * 256 + threadIdx.x;   // over 256*S*32, o innermost
    int o = idx & 31, rest = idx >> 5;
    int s = rest % S, b = rest / S;
    const float* pp = p + (size_t)(b * S + s) * 256 + o;
    float t[8]; float sn = 0.f;
    #pragma unroll
    for (int i = 0; i < 8; ++i) { t[i] = pp[i * 32] + bias[o + i * 32]; sn += t[i] * t[i]; }
    float f = sn / ((1.f + sn) * sqrtf(sn + SQ_EPS));
    float* up = u + (size_t)(b * (32 * S) + o * S + s) * 8;
    float4 w0 = {t[0] * f, t[1] * f, t[2] * f, t[3] * f};
    float4 w1 = {t[4] * f, t[5] * f, t[6] * f, t[7] * f};
    *reinterpret_cast<float4*>(up) = w0;
    *reinterpret_cast<float4*>(up + 4) = w1;
}

// ---------------- routing weights -> bf16 in transposed layout [n][g][r][8] + zero p2/p1 ----------------
__global__ void rwtrans_zero_kernel(const float* __restrict__ w1, const float* __restrict__ w2,
                                    const float* __restrict__ w3,
                                    ushort_t* __restrict__ o1, ushort_t* __restrict__ o2,
                                    ushort_t* __restrict__ o3,
                                    float* __restrict__ p2, float* __restrict__ p1) {
    int blk = blockIdx.x;
    if (blk >= 7840) {   // zero p2 (576 blocks) then p1 (256 blocks)
        int zb = blk - 7840;
        if (zb < 576) ((float4*)p2)[zb * 256 + threadIdx.x] = (float4){0.f, 0.f, 0.f, 0.f};
        else          ((float4*)p1)[(zb - 576) * 256 + threadIdx.x] = (float4){0.f, 0.f, 0.f, 0.f};
        return;
    }
    int idx = blk * 256 + threadIdx.x;  // 7840*256 = 2,007,040 exact
    // dst flat = ((n*16+g)*R + r)*8 + jj ; src = (n*R + r)*128 + g*8 + jj
    if (idx < 163840) {           // br1: R=128
        int t = idx;
        int jj = t & 7; t >>= 3;
        int r = t & 127; t >>= 7;
        int g = t & 15; int n = t >> 4;
        o1[idx] = f2bf(w1[(n * 128 + r) * 128 + g * 8 + jj]);
    } else if (idx < 532480) {    // br2: R=288
        int t = idx - 163840;
        int jj = t & 7; t >>= 3;
        int r = t % 288; t /= 288;
        int g = t & 15; int n = t >> 4;
        o2[idx - 163840] = f2bf(w2[(n * 288 + r) * 128 + g * 8 + jj]);
    } else {                      // br3: R=1152
        int t = idx - 532480;
        int jj = t & 7; t >>= 3;
        int r = t % 1152; t /= 1152;
        int g = t & 15; int n = t >> 4;
        o3[idx - 532480] = f2bf(w3[(n * 1152 + r) * 128 + g * 8 + jj]);
    }
}

// ================= routing (3 iters), all branches fused =================
// it0: softmax(0) is uniform -> no exp/reduce. it1/it2: fused single streaming pass
// (dot -> blog += -> e=exp(blog) [no max-sub: |blog|<~22, fp32-safe] -> sacc += e*pv),
// normalization by sum(e) folded in AFTER the block reduction.
template<int R>
__device__ void routing_body(const float* __restrict__ u, const ushort_t* __restrict__ rwb,
                             float* __restrict__ lens, int n, int b, int tid,
                             unsigned int* pri, float* red, float* vsh, float* sred) {
    constexpr int KMAX = (R + 255) / 256;
    int lane = tid & 63, wv = tid >> 6;
    // ---- build priors; w loads coalesced via [n][g][r][8] layout ----
    #pragma unroll
    for (int k = 0; k < KMAX; ++k) {
        int r = tid + k * 256;
        if (r < R) {
            const float4* up = (const float4*)(u + ((size_t)b * R + r) * 8);
            float4 ua = up[0], ub2 = up[1];
            float uu[8] = {ua.x, ua.y, ua.z, ua.w, ub2.x, ub2.y, ub2.z, ub2.w};
            float po[16] = {};
            #pragma unroll
            for (int g = 0; g < 16; ++g) {
                short8 wg = *reinterpret_cast<const short8*>(rwb + (((size_t)n * 16 + g) * R + r) * 8);
                float ui = uu[g >> 1];
                int o0 = (g & 1) * 8;
                #pragma unroll
                for (int jj = 0; jj < 8; ++jj)
                    po[o0 + jj] += ui * bf2f((unsigned short)wg[jj]);
            }
            #pragma unroll
            for (int j = 0; j < 8; ++j)
                pri[j * R + r] = (unsigned int)f2bf(po[2*j]) | ((unsigned int)f2bf(po[2*j+1]) << 16);
        }
    }
    __syncthreads();
    float v[16];
    float blog[KMAX];
    #pragma unroll
    for (int k = 0; k < KMAX; ++k) blog[k] = 0.f;
    // ---- it0: uniform coupling c = 1/R ----
    {
        float sacc[16] = {};
        #pragma unroll
        for (int k = 0; k < KMAX; ++k) {
            int r = tid + k * 256;
            if (r < R) {
                #pragma unroll
                for (int j = 0; j < 8; ++j) {
                    unsigned int w = pri[j * R + r];
                    sacc[2*j]   += bf2f((unsigned short)(w & 0xffffu));
                    sacc[2*j+1] += bf2f((unsigned short)(w >> 16));
                }
            }
        }
        #pragma unroll
        for (int o = 0; o < 16; ++o) {
            float xv = sacc[o];
            for (int off = 32; off; off >>= 1) xv += __shfl_down(xv, off);
            if (lane == 0) red[wv * 16 + o] = xv;
        }
        __syncthreads();
        if (tid < 16) vsh[tid] = (red[tid] + red[16 + tid] + red[32 + tid] + red[48 + tid]) * (1.0f / (float)R);
        __syncthreads();
        if (tid == 0) {
            float sn = 0.f;
            #pragma unroll
            for (int o = 0; o < 16; ++o) sn += vsh[o] * vsh[o];
            float f = sn / ((1.f + sn) * sqrtf(sn + SQ_EPS));
            #pragma unroll
            for (int o = 0; o < 16; ++o) vsh[o] *= f;
        }
        __syncthreads();
        #pragma unroll
        for (int o = 0; o < 16; ++o) v[o] = vsh[o];
        __syncthreads();
    }
    // ---- it1, it2: fused blog-update + softmax-weighted sum ----
    for (int it = 0; it < 2; ++it) {
        float sacc[16] = {};
        float lsum = 0.f;
        #pragma unroll
        for (int k = 0; k < KMAX; ++k) {
            int r = tid + k * 256;
            if (r < R) {
                float pv[16];
                #pragma unroll
                for (int j = 0; j < 8; ++j) {
                    unsigned int w = pri[j * R + r];
                    pv[2*j]   = bf2f((unsigned short)(w & 0xffffu));
                    pv[2*j+1] = bf2f((unsigned short)(w >> 16));
                }
                float dot = 0.f;
                #pragma unroll
                for (int o = 0; o < 16; ++o) dot += pv[o] * v[o];
                blog[k] += dot;
                float e = expf(blog[k]);
                lsum += e;
                #pragma unroll
                for (int o = 0; o < 16; ++o) sacc[o] += e * pv[o];
            }
        }
        for (int off = 32; off; off >>= 1) lsum += __shfl_down(lsum, off);
        if (lane == 0) sred[wv] = lsum;
        #pragma unroll
        for (int o = 0; o < 16; ++o) {
            float xv = sacc[o];
            for (int off = 32; off; off >>= 1) xv += __shfl_down(xv, off);
            if (lane == 0) red[wv * 16 + o] = xv;
        }
        __syncthreads();
        if (tid < 16) {
            float tot = sred[0] + sred[1] + sred[2] + sred[3];
            vsh[tid] = (red[tid] + red[16 + tid] + red[32 + tid] + red[48 + tid]) / tot;
        }
        __syncthreads();
        if (tid == 0) {
            float sn = 0.f;
            #pragma unroll
            for (int o = 0; o < 16; ++o) sn += vsh[o] * vsh[o];
            float f = sn / ((1.f + sn) * sqrtf(sn + SQ_EPS));
            #pragma unroll
            for (int o = 0; o < 16; ++o) vsh[o] *= f;
        }
        __syncthreads();
        #pragma unroll
        for (int o = 0; o < 16; ++o) v[o] = vsh[o];
        __syncthreads();
    }
    if (tid == 0) {
        float sn = 0.f;
        #pragma unroll
        for (int o = 0; o < 16; ++o) sn += v[o] * v[o];
        lens[b * 10 + n] = sqrtf(sn + SQ_EPS);
    }
}

__global__ __launch_bounds__(256, 4) void routing_all_kernel(
        const float* __restrict__ u1, const float* __restrict__ u2, const float* __restrict__ u3,
        const ushort_t* __restrict__ rwb1, const ushort_t* __restrict__ rwb2,
        const ushort_t* __restrict__ rwb3,
        float* __restrict__ l1, float* __restrict__ l2, float* __restrict__ l3) {
    __shared__ unsigned int pri[8 * 1152];
    __shared__ float red[4 * 16];
    __shared__ float vsh[16];
    __shared__ float sred[4];
    int n = blockIdx.x, b = blockIdx.y, br = blockIdx.z, tid = threadIdx.x;
    if (br == 0)      routing_body<128>(u1, rwb1, l1, n, b, tid, pri, red, vsh, sred);
    else if (br == 1) routing_body<288>(u2, rwb2, l2, n, b, tid, pri, red, vsh, sred);
    else              routing_body<1152>(u3, rwb3, l3, n, b, tid, pri, red, vsh, sred);
}

// ---------------- final: softmax over classes of l1+l2+l3 ----------------
__global__ void final_softmax_kernel(const float* __restrict__ l1, const float* __restrict__ l2,
                                     const float* __restrict__ l3, float* __restrict__ out) {
    int b = threadIdx.x;
    float v[10]; float mx = -1e30f;
    #pragma unroll
    for (int n = 0; n < 10; ++n) {
        v[n] = l1[b * 10 + n] + l2[b * 10 + n] + l3[b * 10 + n];
        mx = fmaxf(mx, v[n]);
    }
    float s = 0.f;
    #pragma unroll
    for (int n = 0; n < 10; ++n) { v[n] = expf(v[n] - mx); s += v[n]; }
    float inv = 1.f / s;
    #pragma unroll
    for (int n = 0; n < 10; ++n) out[b * 10 + n] = v[n] * inv;
}

extern "C" void kernel_launch(void* const* d_in, const int* in_sizes, int n_in,
                              void* d_out, int out_size, void* d_ws, size_t ws_size,
                              hipStream_t stream) {
    const float* x   = (const float*)d_in[0];
    const float* c1w = (const float*)d_in[1];
    const float* c1b = (const float*)d_in[2];
    const float* p1w = (const float*)d_in[3];
    const float* p1b = (const float*)d_in[4];
    const float* d1w = (const float*)d_in[5];
    const float* c2w = (const float*)d_in[6];
    const float* c2b = (const float*)d_in[7];
    const float* p2w = (const float*)d_in[8];
    const float* p2b = (const float*)d_in[9];
    const float* d2w = (const float*)d_in[10];
    const float* c3w = (const float*)d_in[11];
    const float* c3b = (const float*)d_in[12];
    const float* p3w = (const float*)d_in[13];
    const float* p3b = (const float*)d_in[14];
    const float* d3w = (const float*)d_in[15];

    float* ws = (float*)d_ws;
    float* yh1f  = ws + 62720;      // 409600   [aliased by u1 later]
    float* yl1f  = ws + 472320;     // 409600
    float* yh2f  = ws + 881920;     // 1638400  [aliased by u2 later]
    float* yl2f  = ws + 2520320;    // 1638400
    float* yh3f  = ws + 4158720;    // 6553600  [aliased by u3 later]
    float* yl3f  = ws + 10712320;   // 6553600  [aliased by rwb after gemm3]
    float* wh1f  = ws + 17265920;   // 147456
    float* wl1f  = ws + 17413376;   // 147456
    float* wh2f  = ws + 17560832;   // 409600
    float* wl2f  = ws + 17970432;   // 409600
    float* wh3f  = ws + 18380032;   // 1327104  [aliased by p2 later]
    float* wl3f  = ws + 19707136;   // 1327104  [aliased by p1 later]
    float* p3    = ws + 21034240;   // 2359296  [bn partials scratch until zeroed]
    float* bnp1  = ws + 23393536;   // 512 x3
    float* bias1 = ws + 23395072;   // 256
    float* bias2 = ws + 23395328;   // 256
    float* bias3 = ws + 23395584;   // 256
    float* l1    = ws + 23395840;   // 2560
    float* l2    = ws + 23398400;   // 2560
    float* l3    = ws + 23400960;   // 2560

    ushort_t* yh1 = (ushort_t*)yh1f; ushort_t* yl1 = (ushort_t*)yl1f;
    ushort_t* yh2 = (ushort_t*)yh2f; ushort_t* yl2 = (ushort_t*)yl2f;
    ushort_t* yh3 = (ushort_t*)yh3f; ushort_t* yl3 = (ushort_t*)yl3f;
    ushort_t* wh1 = (ushort_t*)wh1f; ushort_t* wl1 = (ushort_t*)wl1f;
    ushort_t* wh2 = (ushort_t*)wh2f; ushort_t* wl2 = (ushort_t*)wl2f;
    ushort_t* wh3 = (ushort_t*)wh3f; ushort_t* wl3 = (ushort_t*)wl3f;
    float* u1 = yh1f;
    float* u2 = yh2f;
    float* u3 = yh3f;
    float* p2 = wh3f;
    float* p1 = wl3f;
    ushort_t* rwb1 = (ushort_t*)yl3f;          // 163840 halves (after gemm3 frees yl3)
    ushort_t* rwb2 = rwb1 + 163840;            // 368640
    ushort_t* rwb3 = rwb2 + 368640;            // 1474560 (total 2,007,040 <= 13,107,200)

    conv_all_kernel<<<768, 256, 0, stream>>>(x, c1w, c1b, c2w, c2b, c3w, c3b,
                                             yh1, yl1, yh2, yl2, yh3, yl3, p3);
    bn_final_kernel<<<3, 128, 0, stream>>>(p3, bnp1);
    wtrans_zero_kernel<<<3072, 256, 0, stream>>>(p1w, p2w, p3w, bnp1, p1b, p2b, p3b,
                                                 wh1, wl1, wh2, wl2, wh3, wl3,
                                                 bias1, bias2, bias3, p3);
    gemm3_kernel<<<dim3(72, 2, 6), 256, 0, stream>>>(yh3, yl3, wh3, wl3, p3);
    rwtrans_zero_kernel<<<8672, 256, 0, stream>>>(d1w, d2w, d3w, rwb1, rwb2, rwb3, p2, p1);
    gemm21_kernel<<<504, 256, 0, stream>>>(yh2, yl2, wh2, wl2, p2, yh1, yl1, wh1, wl1, p1);
    squash_all_kernel<<<1568, 256, 0, stream>>>(p1, p2, p3, bias1, bias2, bias3, u1, u2, u3);
    routing_all_kernel<<<dim3(10, 256, 3), 256, 0, stream>>>(u1, u2, u3, rwb1, rwb2, rwb3, l1, l2, l3);
    final_softmax_kernel<<<1, 256, 0, stream>>>(l1, l2, l3, (float*)d_out);
}

// Round 14
// 532.510 us; speedup vs baseline: 2.4680x; 1.0438x over previous
//
#include <hip/hip_runtime.h>
#include <math.h>

#define SQ_EPS 1e-12f
#define BN_EPS 1e-5f

typedef short short8 __attribute__((ext_vector_type(8)));
typedef float f32x4 __attribute__((ext_vector_type(4)));
typedef unsigned short ushort_t;

__device__ inline unsigned short f2bf(float x) {
    unsigned int u = __float_as_uint(x);
    unsigned int r = (u + 0x7fffu + ((u >> 16) & 1u)) >> 16;   // round-to-nearest-even
    return (unsigned short)r;
}
__device__ inline float bf2f(unsigned short h) {
    return __uint_as_float(((unsigned int)h) << 16);
}

// ================= fused conv (3 branches, pooling inline) =================
template<int IH, int IW, int KS, int OH, int OW>
__device__ void conv_body(const float* __restrict__ w, const float* __restrict__ bias,
                          ushort_t* __restrict__ yh, ushort_t* __restrict__ yl,
                          float* __restrict__ partial,
                          int b, int tid, float* s_img, float* s_w, float* s_red) {
    constexpr int KK = KS * KS;
    constexpr int OS = OH * OW;
    for (int i = tid; i < 128 * KK; i += 256) s_w[i] = w[i];
    __syncthreads();
    int c = tid & 127, half = tid >> 7;
    float bias_c = bias[c];
    float bsum = 0.f, bsq = 0.f;
    for (int r = half; r < OH; r += 2) {
        float acc[OW];
        #pragma unroll
        for (int j = 0; j < OW; ++j) acc[j] = bias_c;
        for (int u = 0; u < KS; ++u) {
            float rg[OW + KS - 1];
            #pragma unroll
            for (int j = 0; j < OW + KS - 1; ++j) rg[j] = s_img[(r + u) * IW + j];
            #pragma unroll
            for (int v = 0; v < KS; ++v) {
                float wv = s_w[c * KK + u * KS + v];
                #pragma unroll
                for (int j = 0; j < OW; ++j) acc[j] += wv * rg[j + v];
            }
        }
        #pragma unroll
        for (int j = 0; j < OW; ++j) {
            float val = fmaxf(acc[j], 0.f);
            bsum += val; bsq += val * val;
            unsigned short h = f2bf(val);
            unsigned short lo = f2bf(val - bf2f(h));
            int oidx = ((b * OS) + r * OW + j) * 128 + c;
            yh[oidx] = h; yl[oidx] = lo;
        }
    }
    s_red[tid] = bsum; __syncthreads();
    if (tid < 128) partial[b * 256 + c] = s_red[tid] + s_red[tid + 128];
    __syncthreads();
    s_red[tid] = bsq; __syncthreads();
    if (tid < 128) partial[b * 256 + 128 + c] = s_red[tid] + s_red[tid + 128];
}

__global__ __launch_bounds__(256) void conv_all_kernel(
        const float* __restrict__ img,
        const float* __restrict__ c1w, const float* __restrict__ c1b,
        const float* __restrict__ c2w, const float* __restrict__ c2b,
        const float* __restrict__ c3w, const float* __restrict__ c3b,
        ushort_t* __restrict__ yh1, ushort_t* __restrict__ yl1,
        ushort_t* __restrict__ yh2, ushort_t* __restrict__ yl2,
        ushort_t* __restrict__ yh3, ushort_t* __restrict__ yl3,
        float* __restrict__ partial_base) {
    __shared__ float s_img[784];
    __shared__ float s_tmp[196];
    __shared__ float s_w[128 * 81];
    __shared__ float s_red[256];
    int br = blockIdx.x >> 8, b = blockIdx.x & 255, tid = threadIdx.x;
    const float* im = img + b * 784;
    for (int i = tid; i < 784; i += 256) s_img[i] = im[i];
    __syncthreads();
    if (br <= 1) {
        for (int idx = tid; idx < 196; idx += 256) {
            int i = idx / 14, j = idx % 14;
            s_tmp[idx] = 0.25f * (s_img[(2*i)*28 + 2*j]   + s_img[(2*i)*28 + 2*j + 1] +
                                  s_img[(2*i+1)*28 + 2*j] + s_img[(2*i+1)*28 + 2*j + 1]);
        }
        __syncthreads();
        if (br == 0) {
            for (int idx = tid; idx < 49; idx += 256) {
                int i = idx / 7, j = idx % 7;
                s_img[idx] = 0.25f * (s_tmp[(2*i)*14 + 2*j]   + s_tmp[(2*i)*14 + 2*j + 1] +
                                      s_tmp[(2*i+1)*14 + 2*j] + s_tmp[(2*i+1)*14 + 2*j + 1]);
            }
        } else {
            for (int idx = tid; idx < 196; idx += 256) s_img[idx] = s_tmp[idx];
        }
        __syncthreads();
    }
    if (br == 0)      conv_body<7, 7, 3, 5, 5>(c1w, c1b, yh1, yl1, partial_base, b, tid, s_img, s_w, s_red);
    else if (br == 1) conv_body<14, 14, 5, 10, 10>(c2w, c2b, yh2, yl2, partial_base + 65536, b, tid, s_img, s_w, s_red);
    else              conv_body<28, 28, 9, 20, 20>(c3w, c3b, yh3, yl3, partial_base + 131072, b, tid, s_img, s_w, s_red);
}

// ---------------- finalize BN from per-block partials ----------------
__global__ void bn_final_kernel(const float* __restrict__ partial_base, float* __restrict__ bnp_base) {
    int br = blockIdx.x;
    const float* pp = partial_base + br * 65536;
    float* bnp = bnp_base + br * 512;
    float N = (br == 0) ? 6400.f : ((br == 1) ? 25600.f : 102400.f);
    int c = threadIdx.x;  // 128
    float s = 0.f, q = 0.f;
    for (int blk = 0; blk < 256; ++blk) {
        s += pp[blk * 256 + c];
        q += pp[blk * 256 + 128 + c];
    }
    float mean = s / N;
    float var = q / N - mean * mean;
    float inv = rsqrtf(var + BN_EPS);
    bnp[256 + c] = inv;
    bnp[384 + c] = -mean * inv;
}

// ---------------- weight transform + bias fold + p3 zeroing (fused) ----------------
__global__ __launch_bounds__(256) void wtrans_zero_kernel(
        const float* __restrict__ w1, const float* __restrict__ w2,
        const float* __restrict__ w3, const float* __restrict__ bnp_base,
        const float* __restrict__ pb1, const float* __restrict__ pb2,
        const float* __restrict__ pb3,
        ushort_t* __restrict__ wh1, ushort_t* __restrict__ wl1,
        ushort_t* __restrict__ wh2, ushort_t* __restrict__ wl2,
        ushort_t* __restrict__ wh3, ushort_t* __restrict__ wl3,
        float* __restrict__ b1, float* __restrict__ b2, float* __restrict__ b3,
        float* __restrict__ p3zero) {
    __shared__ float tile[128 * 81];
    __shared__ float r2[2];
    int blk = blockIdx.x, tid = threadIdx.x;
    if (blk >= 768) {   // zero p3: 2304 blocks x 256 x float4 = 2,359,296 floats
        ((float4*)p3zero)[(blk - 768) * 256 + tid] = (float4){0.f, 0.f, 0.f, 0.f};
        return;
    }
    int br = blk >> 8, ch = blk & 255;
    const float* w; const float* pb; ushort_t* wh; ushort_t* wl; float* bf; int KK;
    if (br == 0)      { w = w1; pb = pb1; wh = wh1; wl = wl1; bf = b1; KK = 9;  }
    else if (br == 1) { w = w2; pb = pb2; wh = wh2; wl = wl2; bf = b2; KK = 25; }
    else              { w = w3; pb = pb3; wh = wh3; wl = wl3; bf = b3; KK = 81; }
    const float* bnp = bnp_base + br * 512;
    int n = 128 * KK;
    const float* wrow = w + ch * n;
    for (int i = tid; i < n; i += 256) tile[i] = wrow[i];   // coalesced fp32 read
    __syncthreads();
    for (int j = tid; j < n; j += 256) {                    // coalesced u16 writes (c innermost)
        int uv = j >> 7, c = j & 127;
        float val = tile[c * KK + uv] * bnp[256 + c];       // stride KK odd -> conflict-free
        unsigned short h = f2bf(val);
        unsigned short lo = f2bf(val - bf2f(h));
        int oidx = uv * 32768 + (ch << 7) + c;
        wh[oidx] = h; wl[oidx] = lo;
    }
    float s = 0.f;
    if (tid < 128) {
        for (int uv = 0; uv < KK; ++uv) s += tile[tid * KK + uv];
        s *= bnp[384 + tid];
    }
    for (int off = 32; off; off >>= 1) s += __shfl_down(s, off);
    if (tid < 128 && (tid & 63) == 0) r2[tid >> 6] = s;
    __syncthreads();
    if (tid == 0) bf[ch] = pb[ch] + r2[0] + r2[1];
}

// ================= split-bf16 MFMA GEMM body (device fn) =================
template<int S, int WO, int IHg, int IWg, int KS, int ZCH>
__device__ void gemm_body(const ushort_t* __restrict__ yh, const ushort_t* __restrict__ yl,
                          const ushort_t* __restrict__ wh, const ushort_t* __restrict__ wl,
                          float* __restrict__ p, int bx, int by, int bz, int tid,
                          ushort_t* Ash, ushort_t* Asl, ushort_t* Bsh, ushort_t* Bsl) {
    int bm = bx * 128, ch0 = by * 128;
    int arow = tid >> 2;
    int c0 = tid & 3;
    int sw0 = (c0 ^ ((arow >> 1) & 3)) * 8;
    int wA0 = arow * 32 + sw0;
    int wA1 = (arow + 64) * 32 + sw0;
    int m0 = bm + arow;
    int b0 = m0 / S, s0 = m0 % S;
    int abase0 = ((b0 * IHg + 2 * (s0 / WO)) * IWg + 2 * (s0 % WO)) * 128 + c0 * 8;
    int m1 = m0 + 64;
    int b1 = m1 / S, s1 = m1 % S;
    int abase1 = ((b1 * IHg + 2 * (s1 / WO)) * IWg + 2 * (s1 % WO)) * 128 + c0 * 8;
    int bbase0 = (ch0 + arow) * 128 + c0 * 8;
    int bbase1 = (ch0 + arow + 64) * 128 + c0 * 8;
    int lane = tid & 63, wid = tid >> 6;
    int wm = wid & 1, wn = wid >> 1;
    int quad = lane >> 4, l16 = lane & 15;
    int aoffL[4], boffL[4];
    #pragma unroll
    for (int mi = 0; mi < 4; ++mi) {
        int row = wm * 64 + mi * 16 + l16;
        aoffL[mi] = row * 32 + ((quad ^ ((row >> 1) & 3)) * 8);
    }
    #pragma unroll
    for (int ni = 0; ni < 4; ++ni) {
        int row = wn * 64 + ni * 16 + l16;
        boffL[ni] = row * 32 + ((quad ^ ((row >> 1) & 3)) * 8);
    }
    f32x4 acc[4][4];
    #pragma unroll
    for (int mi = 0; mi < 4; ++mi)
        #pragma unroll
        for (int ni = 0; ni < 4; ++ni)
            acc[mi][ni] = (f32x4){0.f, 0.f, 0.f, 0.f};

    int kc = bz * ZCH;
    int uv = kc >> 2, ci = kc & 3;
    int u = uv / KS, v = uv - u * KS;
    int aoff = (u * IWg + v) * 128 + (ci << 5);
    int boff = uv * 32768 + (ci << 5);
    int4 a0h = *reinterpret_cast<const int4*>(yh + abase0 + aoff);
    int4 a0l = *reinterpret_cast<const int4*>(yl + abase0 + aoff);
    int4 a1h = *reinterpret_cast<const int4*>(yh + abase1 + aoff);
    int4 a1l = *reinterpret_cast<const int4*>(yl + abase1 + aoff);
    int4 b0h = *reinterpret_cast<const int4*>(wh + bbase0 + boff);
    int4 b0l = *reinterpret_cast<const int4*>(wl + bbase0 + boff);
    int4 b1h = *reinterpret_cast<const int4*>(wh + bbase1 + boff);
    int4 b1l = *reinterpret_cast<const int4*>(wl + bbase1 + boff);

    for (int t = 0; t < ZCH; ++t) {
        __syncthreads();
        *reinterpret_cast<int4*>(&Ash[wA0]) = a0h;
        *reinterpret_cast<int4*>(&Asl[wA0]) = a0l;
        *reinterpret_cast<int4*>(&Ash[wA1]) = a1h;
        *reinterpret_cast<int4*>(&Asl[wA1]) = a1l;
        *reinterpret_cast<int4*>(&Bsh[wA0]) = b0h;
        *reinterpret_cast<int4*>(&Bsl[wA0]) = b0l;
        *reinterpret_cast<int4*>(&Bsh[wA1]) = b1h;
        *reinterpret_cast<int4*>(&Bsl[wA1]) = b1l;
        if (t + 1 < ZCH) {   // prefetch next chunk (uniform branch)
            ci = (ci + 1) & 3;
            if (ci == 0) { ++uv; ++v; if (v == KS) { v = 0; ++u; } }
            aoff = (u * IWg + v) * 128 + (ci << 5);
            boff = uv * 32768 + (ci << 5);
            a0h = *reinterpret_cast<const int4*>(yh + abase0 + aoff);
            a0l = *reinterpret_cast<const int4*>(yl + abase0 + aoff);
            a1h = *reinterpret_cast<const int4*>(yh + abase1 + aoff);
            a1l = *reinterpret_cast<const int4*>(yl + abase1 + aoff);
            b0h = *reinterpret_cast<const int4*>(wh + bbase0 + boff);
            b0l = *reinterpret_cast<const int4*>(wl + bbase0 + boff);
            b1h = *reinterpret_cast<const int4*>(wh + bbase1 + boff);
            b1l = *reinterpret_cast<const int4*>(wl + bbase1 + boff);
        }
        __syncthreads();
        short8 bh[4], bl[4];
        #pragma unroll
        for (int ni = 0; ni < 4; ++ni) {
            bh[ni] = *reinterpret_cast<const short8*>(&Bsh[boffL[ni]]);
            bl[ni] = *reinterpret_cast<const short8*>(&Bsl[boffL[ni]]);
        }
        #pragma unroll
        for (int mi = 0; mi < 4; ++mi) {
            short8 ah = *reinterpret_cast<const short8*>(&Ash[aoffL[mi]]);
            short8 al = *reinterpret_cast<const short8*>(&Asl[aoffL[mi]]);
            #pragma unroll
            for (int ni = 0; ni < 4; ++ni) {
                acc[mi][ni] = __builtin_amdgcn_mfma_f32_16x16x32_bf16(ah, bh[ni], acc[mi][ni], 0, 0, 0);
                acc[mi][ni] = __builtin_amdgcn_mfma_f32_16x16x32_bf16(al, bh[ni], acc[mi][ni], 0, 0, 0);
                acc[mi][ni] = __builtin_amdgcn_mfma_f32_16x16x32_bf16(ah, bl[ni], acc[mi][ni], 0, 0, 0);
            }
        }
    }
    // C/D layout (measured m89): col = lane&15, row = quad*4 + reg
    #pragma unroll
    for (int mi = 0; mi < 4; ++mi)
        #pragma unroll
        for (int ni = 0; ni < 4; ++ni) {
            int col = ch0 + wn * 64 + ni * 16 + l16;
            #pragma unroll
            for (int reg = 0; reg < 4; ++reg) {
                int row = bm + wm * 64 + mi * 16 + quad * 4 + reg;
                atomicAdd(p + (size_t)row * 256 + col, acc[mi][ni][reg]);
            }
        }
}

// gemm3: grid (72, 2, 6)
__global__ __launch_bounds__(256, 3) void gemm3_kernel(
        const ushort_t* __restrict__ yh, const ushort_t* __restrict__ yl,
        const ushort_t* __restrict__ wh, const ushort_t* __restrict__ wl,
        float* __restrict__ p) {
    __shared__ ushort_t Ash[128 * 32], Asl[128 * 32];
    __shared__ ushort_t Bsh[128 * 32], Bsl[128 * 32];
    gemm_body<36, 6, 20, 20, 9, 54>(yh, yl, wh, wl, p,
                                    blockIdx.x, blockIdx.y, blockIdx.z, threadIdx.x,
                                    Ash, Asl, Bsh, Bsl);
}

// gemm2 + gemm1 fused: blocks 0..359 = branch2 (18x2x10, ZCH=10); 360..503 = branch1 (8x2x9, ZCH=4)
__global__ __launch_bounds__(256, 3) void gemm21_kernel(
        const ushort_t* __restrict__ yh2, const ushort_t* __restrict__ yl2,
        const ushort_t* __restrict__ wh2, const ushort_t* __restrict__ wl2, float* __restrict__ p2,
        const ushort_t* __restrict__ yh1, const ushort_t* __restrict__ yl1,
        const ushort_t* __restrict__ wh1, const ushort_t* __restrict__ wl1, float* __restrict__ p1) {
    __shared__ ushort_t Ash[128 * 32], Asl[128 * 32];
    __shared__ ushort_t Bsh[128 * 32], Bsl[128 * 32];
    int blk = blockIdx.x, tid = threadIdx.x;
    if (blk < 360) {
        int z = blk / 36, rem = blk % 36, y = rem / 18, x = rem % 18;
        gemm_body<9, 3, 10, 10, 5, 10>(yh2, yl2, wh2, wl2, p2, x, y, z, tid, Ash, Asl, Bsh, Bsl);
    } else {
        int b = blk - 360;
        int z = b / 16, rem = b % 16, y = rem / 8, x = rem % 8;
        gemm_body<4, 2, 5, 5, 3, 4>(yh1, yl1, wh1, wl1, p1, x, y, z, tid, Ash, Asl, Bsh, Bsl);
    }
}

// ---------------- squash primary caps (all branches): p(B*S,256)+bias -> u(B,32*S,8) ----------------
__global__ void squash_all_kernel(const float* __restrict__ p1, const float* __restrict__ p2,
                                  const float* __restrict__ p3,
                                  const float* __restrict__ bias1, const float* __restrict__ bias2,
                                  const float* __restrict__ bias3,
                                  float* __restrict__ u1, float* __restrict__ u2,
                                  float* __restrict__ u3) {
    int blk = blockIdx.x;
    const float* p; const float* bias; float* u; int S;
    if (blk < 128)      { p = p1; bias = bias1; u = u1; S = 4; }
    else if (blk < 416) { p = p2; bias = bias2; u = u2; S = 9;  blk -= 128; }
    else                { p = p3; bias = bias3; u = u3; S = 36; blk -= 416; }
    int idx = blk * 256 + threadIdx.x;   // over 256*S*32, o innermost
    int o = idx & 31, rest = idx >> 5;
    int s = rest % S, b = rest / S;
    const float* pp = p + (size_t)(b * S + s) * 256 + o;
    float t[8]; float sn = 0.f;
    #pragma unroll
    for (int i = 0; i < 8; ++i) { t[i] = pp[i * 32] + bias[o + i * 32]; sn += t[i] * t[i]; }
    float f = sn / ((1.f + sn) * sqrtf(sn + SQ_EPS));
    float* up = u + (size_t)(b * (32 * S) + o * S + s) * 8;
    float4 w0 = {t[0] * f, t[1] * f, t[2] * f, t[3] * f};
    float4 w1 = {t[4] * f, t[5] * f, t[6] * f, t[7] * f};
    *reinterpret_cast<float4*>(up) = w0;
    *reinterpret_cast<float4*>(up + 4) = w1;
}

// ---------------- routing weights -> f32 transposed [n][g2][r][4] + zero p2/p1 ----------------
__global__ void rwtrans_zero_kernel(const float* __restrict__ w1, const float* __restrict__ w2,
                                    const float* __restrict__ w3,
                                    float* __restrict__ o1, float* __restrict__ o2,
                                    float* __restrict__ o3,
                                    float* __restrict__ p2, float* __restrict__ p1) {
    int blk = blockIdx.x;
    if (blk >= 7840) {   // zero p2 (576 blocks) then p1 (256 blocks)
        int zb = blk - 7840;
        if (zb < 576) ((float4*)p2)[zb * 256 + threadIdx.x] = (float4){0.f, 0.f, 0.f, 0.f};
        else          ((float4*)p1)[(zb - 576) * 256 + threadIdx.x] = (float4){0.f, 0.f, 0.f, 0.f};
        return;
    }
    int idx = blk * 256 + threadIdx.x;  // 7840*256 = 2,007,040 exact
    // dst flat = ((n*32+g2)*R + r)*4 + jj ; src = (n*R + r)*128 + g2*4 + jj
    if (idx < 163840) {           // br1: R=128
        int t = idx;
        int jj = t & 3; t >>= 2;
        int r = t & 127; t >>= 7;
        int g2 = t & 31; int n = t >> 5;
        o1[idx] = w1[(n * 128 + r) * 128 + g2 * 4 + jj];
    } else if (idx < 532480) {    // br2: R=288
        int t = idx - 163840;
        int jj = t & 3; t >>= 2;
        int r = t % 288; t /= 288;
        int g2 = t & 31; int n = t >> 5;
        o2[idx - 163840] = w2[(n * 288 + r) * 128 + g2 * 4 + jj];
    } else {                      // br3: R=1152
        int t = idx - 532480;
        int jj = t & 3; t >>= 2;
        int r = t % 1152; t /= 1152;
        int g2 = t & 31; int n = t >> 5;
        o3[idx - 532480] = w3[(n * 1152 + r) * 128 + g2 * 4 + jj];
    }
}

// ================= routing (3 iters), all branches fused =================
// build: f32 w (coalesced float4, no unpack); pri packed bf16x2 in LDS, b128 via XOR-swizzled
// half-address r*8 + ((c^(r&1))*4): 2 lanes/bank both write & read (free).
// it0: uniform c=1/R (no exp). it1/it2: fused dot->blog->exp->sacc (no max-sub; |blog|<~22).
template<int R>
__device__ void routing_body(const float* __restrict__ u, const float* __restrict__ rwt,
                             float* __restrict__ lens, int n, int b, int tid,
                             unsigned int* pri, float* red, float* vsh, float* sred) {
    constexpr int KMAX = (R + 255) / 256;
    int lane = tid & 63, wv = tid >> 6;
    // ---- build priors ----
    #pragma unroll
    for (int k = 0; k < KMAX; ++k) {
        int r = tid + k * 256;
        if (r < R) {
            const float4* up = (const float4*)(u + ((size_t)b * R + r) * 8);
            float4 ua = up[0], ub2 = up[1];
            float uu[8] = {ua.x, ua.y, ua.z, ua.w, ub2.x, ub2.y, ub2.z, ub2.w};
            float po[16] = {};
            #pragma unroll
            for (int g2 = 0; g2 < 32; ++g2) {
                float4 w4 = *reinterpret_cast<const float4*>(rwt + (((size_t)n * 32 + g2) * R + r) * 4);
                float ui = uu[g2 >> 2];
                int o0 = (g2 & 3) * 4;
                po[o0 + 0] += ui * w4.x;
                po[o0 + 1] += ui * w4.y;
                po[o0 + 2] += ui * w4.z;
                po[o0 + 3] += ui * w4.w;
            }
            unsigned int d[8];
            #pragma unroll
            for (int j = 0; j < 8; ++j)
                d[j] = (unsigned int)f2bf(po[2*j]) | ((unsigned int)f2bf(po[2*j+1]) << 16);
            int i0 = r * 8 + ((0 ^ (r & 1)) * 4);
            int i1 = r * 8 + ((1 ^ (r & 1)) * 4);
            *reinterpret_cast<uint4*>(pri + i0) = (uint4){d[0], d[1], d[2], d[3]};
            *reinterpret_cast<uint4*>(pri + i1) = (uint4){d[4], d[5], d[6], d[7]};
        }
    }
    __syncthreads();
    float v[16];
    float blog[KMAX];
    #pragma unroll
    for (int k = 0; k < KMAX; ++k) blog[k] = 0.f;
    // ---- it0: uniform coupling c = 1/R ----
    {
        float sacc[16] = {};
        #pragma unroll
        for (int k = 0; k < KMAX; ++k) {
            int r = tid + k * 256;
            if (r < R) {
                int i0 = r * 8 + ((0 ^ (r & 1)) * 4);
                int i1 = r * 8 + ((1 ^ (r & 1)) * 4);
                uint4 h0 = *reinterpret_cast<const uint4*>(pri + i0);
                uint4 h1 = *reinterpret_cast<const uint4*>(pri + i1);
                unsigned int d[8] = {h0.x, h0.y, h0.z, h0.w, h1.x, h1.y, h1.z, h1.w};
                #pragma unroll
                for (int j = 0; j < 8; ++j) {
                    sacc[2*j]   += bf2f((unsigned short)(d[j] & 0xffffu));
                    sacc[2*j+1] += bf2f((unsigned short)(d[j] >> 16));
                }
            }
        }
        #pragma unroll
        for (int o = 0; o < 16; ++o) {
            float xv = sacc[o];
            for (int off = 32; off; off >>= 1) xv += __shfl_down(xv, off);
            if (lane == 0) red[wv * 16 + o] = xv;
        }
        __syncthreads();
        if (tid < 16) vsh[tid] = (red[tid] + red[16 + tid] + red[32 + tid] + red[48 + tid]) * (1.0f / (float)R);
        __syncthreads();
        if (tid == 0) {
            float sn = 0.f;
            #pragma unroll
            for (int o = 0; o < 16; ++o) sn += vsh[o] * vsh[o];
            float f = sn / ((1.f + sn) * sqrtf(sn + SQ_EPS));
            #pragma unroll
            for (int o = 0; o < 16; ++o) vsh[o] *= f;
        }
        __syncthreads();
        #pragma unroll
        for (int o = 0; o < 16; ++o) v[o] = vsh[o];
        __syncthreads();
    }
    // ---- it1, it2: fused blog-update + softmax-weighted sum ----
    for (int it = 0; it < 2; ++it) {
        float sacc[16] = {};
        float lsum = 0.f;
        #pragma unroll
        for (int k = 0; k < KMAX; ++k) {
            int r = tid + k * 256;
            if (r < R) {
                int i0 = r * 8 + ((0 ^ (r & 1)) * 4);
                int i1 = r * 8 + ((1 ^ (r & 1)) * 4);
                uint4 h0 = *reinterpret_cast<const uint4*>(pri + i0);
                uint4 h1 = *reinterpret_cast<const uint4*>(pri + i1);
                unsigned int d[8] = {h0.x, h0.y, h0.z, h0.w, h1.x, h1.y, h1.z, h1.w};
                float pv[16];
                #pragma unroll
                for (int j = 0; j < 8; ++j) {
                    pv[2*j]   = bf2f((unsigned short)(d[j] & 0xffffu));
                    pv[2*j+1] = bf2f((unsigned short)(d[j] >> 16));
                }
                float dot = 0.f;
                #pragma unroll
                for (int o = 0; o < 16; ++o) dot += pv[o] * v[o];
                blog[k] += dot;
                float e = expf(blog[k]);
                lsum += e;
                #pragma unroll
                for (int o = 0; o < 16; ++o) sacc[o] += e * pv[o];
            }
        }
        for (int off = 32; off; off >>= 1) lsum += __shfl_down(lsum, off);
        if (lane == 0) sred[wv] = lsum;
        #pragma unroll
        for (int o = 0; o < 16; ++o) {
            float xv = sacc[o];
            for (int off = 32; off; off >>= 1) xv += __shfl_down(xv, off);
            if (lane == 0) red[wv * 16 + o] = xv;
        }
        __syncthreads();
        if (tid < 16) {
            float tot = sred[0] + sred[1] + sred[2] + sred[3];
            vsh[tid] = (red[tid] + red[16 + tid] + red[32 + tid] + red[48 + tid]) / tot;
        }
        __syncthreads();
        if (tid == 0) {
            float sn = 0.f;
            #pragma unroll
            for (int o = 0; o < 16; ++o) sn += vsh[o] * vsh[o];
            float f = sn / ((1.f + sn) * sqrtf(sn + SQ_EPS));
            #pragma unroll
            for (int o = 0; o < 16; ++o) vsh[o] *= f;
        }
        __syncthreads();
        #pragma unroll
        for (int o = 0; o < 16; ++o) v[o] = vsh[o];
        __syncthreads();
    }
    if (tid == 0) {
        float sn = 0.f;
        #pragma unroll
        for (int o = 0; o < 16; ++o) sn += v[o] * v[o];
        lens[b * 10 + n] = sqrtf(sn + SQ_EPS);
    }
}

__global__ __launch_bounds__(256, 4) void routing_all_kernel(
        const float* __restrict__ u1, const float* __restrict__ u2, const float* __restrict__ u3,
        const float* __restrict__ rwt1, const float* __restrict__ rwt2,
        const float* __restrict__ rwt3,
        float* __restrict__ l1, float* __restrict__ l2, float* __restrict__ l3) {
    __shared__ unsigned int pri[8 * 1152];
    __shared__ float red[4 * 16];
    __shared__ float vsh[16];
    __shared__ float sred[4];
    int n = blockIdx.x, b = blockIdx.y, br = 2 - blockIdx.z, tid = threadIdx.x;  // heavy branch first
    if (br == 0)      routing_body<128>(u1, rwt1, l1, n, b, tid, pri, red, vsh, sred);
    else if (br == 1) routing_body<288>(u2, rwt2, l2, n, b, tid, pri, red, vsh, sred);
    else              routing_body<1152>(u3, rwt3, l3, n, b, tid, pri, red, vsh, sred);
}

// ---------------- final: softmax over classes of l1+l2+l3 ----------------
__global__ void final_softmax_kernel(const float* __restrict__ l1, const float* __restrict__ l2,
                                     const float* __restrict__ l3, float* __restrict__ out) {
    int b = threadIdx.x;
    float v[10]; float mx = -1e30f;
    #pragma unroll
    for (int n = 0; n < 10; ++n) {
        v[n] = l1[b * 10 + n] + l2[b * 10 + n] + l3[b * 10 + n];
        mx = fmaxf(mx, v[n]);
    }
    float s = 0.f;
    #pragma unroll
    for (int n = 0; n < 10; ++n) { v[n] = expf(v[n] - mx); s += v[n]; }
    float inv = 1.f / s;
    #pragma unroll
    for (int n = 0; n < 10; ++n) out[b * 10 + n] = v[n] * inv;
}

extern "C" void kernel_launch(void* const* d_in, const int* in_sizes, int n_in,
                              void* d_out, int out_size, void* d_ws, size_t ws_size,
                              hipStream_t stream) {
    const float* x   = (const float*)d_in[0];
    const float* c1w = (const float*)d_in[1];
    const float* c1b = (const float*)d_in[2];
    const float* p1w = (const float*)d_in[3];
    const float* p1b = (const float*)d_in[4];
    const float* d1w = (const float*)d_in[5];
    const float* c2w = (const float*)d_in[6];
    const float* c2b = (const float*)d_in[7];
    const float* p2w = (const float*)d_in[8];
    const float* p2b = (const float*)d_in[9];
    const float* d2w = (const float*)d_in[10];
    const float* c3w = (const float*)d_in[11];
    const float* c3b = (const float*)d_in[12];
    const float* p3w = (const float*)d_in[13];
    const float* p3b = (const float*)d_in[14];
    const float* d3w = (const float*)d_in[15];

    float* ws = (float*)d_ws;
    float* yh1f  = ws + 62720;      // 409600   [aliased by u1 later]
    float* yl1f  = ws + 472320;     // 409600
    float* yh2f  = ws + 881920;     // 1638400  [aliased by u2 later]
    float* yl2f  = ws + 2520320;    // 1638400
    float* yh3f  = ws + 4158720;    // 6553600  [aliased by u3 later]
    float* yl3f  = ws + 10712320;   // 6553600  [aliased by rwt after gemm3]
    float* wh1f  = ws + 17265920;   // 147456
    float* wl1f  = ws + 17413376;   // 147456
    float* wh2f  = ws + 17560832;   // 409600
    float* wl2f  = ws + 17970432;   // 409600
    float* wh3f  = ws + 18380032;   // 1327104  [aliased by p2 later]
    float* wl3f  = ws + 19707136;   // 1327104  [aliased by p1 later]
    float* p3    = ws + 21034240;   // 2359296  [bn partials scratch until zeroed]
    float* bnp1  = ws + 23393536;   // 512 x3
    float* bias1 = ws + 23395072;   // 256
    float* bias2 = ws + 23395328;   // 256
    float* bias3 = ws + 23395584;   // 256
    float* l1    = ws + 23395840;   // 2560
    float* l2    = ws + 23398400;   // 2560
    float* l3    = ws + 23400960;   // 2560

    ushort_t* yh1 = (ushort_t*)yh1f; ushort_t* yl1 = (ushort_t*)yl1f;
    ushort_t* yh2 = (ushort_t*)yh2f; ushort_t* yl2 = (ushort_t*)yl2f;
    ushort_t* yh3 = (ushort_t*)yh3f; ushort_t* yl3 = (ushort_t*)yl3f;
    ushort_t* wh1 = (ushort_t*)wh1f; ushort_t* wl1 = (ushort_t*)wl1f;
    ushort_t* wh2 = (ushort_t*)wh2f; ushort_t* wl2 = (ushort_t*)wl2f;
    ushort_t* wh3 = (ushort_t*)wh3f; ushort_t* wl3 = (ushort_t*)wl3f;
    float* u1 = yh1f;
    float* u2 = yh2f;
    float* u3 = yh3f;
    float* p2 = wh3f;
    float* p1 = wl3f;
    // f32 transposed routing weights in dead yl3 region (after gemm3):
    float* rwt1 = yl3f;                        // 163840 floats
    float* rwt2 = rwt1 + 163840;               // 368640
    float* rwt3 = rwt2 + 368640;               // 1474560 (total 2,007,040 <= 6,553,600)

    conv_all_kernel<<<768, 256, 0, stream>>>(x, c1w, c1b, c2w, c2b, c3w, c3b,
                                             yh1, yl1, yh2, yl2, yh3, yl3, p3);
    bn_final_kernel<<<3, 128, 0, stream>>>(p3, bnp1);
    wtrans_zero_kernel<<<3072, 256, 0, stream>>>(p1w, p2w, p3w, bnp1, p1b, p2b, p3b,
                                                 wh1, wl1, wh2, wl2, wh3, wl3,
                                                 bias1, bias2, bias3, p3);
    gemm3_kernel<<<dim3(72, 2, 6), 256, 0, stream>>>(yh3, yl3, wh3, wl3, p3);
    rwtrans_zero_kernel<<<8672, 256, 0, stream>>>(d1w, d2w, d3w, rwt1, rwt2, rwt3, p2, p1);
    gemm21_kernel<<<504, 256, 0, stream>>>(yh2, yl2, wh2, wl2, p2, yh1, yl1, wh1, wl1, p1);
    squash_all_kernel<<<1568, 256, 0, stream>>>(p1, p2, p3, bias1, bias2, bias3, u1, u2, u3);
    routing_all_kernel<<<dim3(10, 256, 3), 256, 0, stream>>>(u1, u2, u3, rwt1, rwt2, rwt3, l1, l2, l3);
    final_softmax_kernel<<<1, 256, 0, stream>>>(l1, l2, l3, (float*)d_out);
}